// Round 1
// baseline (685.856 us; speedup 1.0000x reference)
//
#include <hip/hip_runtime.h>

// ---- problem constants (from reference setup_inputs) ----
constexpr int cS = 16, cN = 64, cH = 200, cW = 240;
constexpr int cHC = 25, cWC = 30;          // coarse fmap (stride 8)
constexpr int cHF = 100, cWF = 120;        // fine fmap (stride 2)
constexpr int cC = 64;                     // LAT
constexpr int cFF = 3000;                  // 50*60
constexpr int cITERS = 4;                  // setup_inputs fixed

// ---------------------------------------------------------------------------
// helpers
// ---------------------------------------------------------------------------
__device__ __forceinline__ float bilin_hwc(const float* __restrict__ fm, int Hh, int Ww,
                                           float x, float y, int c) {
  x = fminf(fmaxf(x, -2.0e6f), 2.0e6f);
  y = fminf(fmaxf(y, -2.0e6f), 2.0e6f);
  float x0f = floorf(x), y0f = floorf(y);
  int ix = (int)x0f, iy = (int)y0f;
  float wx = x - x0f, wy = y - y0f;
  float acc = 0.f;
  bool vx0 = (ix >= 0) && (ix <= Ww - 1);
  bool vx1 = (ix + 1 >= 0) && (ix + 1 <= Ww - 1);
  bool vy0 = (iy >= 0) && (iy <= Hh - 1);
  bool vy1 = (iy + 1 >= 0) && (iy + 1 <= Hh - 1);
  if (vy0 && vx0) acc += fm[(iy * Ww + ix) * cC + c] * (1.f - wy) * (1.f - wx);
  if (vy0 && vx1) acc += fm[(iy * Ww + ix + 1) * cC + c] * (1.f - wy) * wx;
  if (vy1 && vx0) acc += fm[((iy + 1) * Ww + ix) * cC + c] * wy * (1.f - wx);
  if (vy1 && vx1) acc += fm[((iy + 1) * Ww + ix + 1) * cC + c] * wy * wx;
  return acc;
}

// ---------------------------------------------------------------------------
// frame_flow: ff[s] = (s==0 ? norm(rgb[15]) : norm(rgb[s])-norm(rgb[s-1]))
// downsampled 200x240 -> 50x60 (align_corners=False, exact half-pixel: avg of
// 2x2 center block at rows 4o+1,4o+2 / cols 4p+1,4p+2)
// ---------------------------------------------------------------------------
__global__ void k_ff(const float* __restrict__ rgbs, float* __restrict__ ff) {
  int s = blockIdx.x;
  const float a = 2.0f / 255.0f;
  const float* cur = rgbs + (size_t)s * cH * cW;
  const float* prev = rgbs + (size_t)(s - 1) * cH * cW;
  const float* last = rgbs + (size_t)15 * cH * cW;
  for (int i = threadIdx.x; i < cFF; i += blockDim.x) {
    int o = i / 60, p = i % 60;
    int y = 4 * o + 1, x = 4 * p + 1;
    float v = 0.f;
    #pragma unroll
    for (int dy = 0; dy < 2; dy++)
      #pragma unroll
      for (int dx = 0; dx < 2; dx++) {
        int id = (y + dy) * cW + (x + dx);
        float pv = (s == 0) ? (a * last[id] - 1.0f) : (a * (cur[id] - prev[id]));
        v += pv;
      }
    ff[s * cFF + i] = 0.25f * v;
  }
}

// ffw[s][j] = sum_i ff[s][i] * w1[(off+i)*128 + j]
__global__ void k_ffw(const float* __restrict__ ff, const float* __restrict__ w1,
                      int off, float* __restrict__ out) {
  int s = blockIdx.x, j = threadIdx.x;
  const float* f = ff + s * cFF;
  float acc = 0.f;
  for (int i = 0; i < cFF; i++) acc += f[i] * w1[(size_t)(off + i) * 128 + j];
  out[s * 128 + j] = acc;
}

// LWc[k][j] = sum_m linear_w[k][m] * dbt_w1[m][j];  block 588: b1te = dbt_b1 + lb @ W1[0:392]
__global__ void k_lwc(const float* __restrict__ lw, const float* __restrict__ lb,
                      const float* __restrict__ w1t, const float* __restrict__ b1t,
                      float* __restrict__ LWc, float* __restrict__ b1te) {
  int k = blockIdx.x, j = threadIdx.x;
  if (k < 588) {
    float acc = 0.f;
    for (int m = 0; m < 392; m++) acc += lw[(size_t)k * 392 + m] * w1t[(size_t)m * 128 + j];
    LWc[(size_t)k * 128 + j] = acc;
  } else {
    float acc = b1t[j];
    for (int m = 0; m < 392; m++) acc += lb[m] * w1t[(size_t)m * 128 + j];
    b1te[j] = acc;
  }
}

// ---------------------------------------------------------------------------
// coarse encoder: conv 8x8 stride 8 + instance norm, output HWC [16][750][64]
// block = (q, c)
// ---------------------------------------------------------------------------
__global__ __launch_bounds__(256) void k_convc(const float* __restrict__ rgbs,
                                               const float* __restrict__ wc,
                                               float* __restrict__ fm) {
  int q = blockIdx.x, c = blockIdx.y;
  int tid = threadIdx.x;
  __shared__ float wl[64];
  __shared__ float red[256];
  if (tid < 64) wl[tid] = wc[c * 64 + tid];
  __syncthreads();
  const float a = 2.0f / 255.0f;
  const float* img = rgbs + (size_t)q * cH * cW;
  float vals[3];
  float sum = 0.f, ss = 0.f;
  #pragma unroll
  for (int i = 0; i < 3; i++) {
    int pos = tid + i * 256;
    float v = 0.f;
    if (pos < 750) {
      int y = pos / cWC, x = pos % cWC;
      const float* base = img + (y * 8) * cW + x * 8;
      float acc = 0.f, wsum = 0.f;
      for (int ky = 0; ky < 8; ky++)
        #pragma unroll
        for (int kx = 0; kx < 8; kx++) {
          float wv = wl[ky * 8 + kx];
          acc += wv * base[ky * cW + kx];
          wsum += wv;
        }
      v = a * acc - wsum;  // b = -1 folded: conv(2p/255 - 1)
      sum += v; ss += v * v;
    }
    vals[i] = v;
  }
  red[tid] = sum; __syncthreads();
  for (int st = 128; st > 0; st >>= 1) { if (tid < st) red[tid] += red[tid + st]; __syncthreads(); }
  float tsum = red[0]; __syncthreads();
  red[tid] = ss; __syncthreads();
  for (int st = 128; st > 0; st >>= 1) { if (tid < st) red[tid] += red[tid + st]; __syncthreads(); }
  float tss = red[0];
  float mean = tsum / 750.0f;
  float var = tss / 750.0f - mean * mean;
  float rstd = rsqrtf(var + 1e-5f);
  #pragma unroll
  for (int i = 0; i < 3; i++) {
    int pos = tid + i * 256;
    if (pos < 750) fm[((size_t)q * 750 + pos) * cC + c] = (vals[i] - mean) * rstd;
  }
}

// ---------------------------------------------------------------------------
// fine encoder: conv 2x2 stride 2, HWC raw output + per-(q,c) sum/sumsq atomics
// block = (q, y)
// ---------------------------------------------------------------------------
__global__ __launch_bounds__(256) void k_convf(const float* __restrict__ rgbs,
                                               const float* __restrict__ wf,
                                               float* __restrict__ fm,
                                               float* __restrict__ stats) {
  int q = blockIdx.x, y = blockIdx.y;
  int lane = threadIdx.x & 63, wv = threadIdx.x >> 6;
  float w0 = wf[lane * 4 + 0], w1 = wf[lane * 4 + 1], w2 = wf[lane * 4 + 2], w3 = wf[lane * 4 + 3];
  float wsum = w0 + w1 + w2 + w3;
  const float a = 2.0f / 255.0f;
  const float* img = rgbs + (size_t)q * cH * cW;
  float sum = 0.f, ss = 0.f;
  for (int x = wv; x < cWF; x += 4) {
    const float* b = img + (2 * y) * cW + 2 * x;
    float v = a * (w0 * b[0] + w1 * b[1] + w2 * b[cW] + w3 * b[cW + 1]) - wsum;
    fm[(((size_t)q * cHF + y) * cWF + x) * cC + lane] = v;
    sum += v; ss += v * v;
  }
  __shared__ float red[2][4][64];
  red[0][wv][lane] = sum; red[1][wv][lane] = ss;
  __syncthreads();
  if (wv == 0) {
    float s4 = red[0][0][lane] + red[0][1][lane] + red[0][2][lane] + red[0][3][lane];
    float q4 = red[1][0][lane] + red[1][1][lane] + red[1][2][lane] + red[1][3][lane];
    atomicAdd(&stats[(q * 64 + lane) * 2 + 0], s4);
    atomicAdd(&stats[(q * 64 + lane) * 2 + 1], q4);
  }
}

__global__ void k_normf(float* __restrict__ fm, const float* __restrict__ stats) {
  const int total = 16 * cHF * cWF * cC;
  for (int i = blockIdx.x * blockDim.x + threadIdx.x; i < total; i += gridDim.x * blockDim.x) {
    int c = i & 63;
    int q = i / (cHF * cWF * cC);
    float s = stats[(q * 64 + c) * 2 + 0];
    float qq = stats[(q * 64 + c) * 2 + 1];
    float mean = s / 12000.0f;
    float var = qq / 12000.0f - mean * mean;
    fm[i] = (fm[i] - mean) * rsqrtf(var + 1e-5f);
  }
}

// generic 2x2 avg pool, HWC. block = (q, oy)
__global__ void k_pool(const float* __restrict__ in, float* __restrict__ out,
                       int IH, int IW, int OH, int OW) {
  int q = blockIdx.x, oy = blockIdx.y;
  int items = OW * cC;
  for (int i = threadIdx.x; i < items; i += blockDim.x) {
    int ox = i >> 6, c = i & 63;
    const float* b = in + (((size_t)q * IH + 2 * oy) * IW + 2 * ox) * cC + c;
    out[(((size_t)q * OH + oy) * OW + ox) * cC + c] =
        0.25f * (b[0] + b[cC] + b[(size_t)IW * cC] + b[(size_t)IW * cC + cC]);
  }
}

// averaged-resized coarse pyramid: arp[q][o][p][c] = 0.25*0.125 * sum_l bilin_l(o,p)
__global__ __launch_bounds__(256) void k_arp(const float* __restrict__ l0, const float* __restrict__ l1,
                                             const float* __restrict__ l2, const float* __restrict__ l3,
                                             float* __restrict__ arp) {
  int q = blockIdx.x, o = blockIdx.y;
  int lane = threadIdx.x & 63, wv = threadIdx.x >> 6;
  const float* Ls[4] = {l0, l1, l2, l3};
  const int Hs[4] = {25, 12, 6, 3}, Ws[4] = {30, 15, 7, 3};
  for (int p = wv; p < 14; p += 4) {
    float acc = 0.f;
    #pragma unroll
    for (int l = 0; l < 4; l++) {
      float yy = (float)(o * (Hs[l] - 1)) / 13.0f;
      float xx = (float)(p * (Ws[l] - 1)) / 13.0f;
      int y0 = (int)floorf(yy); int y1 = min(y0 + 1, Hs[l] - 1); float wy = yy - (float)y0;
      int x0 = (int)floorf(xx); int x1 = min(x0 + 1, Ws[l] - 1); float wx = xx - (float)x0;
      const float* L = Ls[l] + (size_t)q * Hs[l] * Ws[l] * cC;
      float v00 = L[(y0 * Ws[l] + x0) * cC + lane], v01 = L[(y0 * Ws[l] + x1) * cC + lane];
      float v10 = L[(y1 * Ws[l] + x0) * cC + lane], v11 = L[(y1 * Ws[l] + x1) * cC + lane];
      acc += (v00 * (1.f - wy) + v10 * wy) * (1.f - wx) + (v01 * (1.f - wy) + v11 * wy) * wx;
    }
    arp[((size_t)q * 196 + (o * 14 + p)) * cC + lane] = acc * 0.25f * 0.125f;
  }
}

// coords_c[s][n] = points_0[n] / 8
__global__ void k_initc(const float* __restrict__ pts, float* __restrict__ coords_c) {
  for (int idx = threadIdx.x; idx < cS * cN; idx += blockDim.x) {
    int n = idx & 63;
    coords_c[idx * 2 + 0] = pts[n * 2 + 0] * 0.125f;
    coords_c[idx * 2 + 1] = pts[n * 2 + 1] * 0.125f;
  }
}

// sample frame-0 features at per-point coords (psrc[n*2+{0,1}] * scale)
__global__ void k_sample_f0(const float* __restrict__ fm, int Hh, int Ww,
                            const float* __restrict__ psrc, float scale,
                            float* __restrict__ out, float* __restrict__ xys) {
  int n = blockIdx.x, c = threadIdx.x;
  float x = psrc[n * 2 + 0] * scale, y = psrc[n * 2 + 1] * scale;
  out[n * cC + c] = bilin_hwc(fm, Hh, Ww, x, y, c);
  if (xys && c < 2) xys[n * 2 + c] = (c == 0) ? x : y;
}

// shifted feats: feats_t[s][n][c] = bilin(fmaps[max(s-shift,0)], coords[max(s-shift,0)][n])
__global__ void k_feats(const float* __restrict__ fm, const float* __restrict__ coords,
                        float* __restrict__ f2, float* __restrict__ f4) {
  int n = blockIdx.x, s = blockIdx.y, t = blockIdx.z;
  int shift = (t == 0) ? 2 : 4;
  int ssrc = max(s - shift, 0);
  int c = threadIdx.x;
  float x = coords[(ssrc * cN + n) * 2 + 0];
  float y = coords[(ssrc * cN + n) * 2 + 1];
  float v = bilin_hwc(fm + (size_t)ssrc * cHF * cWF * cC, cHF, cWF, x, y, c);
  float* dst = (t == 0) ? f2 : f4;
  dst[((size_t)s * cN + n) * cC + c] = v;
}

// fused corr + window-sample. block=(n,s,t), 4 waves = 4 pyramid levels.
// each lane owns one of the 8x8 integer grid points; D via dot(feat, pyr); then
// 49 bilinear combos via shuffles.
__global__ __launch_bounds__(256) void k_corr(const float* __restrict__ p0, const float* __restrict__ p1,
                                              const float* __restrict__ p2, const float* __restrict__ p3,
                                              const float* __restrict__ f0, const float* __restrict__ f2,
                                              const float* __restrict__ f4, const float* __restrict__ coords,
                                              float* __restrict__ fco) {
  int n = blockIdx.x, s = blockIdx.y, t = blockIdx.z;
  __shared__ float feat[64];
  int tid = threadIdx.x;
  if (tid < 64) {
    const float* fs = (t == 0) ? (f0 + (size_t)n * cC)
                               : ((t == 1) ? (f2 + ((size_t)s * cN + n) * cC)
                                           : (f4 + ((size_t)s * cN + n) * cC));
    feat[tid] = fs[tid];
  }
  __syncthreads();
  int l = tid >> 6, lane = tid & 63;
  const float* Ls[4] = {p0, p1, p2, p3};
  const int Hs[4] = {cHF, 50, 25, 12}, Ws[4] = {cWF, 60, 30, 15};
  float cx = coords[((size_t)s * cN + n) * 2 + 0];
  float cy = coords[((size_t)s * cN + n) * 2 + 1];
  float sc = 1.0f / (float)(1 << l);
  float x = fminf(fmaxf(cx * sc, -2.0e6f), 2.0e6f);
  float y = fminf(fmaxf(cy * sc, -2.0e6f), 2.0e6f);
  float x0f = floorf(x), y0f = floorf(y);
  float wx = x - x0f, wy = y - y0f;
  int dxi = lane & 7, dyi = lane >> 3;
  int ix = (int)x0f + dxi - 3, iy = (int)y0f + dyi - 3;
  int Hl = Hs[l], Wl = Ws[l];
  float d = 0.f;
  if (ix >= 0 && ix < Wl && iy >= 0 && iy < Hl) {
    const float4* b4 = (const float4*)(Ls[l] + (((size_t)s * Hl + iy) * Wl + ix) * cC);
    float acc = 0.f;
    #pragma unroll
    for (int c4 = 0; c4 < 16; c4++) {
      float4 v = b4[c4];
      acc += v.x * feat[c4 * 4 + 0] + v.y * feat[c4 * 4 + 1] +
             v.z * feat[c4 * 4 + 2] + v.w * feat[c4 * 4 + 3];
    }
    d = acc * 0.125f;  // 1/sqrt(64)
  }
  int dy = lane / 7, dx = lane - dy * 7;
  int bb = (lane < 49) ? (dy * 8 + dx) : 0;
  float d00 = __shfl(d, bb, 64);
  float d01 = __shfl(d, bb + 1, 64);
  float d10 = __shfl(d, bb + 8, 64);
  float d11 = __shfl(d, bb + 9, 64);
  if (lane < 49) {
    float v = (1.f - wy) * ((1.f - wx) * d00 + wx * d01) + wy * ((1.f - wx) * d10 + wx * d11);
    fco[((size_t)n * cS + s) * 588 + t * 196 + l * 49 + lane] = v;
  }
}

// ---------------------------------------------------------------------------
// MLP delta blocks. Each block: 4 rows (same n, s = sb..sb+3), 128 threads (j).
// ---------------------------------------------------------------------------
__global__ __launch_bounds__(128) void k_mlp_coarse(const float* __restrict__ arp, const float* __restrict__ f0c,
                                                    const float* __restrict__ w1, const float* __restrict__ b1,
                                                    const float* __restrict__ ffw, const float* __restrict__ w2,
                                                    const float* __restrict__ b2, const float* __restrict__ coords,
                                                    const float* __restrict__ pts, float* __restrict__ delta) {
  int n = blockIdx.x >> 2, sb = (blockIdx.x & 3) * 4;
  __shared__ float fc[4][196];
  __shared__ float f0l[64];
  __shared__ float hl[4][128];
  int j = threadIdx.x;
  if (j < 64) f0l[j] = f0c[n * cC + j];
  __syncthreads();
  #pragma unroll
  for (int r = 0; r < 4; r++) {
    int s = sb + r;
    for (int k = j; k < 196; k += 128) {
      const float4* b4 = (const float4*)(arp + ((size_t)s * 196 + k) * cC);
      float acc = 0.f;
      #pragma unroll
      for (int c4 = 0; c4 < 16; c4++) {
        float4 v = b4[c4];
        acc += v.x * f0l[c4 * 4 + 0] + v.y * f0l[c4 * 4 + 1] +
               v.z * f0l[c4 * 4 + 2] + v.w * f0l[c4 * 4 + 3];
      }
      fc[r][k] = acc;
    }
  }
  __syncthreads();
  float h0 = 0.f, h1 = 0.f, h2 = 0.f, h3 = 0.f;
  for (int k = 0; k < 196; k++) {
    float wv = w1[(size_t)k * 128 + j];
    h0 += fc[0][k] * wv; h1 += fc[1][k] * wv; h2 += fc[2][k] * wv; h3 += fc[3][k] * wv;
  }
  float hh[4] = {h0, h1, h2, h3};
  const float* Wfl = w1 + (size_t)196 * 128;
  const float* Wxy = w1 + (size_t)3198 * 128;
  float xx = pts[n * 2 + 0] * 0.125f, yy = pts[n * 2 + 1] * 0.125f;
  #pragma unroll
  for (int r = 0; r < 4; r++) {
    int s = sb + r;
    int sA = min(s + 1, 15), sB = (s == 15) ? 14 : s;
    float flx = coords[(sA * cN + n) * 2 + 0] - coords[(sB * cN + n) * 2 + 0];
    float fly = coords[(sA * cN + n) * 2 + 1] - coords[(sB * cN + n) * 2 + 1];
    float v = hh[r] + b1[j] + ffw[s * 128 + j] + flx * Wfl[j] + fly * Wfl[128 + j] +
              xx * Wxy[j] + yy * Wxy[128 + j];
    hl[r][j] = fmaxf(v, 0.f);
  }
  __syncthreads();
  if (j < 8) {
    int r = j >> 1, d = j & 1;
    float acc = b2[d];
    for (int k = 0; k < 128; k++) acc += hl[r][k] * w2[k * 2 + d];
    delta[((size_t)n * cS + sb + r) * 2 + d] = acc;
  }
}

__global__ __launch_bounds__(128) void k_mlp_fine(const float* __restrict__ fco, const float* __restrict__ LWc,
                                                  const float* __restrict__ b1e, const float* __restrict__ ffw,
                                                  const float* __restrict__ w1t, const float* __restrict__ w2,
                                                  const float* __restrict__ b2, const float* __restrict__ coords,
                                                  const float* __restrict__ xys, float* __restrict__ delta) {
  int n = blockIdx.x >> 2, sb = (blockIdx.x & 3) * 4;
  __shared__ float fc[4][588];
  __shared__ float hl[4][128];
  int j = threadIdx.x;
  #pragma unroll
  for (int r = 0; r < 4; r++)
    for (int k = j; k < 588; k += 128) fc[r][k] = fco[((size_t)n * cS + sb + r) * 588 + k];
  __syncthreads();
  float h0 = 0.f, h1 = 0.f, h2 = 0.f, h3 = 0.f;
  for (int k = 0; k < 588; k++) {
    float wv = LWc[(size_t)k * 128 + j];
    h0 += fc[0][k] * wv; h1 += fc[1][k] * wv; h2 += fc[2][k] * wv; h3 += fc[3][k] * wv;
  }
  float hh[4] = {h0, h1, h2, h3};
  const float* Wfl = w1t + (size_t)392 * 128;
  const float* Wxy = w1t + (size_t)3394 * 128;
  float xx = xys[n * 2 + 0], yy = xys[n * 2 + 1];
  #pragma unroll
  for (int r = 0; r < 4; r++) {
    int s = sb + r;
    int sA = min(s + 1, 15), sB = (s == 15) ? 14 : s;
    float flx = coords[(sA * cN + n) * 2 + 0] - coords[(sB * cN + n) * 2 + 0];
    float fly = coords[(sA * cN + n) * 2 + 1] - coords[(sB * cN + n) * 2 + 1];
    float v = hh[r] + b1e[j] + ffw[s * 128 + j] + flx * Wfl[j] + fly * Wfl[128 + j] +
              xx * Wxy[j] + yy * Wxy[128 + j];
    hl[r][j] = fmaxf(v, 0.f);
  }
  __syncthreads();
  if (j < 8) {
    int r = j >> 1, d = j & 1;
    float acc = b2[d];
    for (int k = 0; k < 128; k++) acc += hl[r][k] * w2[k * 2 + d];
    delta[((size_t)n * cS + sb + r) * 2 + d] = acc;
  }
}

// coarse update: coords_c += delta; preds[0] = 8*coords_c; coords_f = 4*coords_c
__global__ void k_updc(const float* __restrict__ delta, float* __restrict__ coords_c,
                       float* __restrict__ coords_f, float* __restrict__ out) {
  for (int idx = threadIdx.x; idx < cS * cN; idx += blockDim.x) {
    int s = idx >> 6, n = idx & 63;
    float cx = coords_c[idx * 2 + 0] + delta[((size_t)n * cS + s) * 2 + 0];
    float cy = coords_c[idx * 2 + 1] + delta[((size_t)n * cS + s) * 2 + 1];
    coords_c[idx * 2 + 0] = cx; coords_c[idx * 2 + 1] = cy;
    out[idx * 2 + 0] = cx * 8.0f; out[idx * 2 + 1] = cy * 8.0f;
    coords_f[idx * 2 + 0] = cx * 4.0f; coords_f[idx * 2 + 1] = cy * 4.0f;
  }
}

// fine update: coords_f += delta; preds[it+1] = 2*coords_f
__global__ void k_updf(const float* __restrict__ delta, float* __restrict__ coords_f,
                       float* __restrict__ out) {
  for (int idx = threadIdx.x; idx < cS * cN; idx += blockDim.x) {
    int s = idx >> 6, n = idx & 63;
    float cx = coords_f[idx * 2 + 0] + delta[((size_t)n * cS + s) * 2 + 0];
    float cy = coords_f[idx * 2 + 1] + delta[((size_t)n * cS + s) * 2 + 1];
    coords_f[idx * 2 + 0] = cx; coords_f[idx * 2 + 1] = cy;
    out[idx * 2 + 0] = cx * 2.0f; out[idx * 2 + 1] = cy * 2.0f;
  }
}

// ---------------------------------------------------------------------------
extern "C" void kernel_launch(void* const* d_in, const int* in_sizes, int n_in,
                              void* d_out, int out_size, void* d_ws, size_t ws_size,
                              hipStream_t stream) {
  (void)in_sizes; (void)n_in; (void)out_size; (void)ws_size;
  const float* rgbs = (const float*)d_in[0];
  const float* pts  = (const float*)d_in[1];
  const float* fnw  = (const float*)d_in[2];
  const float* fnfw = (const float*)d_in[3];
  const float* lw   = (const float*)d_in[4];
  const float* lb   = (const float*)d_in[5];
  const float* w1s  = (const float*)d_in[6];
  const float* b1s  = (const float*)d_in[7];
  const float* w2s  = (const float*)d_in[8];
  const float* b2s  = (const float*)d_in[9];
  const float* w1t  = (const float*)d_in[10];
  const float* b1t  = (const float*)d_in[11];
  const float* w2t  = (const float*)d_in[12];
  const float* b2t  = (const float*)d_in[13];
  float* out = (float*)d_out;

  float* p = (float*)d_ws;
  auto alloc = [&](size_t nf) { float* r = p; p += nf; return r; };
  float* ff    = alloc((size_t)cS * cFF);
  float* ffw_s = alloc(cS * 128);
  float* ffw_t = alloc(cS * 128);
  float* LWc   = alloc((size_t)588 * 128);
  float* b1te  = alloc(128);
  float* fmc   = alloc((size_t)cS * cHC * cWC * cC);
  float* pc1   = alloc((size_t)cS * 12 * 15 * cC);
  float* pc2   = alloc((size_t)cS * 6 * 7 * cC);
  float* pc3   = alloc((size_t)cS * 3 * 3 * cC);
  float* arp   = alloc((size_t)cS * 196 * cC);
  float* f0c   = alloc((size_t)cN * cC);
  float* coc   = alloc((size_t)cS * cN * 2);
  float* fmf   = alloc((size_t)cS * cHF * cWF * cC);
  float* stats = alloc(cS * cC * 2);
  float* pf1   = alloc((size_t)cS * 50 * 60 * cC);
  float* pf2   = alloc((size_t)cS * 25 * 30 * cC);
  float* pf3   = alloc((size_t)cS * 12 * 15 * cC);
  float* f0f   = alloc((size_t)cN * cC);
  float* xys0  = alloc(cN * 2);
  float* cof   = alloc((size_t)cS * cN * 2);
  float* fe2   = alloc((size_t)cS * cN * cC);
  float* fe4   = alloc((size_t)cS * cN * cC);
  float* fco   = alloc((size_t)cN * cS * 588);
  float* dlt   = alloc((size_t)cS * cN * 2);

  // frame_flow + shared MLP precomputes
  k_ff<<<cS, 256, 0, stream>>>(rgbs, ff);
  k_ffw<<<cS, 128, 0, stream>>>(ff, w1s, 198, ffw_s);
  k_ffw<<<cS, 128, 0, stream>>>(ff, w1t, 394, ffw_t);
  k_lwc<<<589, 128, 0, stream>>>(lw, lb, w1t, b1t, LWc, b1te);

  // ---- coarse stage ----
  k_convc<<<dim3(cS, cC), 256, 0, stream>>>(rgbs, fnw, fmc);
  k_pool<<<dim3(cS, 12), 256, 0, stream>>>(fmc, pc1, 25, 30, 12, 15);
  k_pool<<<dim3(cS, 6), 256, 0, stream>>>(pc1, pc2, 12, 15, 6, 7);
  k_pool<<<dim3(cS, 3), 256, 0, stream>>>(pc2, pc3, 6, 7, 3, 3);
  k_arp<<<dim3(cS, 14), 256, 0, stream>>>(fmc, pc1, pc2, pc3, arp);
  k_initc<<<1, 256, 0, stream>>>(pts, coc);
  k_sample_f0<<<cN, 64, 0, stream>>>(fmc, cHC, cWC, pts, 0.125f, f0c, nullptr);
  k_mlp_coarse<<<256, 128, 0, stream>>>(arp, f0c, w1s, b1s, ffw_s, w2s, b2s, coc, pts, dlt);
  k_updc<<<1, 256, 0, stream>>>(dlt, coc, cof, out);  // preds[0]

  // ---- fine stage ----
  hipMemsetAsync(stats, 0, (size_t)cS * cC * 2 * sizeof(float), stream);
  k_convf<<<dim3(cS, cHF), 256, 0, stream>>>(rgbs, fnfw, fmf, stats);
  k_normf<<<2048, 256, 0, stream>>>(fmf, stats);
  k_pool<<<dim3(cS, 50), 256, 0, stream>>>(fmf, pf1, 100, 120, 50, 60);
  k_pool<<<dim3(cS, 25), 256, 0, stream>>>(pf1, pf2, 50, 60, 25, 30);
  k_pool<<<dim3(cS, 12), 256, 0, stream>>>(pf2, pf3, 25, 30, 12, 15);
  k_sample_f0<<<cN, 64, 0, stream>>>(fmf, cHF, cWF, cof, 1.0f, f0f, xys0);

  for (int it = 0; it < cITERS; it++) {
    k_feats<<<dim3(cN, cS, 2), 64, 0, stream>>>(fmf, cof, fe2, fe4);
    k_corr<<<dim3(cN, cS, 3), 256, 0, stream>>>(fmf, pf1, pf2, pf3, f0f, fe2, fe4, cof, fco);
    k_mlp_fine<<<256, 128, 0, stream>>>(fco, LWc, b1te, ffw_t, w1t, w2t, b2t, cof, xys0, dlt);
    k_updf<<<1, 256, 0, stream>>>(dlt, cof, out + (size_t)(it + 1) * cS * cN * 2);
  }
}

// Round 2
// 497.607 us; speedup vs baseline: 1.3783x; 1.3783x over previous
//
#include <hip/hip_runtime.h>

// ---- problem constants (from reference setup_inputs) ----
constexpr int cS = 16, cN = 64, cH = 200, cW = 240;
constexpr int cHC = 25, cWC = 30;          // coarse fmap (stride 8)
constexpr int cHF = 100, cWF = 120;        // fine fmap (stride 2)
constexpr int cC = 64;                     // LAT
constexpr int cFF = 3000;                  // 50*60
constexpr int cITERS = 4;                  // setup_inputs fixed
constexpr int cCHUNK = 60, cNCH = 50;      // ffw split

// ---------------------------------------------------------------------------
// helpers
// ---------------------------------------------------------------------------
__device__ __forceinline__ float bilin_hwc(const float* __restrict__ fm, int Hh, int Ww,
                                           float x, float y, int c) {
  x = fminf(fmaxf(x, -2.0e6f), 2.0e6f);
  y = fminf(fmaxf(y, -2.0e6f), 2.0e6f);
  float x0f = floorf(x), y0f = floorf(y);
  int ix = (int)x0f, iy = (int)y0f;
  float wx = x - x0f, wy = y - y0f;
  float acc = 0.f;
  bool vx0 = (ix >= 0) && (ix <= Ww - 1);
  bool vx1 = (ix + 1 >= 0) && (ix + 1 <= Ww - 1);
  bool vy0 = (iy >= 0) && (iy <= Hh - 1);
  bool vy1 = (iy + 1 >= 0) && (iy + 1 <= Hh - 1);
  if (vy0 && vx0) acc += fm[(iy * Ww + ix) * cC + c] * (1.f - wy) * (1.f - wx);
  if (vy0 && vx1) acc += fm[(iy * Ww + ix + 1) * cC + c] * (1.f - wy) * wx;
  if (vy1 && vx0) acc += fm[((iy + 1) * Ww + ix) * cC + c] * wy * (1.f - wx);
  if (vy1 && vx1) acc += fm[((iy + 1) * Ww + ix + 1) * cC + c] * wy * wx;
  return acc;
}

// ---------------------------------------------------------------------------
// frame_flow: ff[s] = (s==0 ? norm(rgb[15]) : norm(rgb[s])-norm(rgb[s-1]))
// downsampled 200x240 -> 50x60 (align_corners=False, exact half-pixel: avg of
// 2x2 center block at rows 4o+1,4o+2 / cols 4p+1,4p+2)
// ---------------------------------------------------------------------------
__global__ void k_ff(const float* __restrict__ rgbs, float* __restrict__ ff) {
  int s = blockIdx.x;
  const float a = 2.0f / 255.0f;
  const float* cur = rgbs + (size_t)s * cH * cW;
  const float* prev = rgbs + (size_t)(s - 1) * cH * cW;
  const float* last = rgbs + (size_t)15 * cH * cW;
  for (int i = threadIdx.x; i < cFF; i += blockDim.x) {
    int o = i / 60, p = i % 60;
    int y = 4 * o + 1, x = 4 * p + 1;
    float v = 0.f;
    #pragma unroll
    for (int dy = 0; dy < 2; dy++)
      #pragma unroll
      for (int dx = 0; dx < 2; dx++) {
        int id = (y + dy) * cW + (x + dx);
        float pv = (s == 0) ? (a * last[id] - 1.0f) : (a * (cur[id] - prev[id]));
        v += pv;
      }
    ff[s * cFF + i] = 0.25f * v;
  }
}

// split ffw GEMV: part[t][s][ch][j] = sum_{i in chunk} ff[s][i] * w1[(off+i)*128+j]
__global__ __launch_bounds__(128) void k_ffw_part(const float* __restrict__ ff,
                                                  const float* __restrict__ w1s,
                                                  const float* __restrict__ w1t,
                                                  float* __restrict__ part) {
  int s = blockIdx.x, ch = blockIdx.y, t = blockIdx.z;
  int j = threadIdx.x;
  const float* w = (t == 0) ? (w1s + (size_t)198 * 128) : (w1t + (size_t)394 * 128);
  const float* f = ff + s * cFF + ch * cCHUNK;
  const float* wr = w + (size_t)ch * cCHUNK * 128 + j;
  float acc = 0.f;
  #pragma unroll 4
  for (int i = 0; i < cCHUNK; i++) acc += f[i] * wr[(size_t)i * 128];
  part[(((size_t)t * cS + s) * cNCH + ch) * 128 + j] = acc;
}

__global__ void k_ffw_red(const float* __restrict__ part, float* __restrict__ ffw_s,
                          float* __restrict__ ffw_t) {
  int s = blockIdx.x, t = blockIdx.y, j = threadIdx.x;
  const float* p = part + (((size_t)t * cS + s) * cNCH) * 128 + j;
  float acc = 0.f;
  for (int c = 0; c < cNCH; c++) acc += p[(size_t)c * 128];
  ((t == 0) ? ffw_s : ffw_t)[s * 128 + j] = acc;
}

// LWc[k][j] = sum_m linear_w[k][m] * dbt_w1[m][j];  block 588: b1te = dbt_b1 + lb @ W1[0:392]
__global__ void k_lwc(const float* __restrict__ lw, const float* __restrict__ lb,
                      const float* __restrict__ w1t, const float* __restrict__ b1t,
                      float* __restrict__ LWc, float* __restrict__ b1te) {
  int k = blockIdx.x, j = threadIdx.x;
  if (k < 588) {
    float acc = 0.f;
    for (int m = 0; m < 392; m++) acc += lw[(size_t)k * 392 + m] * w1t[(size_t)m * 128 + j];
    LWc[(size_t)k * 128 + j] = acc;
  } else {
    float acc = b1t[j];
    for (int m = 0; m < 392; m++) acc += lb[m] * w1t[(size_t)m * 128 + j];
    b1te[j] = acc;
  }
}

// ---------------------------------------------------------------------------
// coarse encoder: conv 8x8 stride 8 + instance norm, output HWC [16][750][64]
// block = (q, c)
// ---------------------------------------------------------------------------
__global__ __launch_bounds__(256) void k_convc(const float* __restrict__ rgbs,
                                               const float* __restrict__ wc,
                                               float* __restrict__ fm) {
  int q = blockIdx.x, c = blockIdx.y;
  int tid = threadIdx.x;
  __shared__ float wl[64];
  __shared__ float red[256];
  if (tid < 64) wl[tid] = wc[c * 64 + tid];
  __syncthreads();
  const float a = 2.0f / 255.0f;
  const float* img = rgbs + (size_t)q * cH * cW;
  float vals[3];
  float sum = 0.f, ss = 0.f;
  #pragma unroll
  for (int i = 0; i < 3; i++) {
    int pos = tid + i * 256;
    float v = 0.f;
    if (pos < 750) {
      int y = pos / cWC, x = pos % cWC;
      const float* base = img + (y * 8) * cW + x * 8;
      float acc = 0.f, wsum = 0.f;
      for (int ky = 0; ky < 8; ky++)
        #pragma unroll
        for (int kx = 0; kx < 8; kx++) {
          float wv = wl[ky * 8 + kx];
          acc += wv * base[ky * cW + kx];
          wsum += wv;
        }
      v = a * acc - wsum;  // b = -1 folded: conv(2p/255 - 1)
      sum += v; ss += v * v;
    }
    vals[i] = v;
  }
  red[tid] = sum; __syncthreads();
  for (int st = 128; st > 0; st >>= 1) { if (tid < st) red[tid] += red[tid + st]; __syncthreads(); }
  float tsum = red[0]; __syncthreads();
  red[tid] = ss; __syncthreads();
  for (int st = 128; st > 0; st >>= 1) { if (tid < st) red[tid] += red[tid + st]; __syncthreads(); }
  float tss = red[0];
  float mean = tsum / 750.0f;
  float var = tss / 750.0f - mean * mean;
  float rstd = rsqrtf(var + 1e-5f);
  #pragma unroll
  for (int i = 0; i < 3; i++) {
    int pos = tid + i * 256;
    if (pos < 750) fm[((size_t)q * 750 + pos) * cC + c] = (vals[i] - mean) * rstd;
  }
}

// ---------------------------------------------------------------------------
// fine encoder: conv 2x2 stride 2, HWC raw output + per-(q,c) sum/sumsq atomics
// block = (q, y)
// ---------------------------------------------------------------------------
__global__ __launch_bounds__(256) void k_convf(const float* __restrict__ rgbs,
                                               const float* __restrict__ wf,
                                               float* __restrict__ fm,
                                               float* __restrict__ stats) {
  int q = blockIdx.x, y = blockIdx.y;
  int lane = threadIdx.x & 63, wv = threadIdx.x >> 6;
  float w0 = wf[lane * 4 + 0], w1 = wf[lane * 4 + 1], w2 = wf[lane * 4 + 2], w3 = wf[lane * 4 + 3];
  float wsum = w0 + w1 + w2 + w3;
  const float a = 2.0f / 255.0f;
  const float* img = rgbs + (size_t)q * cH * cW;
  float sum = 0.f, ss = 0.f;
  for (int x = wv; x < cWF; x += 4) {
    const float* b = img + (2 * y) * cW + 2 * x;
    float v = a * (w0 * b[0] + w1 * b[1] + w2 * b[cW] + w3 * b[cW + 1]) - wsum;
    fm[(((size_t)q * cHF + y) * cWF + x) * cC + lane] = v;
    sum += v; ss += v * v;
  }
  __shared__ float red[2][4][64];
  red[0][wv][lane] = sum; red[1][wv][lane] = ss;
  __syncthreads();
  if (wv == 0) {
    float s4 = red[0][0][lane] + red[0][1][lane] + red[0][2][lane] + red[0][3][lane];
    float q4 = red[1][0][lane] + red[1][1][lane] + red[1][2][lane] + red[1][3][lane];
    atomicAdd(&stats[(q * 64 + lane) * 2 + 0], s4);
    atomicAdd(&stats[(q * 64 + lane) * 2 + 1], q4);
  }
}

__global__ void k_normf(float* __restrict__ fm, const float* __restrict__ stats) {
  const int total = 16 * cHF * cWF * cC;
  for (int i = blockIdx.x * blockDim.x + threadIdx.x; i < total; i += gridDim.x * blockDim.x) {
    int c = i & 63;
    int q = i / (cHF * cWF * cC);
    float s = stats[(q * 64 + c) * 2 + 0];
    float qq = stats[(q * 64 + c) * 2 + 1];
    float mean = s / 12000.0f;
    float var = qq / 12000.0f - mean * mean;
    fm[i] = (fm[i] - mean) * rsqrtf(var + 1e-5f);
  }
}

// generic 2x2 avg pool, HWC. block = (q, oy)
__global__ void k_pool(const float* __restrict__ in, float* __restrict__ out,
                       int IH, int IW, int OH, int OW) {
  int q = blockIdx.x, oy = blockIdx.y;
  int items = OW * cC;
  for (int i = threadIdx.x; i < items; i += blockDim.x) {
    int ox = i >> 6, c = i & 63;
    const float* b = in + (((size_t)q * IH + 2 * oy) * IW + 2 * ox) * cC + c;
    out[(((size_t)q * OH + oy) * OW + ox) * cC + c] =
        0.25f * (b[0] + b[cC] + b[(size_t)IW * cC] + b[(size_t)IW * cC + cC]);
  }
}

// averaged-resized coarse pyramid: arp[q][o][p][c] = 0.25*0.125 * sum_l bilin_l(o,p)
__global__ __launch_bounds__(256) void k_arp(const float* __restrict__ l0, const float* __restrict__ l1,
                                             const float* __restrict__ l2, const float* __restrict__ l3,
                                             float* __restrict__ arp) {
  int q = blockIdx.x, o = blockIdx.y;
  int lane = threadIdx.x & 63, wv = threadIdx.x >> 6;
  const float* Ls[4] = {l0, l1, l2, l3};
  const int Hs[4] = {25, 12, 6, 3}, Ws[4] = {30, 15, 7, 3};
  for (int p = wv; p < 14; p += 4) {
    float acc = 0.f;
    #pragma unroll
    for (int l = 0; l < 4; l++) {
      float yy = (float)(o * (Hs[l] - 1)) / 13.0f;
      float xx = (float)(p * (Ws[l] - 1)) / 13.0f;
      int y0 = (int)floorf(yy); int y1 = min(y0 + 1, Hs[l] - 1); float wy = yy - (float)y0;
      int x0 = (int)floorf(xx); int x1 = min(x0 + 1, Ws[l] - 1); float wx = xx - (float)x0;
      const float* L = Ls[l] + (size_t)q * Hs[l] * Ws[l] * cC;
      float v00 = L[(y0 * Ws[l] + x0) * cC + lane], v01 = L[(y0 * Ws[l] + x1) * cC + lane];
      float v10 = L[(y1 * Ws[l] + x0) * cC + lane], v11 = L[(y1 * Ws[l] + x1) * cC + lane];
      acc += (v00 * (1.f - wy) + v10 * wy) * (1.f - wx) + (v01 * (1.f - wy) + v11 * wy) * wx;
    }
    arp[((size_t)q * 196 + (o * 14 + p)) * cC + lane] = acc * 0.25f * 0.125f;
  }
}

// coords_c[s][n] = points_0[n] / 8
__global__ void k_initc(const float* __restrict__ pts, float* __restrict__ coords_c) {
  for (int idx = threadIdx.x; idx < cS * cN; idx += blockDim.x) {
    int n = idx & 63;
    coords_c[idx * 2 + 0] = pts[n * 2 + 0] * 0.125f;
    coords_c[idx * 2 + 1] = pts[n * 2 + 1] * 0.125f;
  }
}

// sample frame-0 features at per-point coords (psrc[n*2+{0,1}] * scale)
__global__ void k_sample_f0(const float* __restrict__ fm, int Hh, int Ww,
                            const float* __restrict__ psrc, float scale,
                            float* __restrict__ out, float* __restrict__ xys) {
  int n = blockIdx.x, c = threadIdx.x;
  float x = psrc[n * 2 + 0] * scale, y = psrc[n * 2 + 1] * scale;
  out[n * cC + c] = bilin_hwc(fm, Hh, Ww, x, y, c);
  if (xys && c < 2) xys[n * 2 + c] = (c == 0) ? x : y;
}

// shifted feats: feats_t[s][n][c] = bilin(fmaps[max(s-shift,0)], coords[max(s-shift,0)][n])
__global__ void k_feats(const float* __restrict__ fm, const float* __restrict__ coords,
                        float* __restrict__ f2, float* __restrict__ f4) {
  int n = blockIdx.x, s = blockIdx.y, t = blockIdx.z;
  int shift = (t == 0) ? 2 : 4;
  int ssrc = max(s - shift, 0);
  int c = threadIdx.x;
  float x = coords[(ssrc * cN + n) * 2 + 0];
  float y = coords[(ssrc * cN + n) * 2 + 1];
  float v = bilin_hwc(fm + (size_t)ssrc * cHF * cWF * cC, cHF, cWF, x, y, c);
  float* dst = (t == 0) ? f2 : f4;
  dst[((size_t)s * cN + n) * cC + c] = v;
}

// fused corr + window-sample. block=(n,s,t), 4 waves = 4 pyramid levels.
__global__ __launch_bounds__(256) void k_corr(const float* __restrict__ p0, const float* __restrict__ p1,
                                              const float* __restrict__ p2, const float* __restrict__ p3,
                                              const float* __restrict__ f0, const float* __restrict__ f2,
                                              const float* __restrict__ f4, const float* __restrict__ coords,
                                              float* __restrict__ fco) {
  int n = blockIdx.x, s = blockIdx.y, t = blockIdx.z;
  __shared__ float feat[64];
  int tid = threadIdx.x;
  if (tid < 64) {
    const float* fs = (t == 0) ? (f0 + (size_t)n * cC)
                               : ((t == 1) ? (f2 + ((size_t)s * cN + n) * cC)
                                           : (f4 + ((size_t)s * cN + n) * cC));
    feat[tid] = fs[tid];
  }
  __syncthreads();
  int l = tid >> 6, lane = tid & 63;
  const float* Ls[4] = {p0, p1, p2, p3};
  const int Hs[4] = {cHF, 50, 25, 12}, Ws[4] = {cWF, 60, 30, 15};
  float cx = coords[((size_t)s * cN + n) * 2 + 0];
  float cy = coords[((size_t)s * cN + n) * 2 + 1];
  float sc = 1.0f / (float)(1 << l);
  float x = fminf(fmaxf(cx * sc, -2.0e6f), 2.0e6f);
  float y = fminf(fmaxf(cy * sc, -2.0e6f), 2.0e6f);
  float x0f = floorf(x), y0f = floorf(y);
  float wx = x - x0f, wy = y - y0f;
  int dxi = lane & 7, dyi = lane >> 3;
  int ix = (int)x0f + dxi - 3, iy = (int)y0f + dyi - 3;
  int Hl = Hs[l], Wl = Ws[l];
  float d = 0.f;
  if (ix >= 0 && ix < Wl && iy >= 0 && iy < Hl) {
    const float4* b4 = (const float4*)(Ls[l] + (((size_t)s * Hl + iy) * Wl + ix) * cC);
    float acc = 0.f;
    #pragma unroll
    for (int c4 = 0; c4 < 16; c4++) {
      float4 v = b4[c4];
      acc += v.x * feat[c4 * 4 + 0] + v.y * feat[c4 * 4 + 1] +
             v.z * feat[c4 * 4 + 2] + v.w * feat[c4 * 4 + 3];
    }
    d = acc * 0.125f;  // 1/sqrt(64)
  }
  int dy = lane / 7, dx = lane - dy * 7;
  int bb = (lane < 49) ? (dy * 8 + dx) : 0;
  float d00 = __shfl(d, bb, 64);
  float d01 = __shfl(d, bb + 1, 64);
  float d10 = __shfl(d, bb + 8, 64);
  float d11 = __shfl(d, bb + 9, 64);
  if (lane < 49) {
    float v = (1.f - wy) * ((1.f - wx) * d00 + wx * d01) + wy * ((1.f - wx) * d10 + wx * d11);
    fco[((size_t)n * cS + s) * 588 + t * 196 + l * 49 + lane] = v;
  }
}

// ---------------------------------------------------------------------------
// MLP delta blocks. Each block: 4 rows (same n, s = sb..sb+3), 128 threads (j).
// ---------------------------------------------------------------------------
__global__ __launch_bounds__(128) void k_mlp_coarse(const float* __restrict__ arp, const float* __restrict__ f0c,
                                                    const float* __restrict__ w1, const float* __restrict__ b1,
                                                    const float* __restrict__ ffw, const float* __restrict__ w2,
                                                    const float* __restrict__ b2, const float* __restrict__ coords,
                                                    const float* __restrict__ pts, float* __restrict__ delta) {
  int n = blockIdx.x >> 2, sb = (blockIdx.x & 3) * 4;
  __shared__ float fc[4][196];
  __shared__ float f0l[64];
  __shared__ float hl[4][128];
  int j = threadIdx.x;
  if (j < 64) f0l[j] = f0c[n * cC + j];
  __syncthreads();
  #pragma unroll
  for (int r = 0; r < 4; r++) {
    int s = sb + r;
    for (int k = j; k < 196; k += 128) {
      const float4* b4 = (const float4*)(arp + ((size_t)s * 196 + k) * cC);
      float acc = 0.f;
      #pragma unroll
      for (int c4 = 0; c4 < 16; c4++) {
        float4 v = b4[c4];
        acc += v.x * f0l[c4 * 4 + 0] + v.y * f0l[c4 * 4 + 1] +
               v.z * f0l[c4 * 4 + 2] + v.w * f0l[c4 * 4 + 3];
      }
      fc[r][k] = acc;
    }
  }
  __syncthreads();
  float h0 = 0.f, h1 = 0.f, h2 = 0.f, h3 = 0.f;
  for (int k = 0; k < 196; k++) {
    float wv = w1[(size_t)k * 128 + j];
    h0 += fc[0][k] * wv; h1 += fc[1][k] * wv; h2 += fc[2][k] * wv; h3 += fc[3][k] * wv;
  }
  float hh[4] = {h0, h1, h2, h3};
  const float* Wfl = w1 + (size_t)196 * 128;
  const float* Wxy = w1 + (size_t)3198 * 128;
  float xx = pts[n * 2 + 0] * 0.125f, yy = pts[n * 2 + 1] * 0.125f;
  #pragma unroll
  for (int r = 0; r < 4; r++) {
    int s = sb + r;
    int sA = min(s + 1, 15), sB = (s == 15) ? 14 : s;
    float flx = coords[(sA * cN + n) * 2 + 0] - coords[(sB * cN + n) * 2 + 0];
    float fly = coords[(sA * cN + n) * 2 + 1] - coords[(sB * cN + n) * 2 + 1];
    float v = hh[r] + b1[j] + ffw[s * 128 + j] + flx * Wfl[j] + fly * Wfl[128 + j] +
              xx * Wxy[j] + yy * Wxy[128 + j];
    hl[r][j] = fmaxf(v, 0.f);
  }
  __syncthreads();
  if (j < 8) {
    int r = j >> 1, d = j & 1;
    float acc = b2[d];
    for (int k = 0; k < 128; k++) acc += hl[r][k] * w2[k * 2 + d];
    delta[((size_t)n * cS + sb + r) * 2 + d] = acc;
  }
}

__global__ __launch_bounds__(128) void k_mlp_fine(const float* __restrict__ fco, const float* __restrict__ LWc,
                                                  const float* __restrict__ b1e, const float* __restrict__ ffw,
                                                  const float* __restrict__ w1t, const float* __restrict__ w2,
                                                  const float* __restrict__ b2, const float* __restrict__ coords,
                                                  const float* __restrict__ xys, float* __restrict__ delta) {
  int n = blockIdx.x >> 2, sb = (blockIdx.x & 3) * 4;
  __shared__ float fc[4][588];
  __shared__ float hl[4][128];
  int j = threadIdx.x;
  #pragma unroll
  for (int r = 0; r < 4; r++)
    for (int k = j; k < 588; k += 128) fc[r][k] = fco[((size_t)n * cS + sb + r) * 588 + k];
  __syncthreads();
  float h0 = 0.f, h1 = 0.f, h2 = 0.f, h3 = 0.f;
  for (int k = 0; k < 588; k++) {
    float wv = LWc[(size_t)k * 128 + j];
    h0 += fc[0][k] * wv; h1 += fc[1][k] * wv; h2 += fc[2][k] * wv; h3 += fc[3][k] * wv;
  }
  float hh[4] = {h0, h1, h2, h3};
  const float* Wfl = w1t + (size_t)392 * 128;
  const float* Wxy = w1t + (size_t)3394 * 128;
  float xx = xys[n * 2 + 0], yy = xys[n * 2 + 1];
  #pragma unroll
  for (int r = 0; r < 4; r++) {
    int s = sb + r;
    int sA = min(s + 1, 15), sB = (s == 15) ? 14 : s;
    float flx = coords[(sA * cN + n) * 2 + 0] - coords[(sB * cN + n) * 2 + 0];
    float fly = coords[(sA * cN + n) * 2 + 1] - coords[(sB * cN + n) * 2 + 1];
    float v = hh[r] + b1e[j] + ffw[s * 128 + j] + flx * Wfl[j] + fly * Wfl[128 + j] +
              xx * Wxy[j] + yy * Wxy[128 + j];
    hl[r][j] = fmaxf(v, 0.f);
  }
  __syncthreads();
  if (j < 8) {
    int r = j >> 1, d = j & 1;
    float acc = b2[d];
    for (int k = 0; k < 128; k++) acc += hl[r][k] * w2[k * 2 + d];
    delta[((size_t)n * cS + sb + r) * 2 + d] = acc;
  }
}

// coarse update: coords_c += delta; preds[0] = 8*coords_c; coords_f = 4*coords_c
__global__ void k_updc(const float* __restrict__ delta, float* __restrict__ coords_c,
                       float* __restrict__ coords_f, float* __restrict__ out) {
  for (int idx = threadIdx.x; idx < cS * cN; idx += blockDim.x) {
    int s = idx >> 6, n = idx & 63;
    float cx = coords_c[idx * 2 + 0] + delta[((size_t)n * cS + s) * 2 + 0];
    float cy = coords_c[idx * 2 + 1] + delta[((size_t)n * cS + s) * 2 + 1];
    coords_c[idx * 2 + 0] = cx; coords_c[idx * 2 + 1] = cy;
    out[idx * 2 + 0] = cx * 8.0f; out[idx * 2 + 1] = cy * 8.0f;
    coords_f[idx * 2 + 0] = cx * 4.0f; coords_f[idx * 2 + 1] = cy * 4.0f;
  }
}

// fine update: coords_f += delta; preds[it+1] = 2*coords_f
__global__ void k_updf(const float* __restrict__ delta, float* __restrict__ coords_f,
                       float* __restrict__ out) {
  for (int idx = threadIdx.x; idx < cS * cN; idx += blockDim.x) {
    int s = idx >> 6, n = idx & 63;
    float cx = coords_f[idx * 2 + 0] + delta[((size_t)n * cS + s) * 2 + 0];
    float cy = coords_f[idx * 2 + 1] + delta[((size_t)n * cS + s) * 2 + 1];
    coords_f[idx * 2 + 0] = cx; coords_f[idx * 2 + 1] = cy;
    out[idx * 2 + 0] = cx * 2.0f; out[idx * 2 + 1] = cy * 2.0f;
  }
}

// ---------------------------------------------------------------------------
extern "C" void kernel_launch(void* const* d_in, const int* in_sizes, int n_in,
                              void* d_out, int out_size, void* d_ws, size_t ws_size,
                              hipStream_t stream) {
  (void)in_sizes; (void)n_in; (void)out_size; (void)ws_size;
  const float* rgbs = (const float*)d_in[0];
  const float* pts  = (const float*)d_in[1];
  const float* fnw  = (const float*)d_in[2];
  const float* fnfw = (const float*)d_in[3];
  const float* lw   = (const float*)d_in[4];
  const float* lb   = (const float*)d_in[5];
  const float* w1s  = (const float*)d_in[6];
  const float* b1s  = (const float*)d_in[7];
  const float* w2s  = (const float*)d_in[8];
  const float* b2s  = (const float*)d_in[9];
  const float* w1t  = (const float*)d_in[10];
  const float* b1t  = (const float*)d_in[11];
  const float* w2t  = (const float*)d_in[12];
  const float* b2t  = (const float*)d_in[13];
  float* out = (float*)d_out;

  float* p = (float*)d_ws;
  auto alloc = [&](size_t nf) { float* r = p; p += nf; return r; };
  float* ff    = alloc((size_t)cS * cFF);
  float* ffp   = alloc((size_t)2 * cS * cNCH * 128);
  float* ffw_s = alloc(cS * 128);
  float* ffw_t = alloc(cS * 128);
  float* LWc   = alloc((size_t)588 * 128);
  float* b1te  = alloc(128);
  float* fmc   = alloc((size_t)cS * cHC * cWC * cC);
  float* pc1   = alloc((size_t)cS * 12 * 15 * cC);
  float* pc2   = alloc((size_t)cS * 6 * 7 * cC);
  float* pc3   = alloc((size_t)cS * 3 * 3 * cC);
  float* arp   = alloc((size_t)cS * 196 * cC);
  float* f0c   = alloc((size_t)cN * cC);
  float* coc   = alloc((size_t)cS * cN * 2);
  float* fmf   = alloc((size_t)cS * cHF * cWF * cC);
  float* stats = alloc(cS * cC * 2);
  float* pf1   = alloc((size_t)cS * 50 * 60 * cC);
  float* pf2   = alloc((size_t)cS * 25 * 30 * cC);
  float* pf3   = alloc((size_t)cS * 12 * 15 * cC);
  float* f0f   = alloc((size_t)cN * cC);
  float* xys0  = alloc(cN * 2);
  float* cof   = alloc((size_t)cS * cN * 2);
  float* fe2   = alloc((size_t)cS * cN * cC);
  float* fe4   = alloc((size_t)cS * cN * cC);
  float* fco   = alloc((size_t)cN * cS * 588);
  float* dlt   = alloc((size_t)cS * cN * 2);

  // frame_flow + shared MLP precomputes
  k_ff<<<cS, 256, 0, stream>>>(rgbs, ff);
  k_ffw_part<<<dim3(cS, cNCH, 2), 128, 0, stream>>>(ff, w1s, w1t, ffp);
  k_ffw_red<<<dim3(cS, 2), 128, 0, stream>>>(ffp, ffw_s, ffw_t);
  k_lwc<<<589, 128, 0, stream>>>(lw, lb, w1t, b1t, LWc, b1te);

  // ---- coarse stage ----
  k_convc<<<dim3(cS, cC), 256, 0, stream>>>(rgbs, fnw, fmc);
  k_pool<<<dim3(cS, 12), 256, 0, stream>>>(fmc, pc1, 25, 30, 12, 15);
  k_pool<<<dim3(cS, 6), 256, 0, stream>>>(pc1, pc2, 12, 15, 6, 7);
  k_pool<<<dim3(cS, 3), 256, 0, stream>>>(pc2, pc3, 6, 7, 3, 3);
  k_arp<<<dim3(cS, 14), 256, 0, stream>>>(fmc, pc1, pc2, pc3, arp);
  k_initc<<<1, 256, 0, stream>>>(pts, coc);
  k_sample_f0<<<cN, 64, 0, stream>>>(fmc, cHC, cWC, pts, 0.125f, f0c, nullptr);
  k_mlp_coarse<<<256, 128, 0, stream>>>(arp, f0c, w1s, b1s, ffw_s, w2s, b2s, coc, pts, dlt);
  k_updc<<<1, 256, 0, stream>>>(dlt, coc, cof, out);  // preds[0]

  // ---- fine stage ----
  hipMemsetAsync(stats, 0, (size_t)cS * cC * 2 * sizeof(float), stream);
  k_convf<<<dim3(cS, cHF), 256, 0, stream>>>(rgbs, fnfw, fmf, stats);
  k_normf<<<2048, 256, 0, stream>>>(fmf, stats);
  k_pool<<<dim3(cS, 50), 256, 0, stream>>>(fmf, pf1, 100, 120, 50, 60);
  k_pool<<<dim3(cS, 25), 256, 0, stream>>>(pf1, pf2, 50, 60, 25, 30);
  k_pool<<<dim3(cS, 12), 256, 0, stream>>>(pf2, pf3, 25, 30, 12, 15);
  k_sample_f0<<<cN, 64, 0, stream>>>(fmf, cHF, cWF, cof, 1.0f, f0f, xys0);

  for (int it = 0; it < cITERS; it++) {
    k_feats<<<dim3(cN, cS, 2), 64, 0, stream>>>(fmf, cof, fe2, fe4);
    k_corr<<<dim3(cN, cS, 3), 256, 0, stream>>>(fmf, pf1, pf2, pf3, f0f, fe2, fe4, cof, fco);
    k_mlp_fine<<<256, 128, 0, stream>>>(fco, LWc, b1te, ffw_t, w1t, w2t, b2t, cof, xys0, dlt);
    k_updf<<<1, 256, 0, stream>>>(dlt, cof, out + (size_t)(it + 1) * cS * cN * 2);
  }
}

// Round 3
// 362.972 us; speedup vs baseline: 1.8896x; 1.3709x over previous
//
#include <hip/hip_runtime.h>

// ---- problem constants (from reference setup_inputs) ----
constexpr int cS = 16, cN = 64, cH = 200, cW = 240;
constexpr int cHC = 25, cWC = 30;          // coarse fmap (stride 8)
constexpr int cHF = 100, cWF = 120;        // fine fmap (stride 2)
constexpr int cC = 64;                     // LAT
constexpr int cFF = 3000;                  // 50*60
constexpr int cITERS = 4;                  // setup_inputs fixed
constexpr int cCHUNK = 60, cNCH = 50;      // ffw split

// ---------------------------------------------------------------------------
// helpers
// ---------------------------------------------------------------------------
__device__ __forceinline__ float bilin_hwc(const float* __restrict__ fm, int Hh, int Ww,
                                           float x, float y, int c) {
  x = fminf(fmaxf(x, -2.0e6f), 2.0e6f);
  y = fminf(fmaxf(y, -2.0e6f), 2.0e6f);
  float x0f = floorf(x), y0f = floorf(y);
  int ix = (int)x0f, iy = (int)y0f;
  float wx = x - x0f, wy = y - y0f;
  float acc = 0.f;
  bool vx0 = (ix >= 0) && (ix <= Ww - 1);
  bool vx1 = (ix + 1 >= 0) && (ix + 1 <= Ww - 1);
  bool vy0 = (iy >= 0) && (iy <= Hh - 1);
  bool vy1 = (iy + 1 >= 0) && (iy + 1 <= Hh - 1);
  if (vy0 && vx0) acc += fm[(iy * Ww + ix) * cC + c] * (1.f - wy) * (1.f - wx);
  if (vy0 && vx1) acc += fm[(iy * Ww + ix + 1) * cC + c] * (1.f - wy) * wx;
  if (vy1 && vx0) acc += fm[((iy + 1) * Ww + ix) * cC + c] * wy * (1.f - wx);
  if (vy1 && vx1) acc += fm[((iy + 1) * Ww + ix + 1) * cC + c] * wy * wx;
  return acc;
}

// ---------------------------------------------------------------------------
// frame_flow
// ---------------------------------------------------------------------------
__global__ void k_ff(const float* __restrict__ rgbs, float* __restrict__ ff) {
  int s = blockIdx.x;
  const float a = 2.0f / 255.0f;
  const float* cur = rgbs + (size_t)s * cH * cW;
  const float* prev = rgbs + (size_t)(s - 1) * cH * cW;
  const float* last = rgbs + (size_t)15 * cH * cW;
  for (int i = threadIdx.x; i < cFF; i += blockDim.x) {
    int o = i / 60, p = i % 60;
    int y = 4 * o + 1, x = 4 * p + 1;
    float v = 0.f;
    #pragma unroll
    for (int dy = 0; dy < 2; dy++)
      #pragma unroll
      for (int dx = 0; dx < 2; dx++) {
        int id = (y + dy) * cW + (x + dx);
        float pv = (s == 0) ? (a * last[id] - 1.0f) : (a * (cur[id] - prev[id]));
        v += pv;
      }
    ff[s * cFF + i] = 0.25f * v;
  }
}

// split ffw GEMV: part[t][s][ch][j] = sum_{i in chunk} ff[s][i] * w1[(off+i)*128+j]
__global__ __launch_bounds__(128) void k_ffw_part(const float* __restrict__ ff,
                                                  const float* __restrict__ w1s,
                                                  const float* __restrict__ w1t,
                                                  float* __restrict__ part) {
  int s = blockIdx.x, ch = blockIdx.y, t = blockIdx.z;
  int j = threadIdx.x;
  const float* w = (t == 0) ? (w1s + (size_t)198 * 128) : (w1t + (size_t)394 * 128);
  const float* f = ff + s * cFF + ch * cCHUNK;
  const float* wr = w + (size_t)ch * cCHUNK * 128 + j;
  float acc = 0.f;
  #pragma unroll 4
  for (int i = 0; i < cCHUNK; i++) acc += f[i] * wr[(size_t)i * 128];
  part[(((size_t)t * cS + s) * cNCH + ch) * 128 + j] = acc;
}

__global__ void k_ffw_red(const float* __restrict__ part, float* __restrict__ ffw_s,
                          float* __restrict__ ffw_t) {
  int s = blockIdx.x, t = blockIdx.y, j = threadIdx.x;
  const float* p = part + (((size_t)t * cS + s) * cNCH) * 128 + j;
  float acc = 0.f;
  for (int c = 0; c < cNCH; c++) acc += p[(size_t)c * 128];
  ((t == 0) ? ffw_s : ffw_t)[s * 128 + j] = acc;
}

// LWc[k][j] = sum_m linear_w[k][m] * dbt_w1[m][j];  block 588: b1te = dbt_b1 + lb @ W1[0:392]
__global__ void k_lwc(const float* __restrict__ lw, const float* __restrict__ lb,
                      const float* __restrict__ w1t, const float* __restrict__ b1t,
                      float* __restrict__ LWc, float* __restrict__ b1te) {
  int k = blockIdx.x, j = threadIdx.x;
  if (k < 588) {
    float acc = 0.f;
    for (int m = 0; m < 392; m++) acc += lw[(size_t)k * 392 + m] * w1t[(size_t)m * 128 + j];
    LWc[(size_t)k * 128 + j] = acc;
  } else {
    float acc = b1t[j];
    for (int m = 0; m < 392; m++) acc += lb[m] * w1t[(size_t)m * 128 + j];
    b1te[j] = acc;
  }
}

// ---------------------------------------------------------------------------
// coarse encoder: conv 8x8 stride 8 + instance norm, output HWC [16][750][64]
// ---------------------------------------------------------------------------
__global__ __launch_bounds__(256) void k_convc(const float* __restrict__ rgbs,
                                               const float* __restrict__ wc,
                                               float* __restrict__ fm) {
  int q = blockIdx.x, c = blockIdx.y;
  int tid = threadIdx.x;
  __shared__ float wl[64];
  __shared__ float red[256];
  if (tid < 64) wl[tid] = wc[c * 64 + tid];
  __syncthreads();
  const float a = 2.0f / 255.0f;
  const float* img = rgbs + (size_t)q * cH * cW;
  float vals[3];
  float sum = 0.f, ss = 0.f;
  #pragma unroll
  for (int i = 0; i < 3; i++) {
    int pos = tid + i * 256;
    float v = 0.f;
    if (pos < 750) {
      int y = pos / cWC, x = pos % cWC;
      const float* base = img + (y * 8) * cW + x * 8;
      float acc = 0.f, wsum = 0.f;
      for (int ky = 0; ky < 8; ky++)
        #pragma unroll
        for (int kx = 0; kx < 8; kx++) {
          float wv = wl[ky * 8 + kx];
          acc += wv * base[ky * cW + kx];
          wsum += wv;
        }
      v = a * acc - wsum;  // b = -1 folded: conv(2p/255 - 1)
      sum += v; ss += v * v;
    }
    vals[i] = v;
  }
  red[tid] = sum; __syncthreads();
  for (int st = 128; st > 0; st >>= 1) { if (tid < st) red[tid] += red[tid + st]; __syncthreads(); }
  float tsum = red[0]; __syncthreads();
  red[tid] = ss; __syncthreads();
  for (int st = 128; st > 0; st >>= 1) { if (tid < st) red[tid] += red[tid + st]; __syncthreads(); }
  float tss = red[0];
  float mean = tsum / 750.0f;
  float var = tss / 750.0f - mean * mean;
  float rstd = rsqrtf(var + 1e-5f);
  #pragma unroll
  for (int i = 0; i < 3; i++) {
    int pos = tid + i * 256;
    if (pos < 750) fm[((size_t)q * 750 + pos) * cC + c] = (vals[i] - mean) * rstd;
  }
}

// ---------------------------------------------------------------------------
// fine encoder: conv 2x2 stride 2, HWC raw output + per-(q,c) sum/sumsq atomics
// ---------------------------------------------------------------------------
__global__ __launch_bounds__(256) void k_convf(const float* __restrict__ rgbs,
                                               const float* __restrict__ wf,
                                               float* __restrict__ fm,
                                               float* __restrict__ stats) {
  int q = blockIdx.x, y = blockIdx.y;
  int lane = threadIdx.x & 63, wv = threadIdx.x >> 6;
  float w0 = wf[lane * 4 + 0], w1 = wf[lane * 4 + 1], w2 = wf[lane * 4 + 2], w3 = wf[lane * 4 + 3];
  float wsum = w0 + w1 + w2 + w3;
  const float a = 2.0f / 255.0f;
  const float* img = rgbs + (size_t)q * cH * cW;
  float sum = 0.f, ss = 0.f;
  for (int x = wv; x < cWF; x += 4) {
    const float* b = img + (2 * y) * cW + 2 * x;
    float v = a * (w0 * b[0] + w1 * b[1] + w2 * b[cW] + w3 * b[cW + 1]) - wsum;
    fm[(((size_t)q * cHF + y) * cWF + x) * cC + lane] = v;
    sum += v; ss += v * v;
  }
  __shared__ float red[2][4][64];
  red[0][wv][lane] = sum; red[1][wv][lane] = ss;
  __syncthreads();
  if (wv == 0) {
    float s4 = red[0][0][lane] + red[0][1][lane] + red[0][2][lane] + red[0][3][lane];
    float q4 = red[1][0][lane] + red[1][1][lane] + red[1][2][lane] + red[1][3][lane];
    atomicAdd(&stats[(q * 64 + lane) * 2 + 0], s4);
    atomicAdd(&stats[(q * 64 + lane) * 2 + 1], q4);
  }
}

__global__ void k_normf(float* __restrict__ fm, const float* __restrict__ stats) {
  const int total = 16 * cHF * cWF * cC;
  for (int i = blockIdx.x * blockDim.x + threadIdx.x; i < total; i += gridDim.x * blockDim.x) {
    int c = i & 63;
    int q = i / (cHF * cWF * cC);
    float s = stats[(q * 64 + c) * 2 + 0];
    float qq = stats[(q * 64 + c) * 2 + 1];
    float mean = s / 12000.0f;
    float var = qq / 12000.0f - mean * mean;
    fm[i] = (fm[i] - mean) * rsqrtf(var + 1e-5f);
  }
}

// generic 2x2 avg pool, HWC. block = (q, oy)
__global__ void k_pool(const float* __restrict__ in, float* __restrict__ out,
                       int IH, int IW, int OH, int OW) {
  int q = blockIdx.x, oy = blockIdx.y;
  int items = OW * cC;
  for (int i = threadIdx.x; i < items; i += blockDim.x) {
    int ox = i >> 6, c = i & 63;
    const float* b = in + (((size_t)q * IH + 2 * oy) * IW + 2 * ox) * cC + c;
    out[(((size_t)q * OH + oy) * OW + ox) * cC + c] =
        0.25f * (b[0] + b[cC] + b[(size_t)IW * cC] + b[(size_t)IW * cC + cC]);
  }
}

// averaged-resized coarse pyramid
__global__ __launch_bounds__(256) void k_arp(const float* __restrict__ l0, const float* __restrict__ l1,
                                             const float* __restrict__ l2, const float* __restrict__ l3,
                                             float* __restrict__ arp) {
  int q = blockIdx.x, o = blockIdx.y;
  int lane = threadIdx.x & 63, wv = threadIdx.x >> 6;
  const float* Ls[4] = {l0, l1, l2, l3};
  const int Hs[4] = {25, 12, 6, 3}, Ws[4] = {30, 15, 7, 3};
  for (int p = wv; p < 14; p += 4) {
    float acc = 0.f;
    #pragma unroll
    for (int l = 0; l < 4; l++) {
      float yy = (float)(o * (Hs[l] - 1)) / 13.0f;
      float xx = (float)(p * (Ws[l] - 1)) / 13.0f;
      int y0 = (int)floorf(yy); int y1 = min(y0 + 1, Hs[l] - 1); float wy = yy - (float)y0;
      int x0 = (int)floorf(xx); int x1 = min(x0 + 1, Ws[l] - 1); float wx = xx - (float)x0;
      const float* L = Ls[l] + (size_t)q * Hs[l] * Ws[l] * cC;
      float v00 = L[(y0 * Ws[l] + x0) * cC + lane], v01 = L[(y0 * Ws[l] + x1) * cC + lane];
      float v10 = L[(y1 * Ws[l] + x0) * cC + lane], v11 = L[(y1 * Ws[l] + x1) * cC + lane];
      acc += (v00 * (1.f - wy) + v10 * wy) * (1.f - wx) + (v01 * (1.f - wy) + v11 * wy) * wx;
    }
    arp[((size_t)q * 196 + (o * 14 + p)) * cC + lane] = acc * 0.25f * 0.125f;
  }
}

// coords_c[s][n] = points_0[n] / 8
__global__ void k_initc(const float* __restrict__ pts, float* __restrict__ coords_c) {
  for (int idx = threadIdx.x; idx < cS * cN; idx += blockDim.x) {
    int n = idx & 63;
    coords_c[idx * 2 + 0] = pts[n * 2 + 0] * 0.125f;
    coords_c[idx * 2 + 1] = pts[n * 2 + 1] * 0.125f;
  }
}

// sample frame-0 features at per-point coords (psrc[n*2+{0,1}] * scale)
__global__ void k_sample_f0(const float* __restrict__ fm, int Hh, int Ww,
                            const float* __restrict__ psrc, float scale,
                            float* __restrict__ out, float* __restrict__ xys) {
  int n = blockIdx.x, c = threadIdx.x;
  float x = psrc[n * 2 + 0] * scale, y = psrc[n * 2 + 1] * scale;
  out[n * cC + c] = bilin_hwc(fm, Hh, Ww, x, y, c);
  if (xys && c < 2) xys[n * 2 + c] = (c == 0) ? x : y;
}

// shifted feats
__global__ void k_feats(const float* __restrict__ fm, const float* __restrict__ coords,
                        float* __restrict__ f2, float* __restrict__ f4) {
  int n = blockIdx.x, s = blockIdx.y, t = blockIdx.z;
  int shift = (t == 0) ? 2 : 4;
  int ssrc = max(s - shift, 0);
  int c = threadIdx.x;
  float x = coords[(ssrc * cN + n) * 2 + 0];
  float y = coords[(ssrc * cN + n) * 2 + 1];
  float v = bilin_hwc(fm + (size_t)ssrc * cHF * cWF * cC, cHF, cWF, x, y, c);
  float* dst = (t == 0) ? f2 : f4;
  dst[((size_t)s * cN + n) * cC + c] = v;
}

// fused corr + window-sample, ALL THREE feature sets per block (shared gather).
// grid = 1024 blocks (XCD-swizzled), block = 256 = 4 waves = 4 pyramid levels.
// Each lane owns one 8x8 integer grid point: load the 64-float pyramid row ONCE,
// dot against 3 feature vectors; then 49 bilinear combos per set via shuffles.
__global__ __launch_bounds__(256) void k_corr(const float* __restrict__ p0, const float* __restrict__ p1,
                                              const float* __restrict__ p2, const float* __restrict__ p3,
                                              const float* __restrict__ f0, const float* __restrict__ f2,
                                              const float* __restrict__ f4, const float* __restrict__ coords,
                                              float* __restrict__ fco) {
  // bijective XCD swizzle: 1024 blocks = 8 XCDs x 128; each XCD gets 2 frames
  int bid = blockIdx.x;
  int w = (bid & 7) * 128 + (bid >> 3);
  int s = w >> 6, n = w & 63;
  __shared__ float feat[3][64];
  int tid = threadIdx.x;
  if (tid < 64) feat[0][tid] = f0[(size_t)n * cC + tid];
  else if (tid < 128) feat[1][tid - 64] = f2[((size_t)s * cN + n) * cC + (tid - 64)];
  else if (tid < 192) feat[2][tid - 128] = f4[((size_t)s * cN + n) * cC + (tid - 128)];
  __syncthreads();
  int l = tid >> 6, lane = tid & 63;
  const float* Ls[4] = {p0, p1, p2, p3};
  const int Hs[4] = {cHF, 50, 25, 12}, Ws[4] = {cWF, 60, 30, 15};
  float cx = coords[((size_t)s * cN + n) * 2 + 0];
  float cy = coords[((size_t)s * cN + n) * 2 + 1];
  float sc = 1.0f / (float)(1 << l);
  float x = fminf(fmaxf(cx * sc, -2.0e6f), 2.0e6f);
  float y = fminf(fmaxf(cy * sc, -2.0e6f), 2.0e6f);
  float x0f = floorf(x), y0f = floorf(y);
  float wx = x - x0f, wy = y - y0f;
  int dxi = lane & 7, dyi = lane >> 3;
  int ix = (int)x0f + dxi - 3, iy = (int)y0f + dyi - 3;
  int Hl = Hs[l], Wl = Ws[l];
  float d[3] = {0.f, 0.f, 0.f};
  if (ix >= 0 && ix < Wl && iy >= 0 && iy < Hl) {
    const float4* b4 = (const float4*)(Ls[l] + (((size_t)s * Hl + iy) * Wl + ix) * cC);
    float a0 = 0.f, a1 = 0.f, a2 = 0.f;
    #pragma unroll
    for (int c4 = 0; c4 < 16; c4++) {
      float4 v = b4[c4];
      const float* q0 = &feat[0][c4 * 4];
      const float* q1 = &feat[1][c4 * 4];
      const float* q2 = &feat[2][c4 * 4];
      a0 += v.x * q0[0] + v.y * q0[1] + v.z * q0[2] + v.w * q0[3];
      a1 += v.x * q1[0] + v.y * q1[1] + v.z * q1[2] + v.w * q1[3];
      a2 += v.x * q2[0] + v.y * q2[1] + v.z * q2[2] + v.w * q2[3];
    }
    d[0] = a0 * 0.125f; d[1] = a1 * 0.125f; d[2] = a2 * 0.125f;  // 1/sqrt(64)
  }
  int dy = lane / 7, dx = lane - dy * 7;
  int bb = (lane < 49) ? (dy * 8 + dx) : 0;
  float w00 = (1.f - wy) * (1.f - wx), w01 = (1.f - wy) * wx;
  float w10 = wy * (1.f - wx), w11 = wy * wx;
  float* dst = fco + ((size_t)n * cS + s) * 588 + l * 49 + lane;
  #pragma unroll
  for (int t = 0; t < 3; t++) {
    float d00 = __shfl(d[t], bb, 64);
    float d01 = __shfl(d[t], bb + 1, 64);
    float d10 = __shfl(d[t], bb + 8, 64);
    float d11 = __shfl(d[t], bb + 9, 64);
    if (lane < 49) dst[t * 196] = w00 * d00 + w01 * d01 + w10 * d10 + w11 * d11;
  }
}

// ---------------------------------------------------------------------------
// MLP delta blocks. Each block: 4 rows (same n, s = sb..sb+3), 128 threads (j).
// ---------------------------------------------------------------------------
__global__ __launch_bounds__(128) void k_mlp_coarse(const float* __restrict__ arp, const float* __restrict__ f0c,
                                                    const float* __restrict__ w1, const float* __restrict__ b1,
                                                    const float* __restrict__ ffw, const float* __restrict__ w2,
                                                    const float* __restrict__ b2, const float* __restrict__ coords,
                                                    const float* __restrict__ pts, float* __restrict__ delta) {
  int n = blockIdx.x >> 2, sb = (blockIdx.x & 3) * 4;
  __shared__ float fc[4][196];
  __shared__ float f0l[64];
  __shared__ float hl[4][128];
  int j = threadIdx.x;
  if (j < 64) f0l[j] = f0c[n * cC + j];
  __syncthreads();
  #pragma unroll
  for (int r = 0; r < 4; r++) {
    int s = sb + r;
    for (int k = j; k < 196; k += 128) {
      const float4* b4 = (const float4*)(arp + ((size_t)s * 196 + k) * cC);
      float acc = 0.f;
      #pragma unroll
      for (int c4 = 0; c4 < 16; c4++) {
        float4 v = b4[c4];
        acc += v.x * f0l[c4 * 4 + 0] + v.y * f0l[c4 * 4 + 1] +
               v.z * f0l[c4 * 4 + 2] + v.w * f0l[c4 * 4 + 3];
      }
      fc[r][k] = acc;
    }
  }
  __syncthreads();
  float h0 = 0.f, h1 = 0.f, h2 = 0.f, h3 = 0.f;
  for (int k = 0; k < 196; k++) {
    float wv = w1[(size_t)k * 128 + j];
    h0 += fc[0][k] * wv; h1 += fc[1][k] * wv; h2 += fc[2][k] * wv; h3 += fc[3][k] * wv;
  }
  float hh[4] = {h0, h1, h2, h3};
  const float* Wfl = w1 + (size_t)196 * 128;
  const float* Wxy = w1 + (size_t)3198 * 128;
  float xx = pts[n * 2 + 0] * 0.125f, yy = pts[n * 2 + 1] * 0.125f;
  #pragma unroll
  for (int r = 0; r < 4; r++) {
    int s = sb + r;
    int sA = min(s + 1, 15), sB = (s == 15) ? 14 : s;
    float flx = coords[(sA * cN + n) * 2 + 0] - coords[(sB * cN + n) * 2 + 0];
    float fly = coords[(sA * cN + n) * 2 + 1] - coords[(sB * cN + n) * 2 + 1];
    float v = hh[r] + b1[j] + ffw[s * 128 + j] + flx * Wfl[j] + fly * Wfl[128 + j] +
              xx * Wxy[j] + yy * Wxy[128 + j];
    hl[r][j] = fmaxf(v, 0.f);
  }
  __syncthreads();
  if (j < 8) {
    int r = j >> 1, d = j & 1;
    float acc = b2[d];
    for (int k = 0; k < 128; k++) acc += hl[r][k] * w2[k * 2 + d];
    delta[((size_t)n * cS + sb + r) * 2 + d] = acc;
  }
}

__global__ __launch_bounds__(128) void k_mlp_fine(const float* __restrict__ fco, const float* __restrict__ LWc,
                                                  const float* __restrict__ b1e, const float* __restrict__ ffw,
                                                  const float* __restrict__ w1t, const float* __restrict__ w2,
                                                  const float* __restrict__ b2, const float* __restrict__ coords,
                                                  const float* __restrict__ xys, float* __restrict__ delta) {
  int n = blockIdx.x >> 2, sb = (blockIdx.x & 3) * 4;
  __shared__ float fc[4][588];
  __shared__ float hl[4][128];
  int j = threadIdx.x;
  #pragma unroll
  for (int r = 0; r < 4; r++)
    for (int k = j; k < 588; k += 128) fc[r][k] = fco[((size_t)n * cS + sb + r) * 588 + k];
  __syncthreads();
  float h0 = 0.f, h1 = 0.f, h2 = 0.f, h3 = 0.f;
  for (int k = 0; k < 588; k++) {
    float wv = LWc[(size_t)k * 128 + j];
    h0 += fc[0][k] * wv; h1 += fc[1][k] * wv; h2 += fc[2][k] * wv; h3 += fc[3][k] * wv;
  }
  float hh[4] = {h0, h1, h2, h3};
  const float* Wfl = w1t + (size_t)392 * 128;
  const float* Wxy = w1t + (size_t)3394 * 128;
  float xx = xys[n * 2 + 0], yy = xys[n * 2 + 1];
  #pragma unroll
  for (int r = 0; r < 4; r++) {
    int s = sb + r;
    int sA = min(s + 1, 15), sB = (s == 15) ? 14 : s;
    float flx = coords[(sA * cN + n) * 2 + 0] - coords[(sB * cN + n) * 2 + 0];
    float fly = coords[(sA * cN + n) * 2 + 1] - coords[(sB * cN + n) * 2 + 1];
    float v = hh[r] + b1e[j] + ffw[s * 128 + j] + flx * Wfl[j] + fly * Wfl[128 + j] +
              xx * Wxy[j] + yy * Wxy[128 + j];
    hl[r][j] = fmaxf(v, 0.f);
  }
  __syncthreads();
  if (j < 8) {
    int r = j >> 1, d = j & 1;
    float acc = b2[d];
    for (int k = 0; k < 128; k++) acc += hl[r][k] * w2[k * 2 + d];
    delta[((size_t)n * cS + sb + r) * 2 + d] = acc;
  }
}

// coarse update: coords_c += delta; preds[0] = 8*coords_c; coords_f = 4*coords_c
__global__ void k_updc(const float* __restrict__ delta, float* __restrict__ coords_c,
                       float* __restrict__ coords_f, float* __restrict__ out) {
  for (int idx = threadIdx.x; idx < cS * cN; idx += blockDim.x) {
    int s = idx >> 6, n = idx & 63;
    float cx = coords_c[idx * 2 + 0] + delta[((size_t)n * cS + s) * 2 + 0];
    float cy = coords_c[idx * 2 + 1] + delta[((size_t)n * cS + s) * 2 + 1];
    coords_c[idx * 2 + 0] = cx; coords_c[idx * 2 + 1] = cy;
    out[idx * 2 + 0] = cx * 8.0f; out[idx * 2 + 1] = cy * 8.0f;
    coords_f[idx * 2 + 0] = cx * 4.0f; coords_f[idx * 2 + 1] = cy * 4.0f;
  }
}

// fine update: coords_f += delta; preds[it+1] = 2*coords_f
__global__ void k_updf(const float* __restrict__ delta, float* __restrict__ coords_f,
                       float* __restrict__ out) {
  for (int idx = threadIdx.x; idx < cS * cN; idx += blockDim.x) {
    int s = idx >> 6, n = idx & 63;
    float cx = coords_f[idx * 2 + 0] + delta[((size_t)n * cS + s) * 2 + 0];
    float cy = coords_f[idx * 2 + 1] + delta[((size_t)n * cS + s) * 2 + 1];
    coords_f[idx * 2 + 0] = cx; coords_f[idx * 2 + 1] = cy;
    out[idx * 2 + 0] = cx * 2.0f; out[idx * 2 + 1] = cy * 2.0f;
  }
}

// ---------------------------------------------------------------------------
extern "C" void kernel_launch(void* const* d_in, const int* in_sizes, int n_in,
                              void* d_out, int out_size, void* d_ws, size_t ws_size,
                              hipStream_t stream) {
  (void)in_sizes; (void)n_in; (void)out_size; (void)ws_size;
  const float* rgbs = (const float*)d_in[0];
  const float* pts  = (const float*)d_in[1];
  const float* fnw  = (const float*)d_in[2];
  const float* fnfw = (const float*)d_in[3];
  const float* lw   = (const float*)d_in[4];
  const float* lb   = (const float*)d_in[5];
  const float* w1s  = (const float*)d_in[6];
  const float* b1s  = (const float*)d_in[7];
  const float* w2s  = (const float*)d_in[8];
  const float* b2s  = (const float*)d_in[9];
  const float* w1t  = (const float*)d_in[10];
  const float* b1t  = (const float*)d_in[11];
  const float* w2t  = (const float*)d_in[12];
  const float* b2t  = (const float*)d_in[13];
  float* out = (float*)d_out;

  float* p = (float*)d_ws;
  auto alloc = [&](size_t nf) { float* r = p; p += nf; return r; };
  float* ff    = alloc((size_t)cS * cFF);
  float* ffp   = alloc((size_t)2 * cS * cNCH * 128);
  float* ffw_s = alloc(cS * 128);
  float* ffw_t = alloc(cS * 128);
  float* LWc   = alloc((size_t)588 * 128);
  float* b1te  = alloc(128);
  float* fmc   = alloc((size_t)cS * cHC * cWC * cC);
  float* pc1   = alloc((size_t)cS * 12 * 15 * cC);
  float* pc2   = alloc((size_t)cS * 6 * 7 * cC);
  float* pc3   = alloc((size_t)cS * 3 * 3 * cC);
  float* arp   = alloc((size_t)cS * 196 * cC);
  float* f0c   = alloc((size_t)cN * cC);
  float* coc   = alloc((size_t)cS * cN * 2);
  float* fmf   = alloc((size_t)cS * cHF * cWF * cC);
  float* stats = alloc(cS * cC * 2);
  float* pf1   = alloc((size_t)cS * 50 * 60 * cC);
  float* pf2   = alloc((size_t)cS * 25 * 30 * cC);
  float* pf3   = alloc((size_t)cS * 12 * 15 * cC);
  float* f0f   = alloc((size_t)cN * cC);
  float* xys0  = alloc(cN * 2);
  float* cof   = alloc((size_t)cS * cN * 2);
  float* fe2   = alloc((size_t)cS * cN * cC);
  float* fe4   = alloc((size_t)cS * cN * cC);
  float* fco   = alloc((size_t)cN * cS * 588);
  float* dlt   = alloc((size_t)cS * cN * 2);

  // frame_flow + shared MLP precomputes
  k_ff<<<cS, 256, 0, stream>>>(rgbs, ff);
  k_ffw_part<<<dim3(cS, cNCH, 2), 128, 0, stream>>>(ff, w1s, w1t, ffp);
  k_ffw_red<<<dim3(cS, 2), 128, 0, stream>>>(ffp, ffw_s, ffw_t);
  k_lwc<<<589, 128, 0, stream>>>(lw, lb, w1t, b1t, LWc, b1te);

  // ---- coarse stage ----
  k_convc<<<dim3(cS, cC), 256, 0, stream>>>(rgbs, fnw, fmc);
  k_pool<<<dim3(cS, 12), 256, 0, stream>>>(fmc, pc1, 25, 30, 12, 15);
  k_pool<<<dim3(cS, 6), 256, 0, stream>>>(pc1, pc2, 12, 15, 6, 7);
  k_pool<<<dim3(cS, 3), 256, 0, stream>>>(pc2, pc3, 6, 7, 3, 3);
  k_arp<<<dim3(cS, 14), 256, 0, stream>>>(fmc, pc1, pc2, pc3, arp);
  k_initc<<<1, 256, 0, stream>>>(pts, coc);
  k_sample_f0<<<cN, 64, 0, stream>>>(fmc, cHC, cWC, pts, 0.125f, f0c, nullptr);
  k_mlp_coarse<<<256, 128, 0, stream>>>(arp, f0c, w1s, b1s, ffw_s, w2s, b2s, coc, pts, dlt);
  k_updc<<<1, 256, 0, stream>>>(dlt, coc, cof, out);  // preds[0]

  // ---- fine stage ----
  hipMemsetAsync(stats, 0, (size_t)cS * cC * 2 * sizeof(float), stream);
  k_convf<<<dim3(cS, cHF), 256, 0, stream>>>(rgbs, fnfw, fmf, stats);
  k_normf<<<2048, 256, 0, stream>>>(fmf, stats);
  k_pool<<<dim3(cS, 50), 256, 0, stream>>>(fmf, pf1, 100, 120, 50, 60);
  k_pool<<<dim3(cS, 25), 256, 0, stream>>>(pf1, pf2, 50, 60, 25, 30);
  k_pool<<<dim3(cS, 12), 256, 0, stream>>>(pf2, pf3, 25, 30, 12, 15);
  k_sample_f0<<<cN, 64, 0, stream>>>(fmf, cHF, cWF, cof, 1.0f, f0f, xys0);

  for (int it = 0; it < cITERS; it++) {
    k_feats<<<dim3(cN, cS, 2), 64, 0, stream>>>(fmf, cof, fe2, fe4);
    k_corr<<<1024, 256, 0, stream>>>(fmf, pf1, pf2, pf3, f0f, fe2, fe4, cof, fco);
    k_mlp_fine<<<256, 128, 0, stream>>>(fco, LWc, b1te, ffw_t, w1t, w2t, b2t, cof, xys0, dlt);
    k_updf<<<1, 256, 0, stream>>>(dlt, cof, out + (size_t)(it + 1) * cS * cN * 2);
  }
}

// Round 4
// 308.699 us; speedup vs baseline: 2.2218x; 1.1758x over previous
//
#include <hip/hip_runtime.h>

// ---- problem constants (from reference setup_inputs) ----
constexpr int cS = 16, cN = 64, cH = 200, cW = 240;
constexpr int cHC = 25, cWC = 30;          // coarse fmap (stride 8)
constexpr int cHF = 100, cWF = 120;        // fine fmap (stride 2)
constexpr int cC = 64;                     // LAT
constexpr int cFF = 3000;                  // 50*60
constexpr int cITERS = 4;                  // setup_inputs fixed
constexpr int cCHUNK = 60, cNCH = 50;      // ffw split

// ---------------------------------------------------------------------------
// helpers
// ---------------------------------------------------------------------------
__device__ __forceinline__ float bilin_hwc(const float* __restrict__ fm, int Hh, int Ww,
                                           float x, float y, int c) {
  x = fminf(fmaxf(x, -2.0e6f), 2.0e6f);
  y = fminf(fmaxf(y, -2.0e6f), 2.0e6f);
  float x0f = floorf(x), y0f = floorf(y);
  int ix = (int)x0f, iy = (int)y0f;
  float wx = x - x0f, wy = y - y0f;
  float acc = 0.f;
  bool vx0 = (ix >= 0) && (ix <= Ww - 1);
  bool vx1 = (ix + 1 >= 0) && (ix + 1 <= Ww - 1);
  bool vy0 = (iy >= 0) && (iy <= Hh - 1);
  bool vy1 = (iy + 1 >= 0) && (iy + 1 <= Hh - 1);
  if (vy0 && vx0) acc += fm[(iy * Ww + ix) * cC + c] * (1.f - wy) * (1.f - wx);
  if (vy0 && vx1) acc += fm[(iy * Ww + ix + 1) * cC + c] * (1.f - wy) * wx;
  if (vy1 && vx0) acc += fm[((iy + 1) * Ww + ix) * cC + c] * wy * (1.f - wx);
  if (vy1 && vx1) acc += fm[((iy + 1) * Ww + ix + 1) * cC + c] * wy * wx;
  return acc;
}

// ---------------------------------------------------------------------------
// fused frame_flow + partial GEMV. block (s, ch, t): recompute ff row ch (60
// vals) in LDS, then partial dot into part[t][s][ch][j].
// ---------------------------------------------------------------------------
__global__ __launch_bounds__(128) void k_ffp(const float* __restrict__ rgbs,
                                             const float* __restrict__ w1s,
                                             const float* __restrict__ w1t,
                                             float* __restrict__ part) {
  int s = blockIdx.x, ch = blockIdx.y, t = blockIdx.z;
  int j = threadIdx.x;
  __shared__ float fr[cCHUNK];
  if (j < cCHUNK) {
    const float a = 2.0f / 255.0f;
    const float* cur = rgbs + (size_t)s * cH * cW;
    const float* prev = rgbs + (size_t)(s - 1) * cH * cW;
    const float* last = rgbs + (size_t)15 * cH * cW;
    int y = 4 * ch + 1, x = 4 * j + 1;
    float v = 0.f;
    #pragma unroll
    for (int dy = 0; dy < 2; dy++)
      #pragma unroll
      for (int dx = 0; dx < 2; dx++) {
        int id = (y + dy) * cW + (x + dx);
        float pv = (s == 0) ? (a * last[id] - 1.0f) : (a * (cur[id] - prev[id]));
        v += pv;
      }
    fr[j] = 0.25f * v;
  }
  __syncthreads();
  const float* w = (t == 0) ? (w1s + (size_t)198 * 128) : (w1t + (size_t)394 * 128);
  const float* wr = w + (size_t)ch * cCHUNK * 128 + j;
  float acc = 0.f;
  #pragma unroll 4
  for (int i = 0; i < cCHUNK; i++) acc += fr[i] * wr[(size_t)i * 128];
  part[(((size_t)t * cS + s) * cNCH + ch) * 128 + j] = acc;
}

__global__ void k_ffw_red(const float* __restrict__ part, float* __restrict__ ffw_s,
                          float* __restrict__ ffw_t) {
  int s = blockIdx.x, t = blockIdx.y, j = threadIdx.x;
  const float* p = part + (((size_t)t * cS + s) * cNCH) * 128 + j;
  float acc = 0.f;
  for (int c = 0; c < cNCH; c++) acc += p[(size_t)c * 128];
  ((t == 0) ? ffw_s : ffw_t)[s * 128 + j] = acc;
}

// LWc[k][j] = sum_m lw[k][m]*w1t[m][j]. 4 k-rows per block (amortize w1t read).
// block 147: b1te = dbt_b1 + lb @ W1[0:392]
__global__ __launch_bounds__(128) void k_lwc(const float* __restrict__ lw, const float* __restrict__ lb,
                                             const float* __restrict__ w1t, const float* __restrict__ b1t,
                                             float* __restrict__ LWc, float* __restrict__ b1te) {
  int bid = blockIdx.x, j = threadIdx.x;
  if (bid < 147) {
    int k0 = bid * 4;
    const float* l0 = lw + (size_t)(k0 + 0) * 392;
    const float* l1 = lw + (size_t)(k0 + 1) * 392;
    const float* l2 = lw + (size_t)(k0 + 2) * 392;
    const float* l3 = lw + (size_t)(k0 + 3) * 392;
    float a0 = 0.f, a1 = 0.f, a2 = 0.f, a3 = 0.f;
    for (int m = 0; m < 392; m++) {
      float wv = w1t[(size_t)m * 128 + j];
      a0 += l0[m] * wv; a1 += l1[m] * wv; a2 += l2[m] * wv; a3 += l3[m] * wv;
    }
    LWc[(size_t)(k0 + 0) * 128 + j] = a0;
    LWc[(size_t)(k0 + 1) * 128 + j] = a1;
    LWc[(size_t)(k0 + 2) * 128 + j] = a2;
    LWc[(size_t)(k0 + 3) * 128 + j] = a3;
  } else {
    float acc = b1t[j];
    for (int m = 0; m < 392; m++) acc += lb[m] * w1t[(size_t)m * 128 + j];
    b1te[j] = acc;
  }
}

// ---------------------------------------------------------------------------
// coarse encoder: conv 8x8 stride 8 + instance norm, output HWC [16][750][64]
// ---------------------------------------------------------------------------
__global__ __launch_bounds__(256) void k_convc(const float* __restrict__ rgbs,
                                               const float* __restrict__ wc,
                                               float* __restrict__ fm) {
  int q = blockIdx.x, c = blockIdx.y;
  int tid = threadIdx.x;
  __shared__ float wl[64];
  __shared__ float red[256];
  if (tid < 64) wl[tid] = wc[c * 64 + tid];
  __syncthreads();
  const float a = 2.0f / 255.0f;
  const float* img = rgbs + (size_t)q * cH * cW;
  float vals[3];
  float sum = 0.f, ss = 0.f;
  #pragma unroll
  for (int i = 0; i < 3; i++) {
    int pos = tid + i * 256;
    float v = 0.f;
    if (pos < 750) {
      int y = pos / cWC, x = pos % cWC;
      const float* base = img + (y * 8) * cW + x * 8;
      float acc = 0.f, wsum = 0.f;
      for (int ky = 0; ky < 8; ky++)
        #pragma unroll
        for (int kx = 0; kx < 8; kx++) {
          float wv = wl[ky * 8 + kx];
          acc += wv * base[ky * cW + kx];
          wsum += wv;
        }
      v = a * acc - wsum;  // b = -1 folded: conv(2p/255 - 1)
      sum += v; ss += v * v;
    }
    vals[i] = v;
  }
  red[tid] = sum; __syncthreads();
  for (int st = 128; st > 0; st >>= 1) { if (tid < st) red[tid] += red[tid + st]; __syncthreads(); }
  float tsum = red[0]; __syncthreads();
  red[tid] = ss; __syncthreads();
  for (int st = 128; st > 0; st >>= 1) { if (tid < st) red[tid] += red[tid + st]; __syncthreads(); }
  float tss = red[0];
  float mean = tsum / 750.0f;
  float var = tss / 750.0f - mean * mean;
  float rstd = rsqrtf(var + 1e-5f);
  #pragma unroll
  for (int i = 0; i < 3; i++) {
    int pos = tid + i * 256;
    if (pos < 750) fm[((size_t)q * 750 + pos) * cC + c] = (vals[i] - mean) * rstd;
  }
}

// ---------------------------------------------------------------------------
// fused coarse pyramid (3 pools in LDS) + averaged-resize (arp). block = q.
// ---------------------------------------------------------------------------
__global__ __launch_bounds__(256) void k_pyrc(const float* __restrict__ fmc,
                                              float* __restrict__ arp) {
  int q = blockIdx.x, tid = threadIdx.x;
  __shared__ float pc1[12 * 15 * 64];
  __shared__ float pc2[6 * 7 * 64];
  __shared__ float pc3[3 * 3 * 64];
  const float* L0 = fmc + (size_t)q * 750 * cC;
  // pool 1: 25x30 -> 12x15
  for (int i = tid; i < 12 * 15 * 64; i += 256) {
    int c = i & 63, pos = i >> 6, oy = pos / 15, ox = pos % 15;
    const float* b = L0 + ((2 * oy) * 30 + 2 * ox) * cC + c;
    pc1[i] = 0.25f * (b[0] + b[cC] + b[30 * cC] + b[30 * cC + cC]);
  }
  __syncthreads();
  // pool 2: 12x15 -> 6x7
  for (int i = tid; i < 6 * 7 * 64; i += 256) {
    int c = i & 63, pos = i >> 6, oy = pos / 7, ox = pos % 7;
    const float* b = pc1 + ((2 * oy) * 15 + 2 * ox) * cC + c;
    pc2[i] = 0.25f * (b[0] + b[cC] + b[15 * cC] + b[15 * cC + cC]);
  }
  __syncthreads();
  // pool 3: 6x7 -> 3x3
  for (int i = tid; i < 3 * 3 * 64; i += 256) {
    int c = i & 63, pos = i >> 6, oy = pos / 3, ox = pos % 3;
    const float* b = pc2 + ((2 * oy) * 7 + 2 * ox) * cC + c;
    pc3[i] = 0.25f * (b[0] + b[cC] + b[7 * cC] + b[7 * cC + cC]);
  }
  __syncthreads();
  // arp: 14x14 align-corners resize of all 4 levels, averaged (x 0.25*0.125)
  const int Hs[4] = {25, 12, 6, 3}, Ws[4] = {30, 15, 7, 3};
  for (int i = tid; i < 196 * 64; i += 256) {
    int c = i & 63, pos = i >> 6, o = pos / 14, p = pos % 14;
    float acc = 0.f;
    #pragma unroll
    for (int l = 0; l < 4; l++) {
      float yy = (float)(o * (Hs[l] - 1)) / 13.0f;
      float xx = (float)(p * (Ws[l] - 1)) / 13.0f;
      int y0 = (int)floorf(yy); int y1 = min(y0 + 1, Hs[l] - 1); float wy = yy - (float)y0;
      int x0 = (int)floorf(xx); int x1 = min(x0 + 1, Ws[l] - 1); float wx = xx - (float)x0;
      const float* L = (l == 0) ? L0 : ((l == 1) ? pc1 : ((l == 2) ? pc2 : pc3));
      float v00 = L[(y0 * Ws[l] + x0) * cC + c], v01 = L[(y0 * Ws[l] + x1) * cC + c];
      float v10 = L[(y1 * Ws[l] + x0) * cC + c], v11 = L[(y1 * Ws[l] + x1) * cC + c];
      acc += (v00 * (1.f - wy) + v10 * wy) * (1.f - wx) + (v01 * (1.f - wy) + v11 * wy) * wx;
    }
    arp[((size_t)q * 196 + pos) * cC + c] = acc * 0.25f * 0.125f;
  }
}

// ---------------------------------------------------------------------------
// fine encoder: conv 2x2 stride 2, HWC raw output + per-(q,c) sum/sumsq atomics
// ---------------------------------------------------------------------------
__global__ __launch_bounds__(256) void k_convf(const float* __restrict__ rgbs,
                                               const float* __restrict__ wf,
                                               float* __restrict__ fm,
                                               float* __restrict__ stats) {
  int q = blockIdx.x, y = blockIdx.y;
  int lane = threadIdx.x & 63, wv = threadIdx.x >> 6;
  float w0 = wf[lane * 4 + 0], w1 = wf[lane * 4 + 1], w2 = wf[lane * 4 + 2], w3 = wf[lane * 4 + 3];
  float wsum = w0 + w1 + w2 + w3;
  const float a = 2.0f / 255.0f;
  const float* img = rgbs + (size_t)q * cH * cW;
  float sum = 0.f, ss = 0.f;
  for (int x = wv; x < cWF; x += 4) {
    const float* b = img + (2 * y) * cW + 2 * x;
    float v = a * (w0 * b[0] + w1 * b[1] + w2 * b[cW] + w3 * b[cW + 1]) - wsum;
    fm[(((size_t)q * cHF + y) * cWF + x) * cC + lane] = v;
    sum += v; ss += v * v;
  }
  __shared__ float red[2][4][64];
  red[0][wv][lane] = sum; red[1][wv][lane] = ss;
  __syncthreads();
  if (wv == 0) {
    float s4 = red[0][0][lane] + red[0][1][lane] + red[0][2][lane] + red[0][3][lane];
    float q4 = red[1][0][lane] + red[1][1][lane] + red[1][2][lane] + red[1][3][lane];
    atomicAdd(&stats[(q * 64 + lane) * 2 + 0], s4);
    atomicAdd(&stats[(q * 64 + lane) * 2 + 1], q4);
  }
}

__global__ void k_normf(float* __restrict__ fm, const float* __restrict__ stats) {
  const int total = 16 * cHF * cWF * cC;
  for (int i = blockIdx.x * blockDim.x + threadIdx.x; i < total; i += gridDim.x * blockDim.x) {
    int c = i & 63;
    int q = i / (cHF * cWF * cC);
    float s = stats[(q * 64 + c) * 2 + 0];
    float qq = stats[(q * 64 + c) * 2 + 1];
    float mean = s / 12000.0f;
    float var = qq / 12000.0f - mean * mean;
    fm[i] = (fm[i] - mean) * rsqrtf(var + 1e-5f);
  }
}

// generic 2x2 avg pool, HWC. block = (q, oy)
__global__ void k_pool(const float* __restrict__ in, float* __restrict__ out,
                       int IH, int IW, int OH, int OW) {
  int q = blockIdx.x, oy = blockIdx.y;
  int items = OW * cC;
  for (int i = threadIdx.x; i < items; i += blockDim.x) {
    int ox = i >> 6, c = i & 63;
    const float* b = in + (((size_t)q * IH + 2 * oy) * IW + 2 * ox) * cC + c;
    out[(((size_t)q * OH + oy) * OW + ox) * cC + c] =
        0.25f * (b[0] + b[cC] + b[(size_t)IW * cC] + b[(size_t)IW * cC + cC]);
  }
}

// sample frame-0 features at per-point coords (psrc[n*2+{0,1}] * scale)
__global__ void k_sample_f0(const float* __restrict__ fm, int Hh, int Ww,
                            const float* __restrict__ psrc, float scale,
                            float* __restrict__ out, float* __restrict__ xys) {
  int n = blockIdx.x, c = threadIdx.x;
  float x = psrc[n * 2 + 0] * scale, y = psrc[n * 2 + 1] * scale;
  out[n * cC + c] = bilin_hwc(fm, Hh, Ww, x, y, c);
  if (xys && c < 2) xys[n * 2 + c] = (c == 0) ? x : y;
}

// fused corr + in-block shifted feats + window-sample. grid = 1024 (XCD swizzle),
// block = 256 = 4 waves = 4 pyramid levels.
__global__ __launch_bounds__(256) void k_corr(const float* __restrict__ p0, const float* __restrict__ p1,
                                              const float* __restrict__ p2, const float* __restrict__ p3,
                                              const float* __restrict__ f0, const float* __restrict__ coords,
                                              float* __restrict__ fco) {
  int bid = blockIdx.x;
  int w = (bid & 7) * 128 + (bid >> 3);
  int s = w >> 6, n = w & 63;
  __shared__ float feat[3][64];
  int tid = threadIdx.x;
  if (tid < 64) {
    feat[0][tid] = f0[(size_t)n * cC + tid];
  } else if (tid < 192) {
    int t = (tid < 128) ? 1 : 2;
    int c = tid & 63;
    int ssrc = max(s - 2 * t, 0);
    float fx = coords[((size_t)ssrc * cN + n) * 2 + 0];
    float fy = coords[((size_t)ssrc * cN + n) * 2 + 1];
    feat[t][c] = bilin_hwc(p0 + (size_t)ssrc * cHF * cWF * cC, cHF, cWF, fx, fy, c);
  }
  __syncthreads();
  int l = tid >> 6, lane = tid & 63;
  const float* Ls[4] = {p0, p1, p2, p3};
  const int Hs[4] = {cHF, 50, 25, 12}, Ws[4] = {cWF, 60, 30, 15};
  float cx = coords[((size_t)s * cN + n) * 2 + 0];
  float cy = coords[((size_t)s * cN + n) * 2 + 1];
  float sc = 1.0f / (float)(1 << l);
  float x = fminf(fmaxf(cx * sc, -2.0e6f), 2.0e6f);
  float y = fminf(fmaxf(cy * sc, -2.0e6f), 2.0e6f);
  float x0f = floorf(x), y0f = floorf(y);
  float wx = x - x0f, wy = y - y0f;
  int dxi = lane & 7, dyi = lane >> 3;
  int ix = (int)x0f + dxi - 3, iy = (int)y0f + dyi - 3;
  int Hl = Hs[l], Wl = Ws[l];
  float d[3] = {0.f, 0.f, 0.f};
  if (ix >= 0 && ix < Wl && iy >= 0 && iy < Hl) {
    const float4* b4 = (const float4*)(Ls[l] + (((size_t)s * Hl + iy) * Wl + ix) * cC);
    float a0 = 0.f, a1 = 0.f, a2 = 0.f;
    #pragma unroll
    for (int c4 = 0; c4 < 16; c4++) {
      float4 v = b4[c4];
      const float* q0 = &feat[0][c4 * 4];
      const float* q1 = &feat[1][c4 * 4];
      const float* q2 = &feat[2][c4 * 4];
      a0 += v.x * q0[0] + v.y * q0[1] + v.z * q0[2] + v.w * q0[3];
      a1 += v.x * q1[0] + v.y * q1[1] + v.z * q1[2] + v.w * q1[3];
      a2 += v.x * q2[0] + v.y * q2[1] + v.z * q2[2] + v.w * q2[3];
    }
    d[0] = a0 * 0.125f; d[1] = a1 * 0.125f; d[2] = a2 * 0.125f;  // 1/sqrt(64)
  }
  int dy = lane / 7, dx = lane - dy * 7;
  int bb = (lane < 49) ? (dy * 8 + dx) : 0;
  float w00 = (1.f - wy) * (1.f - wx), w01 = (1.f - wy) * wx;
  float w10 = wy * (1.f - wx), w11 = wy * wx;
  float* dst = fco + ((size_t)n * cS + s) * 588 + l * 49 + lane;
  #pragma unroll
  for (int t = 0; t < 3; t++) {
    float d00 = __shfl(d[t], bb, 64);
    float d01 = __shfl(d[t], bb + 1, 64);
    float d10 = __shfl(d[t], bb + 8, 64);
    float d11 = __shfl(d[t], bb + 9, 64);
    if (lane < 49) dst[t * 196] = w00 * d00 + w01 * d01 + w10 * d10 + w11 * d11;
  }
}

// ---------------------------------------------------------------------------
// coarse MLP (fused f0-sample + coords update). Each block: 4 rows (n, sb..sb+3).
// NOTE: coarse flow term is exactly zero (coords are a broadcast pre-update).
// ---------------------------------------------------------------------------
__global__ __launch_bounds__(128) void k_mlp_coarse(const float* __restrict__ arp, const float* __restrict__ fmc,
                                                    const float* __restrict__ w1, const float* __restrict__ b1,
                                                    const float* __restrict__ ffw, const float* __restrict__ w2,
                                                    const float* __restrict__ b2,
                                                    const float* __restrict__ pts, float* __restrict__ cof,
                                                    float* __restrict__ out) {
  int n = blockIdx.x >> 2, sb = (blockIdx.x & 3) * 4;
  __shared__ float fc[4][196];
  __shared__ float f0l[64];
  __shared__ float hl[4][128];
  int j = threadIdx.x;
  float xx = pts[n * 2 + 0] * 0.125f, yy = pts[n * 2 + 1] * 0.125f;
  if (j < 64) f0l[j] = bilin_hwc(fmc, cHC, cWC, xx, yy, j);
  __syncthreads();
  #pragma unroll
  for (int r = 0; r < 4; r++) {
    int s = sb + r;
    for (int k = j; k < 196; k += 128) {
      const float4* b4 = (const float4*)(arp + ((size_t)s * 196 + k) * cC);
      float acc = 0.f;
      #pragma unroll
      for (int c4 = 0; c4 < 16; c4++) {
        float4 v = b4[c4];
        acc += v.x * f0l[c4 * 4 + 0] + v.y * f0l[c4 * 4 + 1] +
               v.z * f0l[c4 * 4 + 2] + v.w * f0l[c4 * 4 + 3];
      }
      fc[r][k] = acc;
    }
  }
  __syncthreads();
  float h0 = 0.f, h1 = 0.f, h2 = 0.f, h3 = 0.f;
  for (int k = 0; k < 196; k++) {
    float wv = w1[(size_t)k * 128 + j];
    h0 += fc[0][k] * wv; h1 += fc[1][k] * wv; h2 += fc[2][k] * wv; h3 += fc[3][k] * wv;
  }
  float hh[4] = {h0, h1, h2, h3};
  const float* Wxy = w1 + (size_t)3198 * 128;
  #pragma unroll
  for (int r = 0; r < 4; r++) {
    int s = sb + r;
    float v = hh[r] + b1[j] + ffw[s * 128 + j] + xx * Wxy[j] + yy * Wxy[128 + j];
    hl[r][j] = fmaxf(v, 0.f);
  }
  __syncthreads();
  if (j < 8) {
    int r = j >> 1, d = j & 1;
    float acc = b2[d];
    for (int k = 0; k < 128; k++) acc += hl[r][k] * w2[k * 2 + d];
    int s = sb + r;
    float base = pts[n * 2 + d] * 0.125f;
    float cc = base + acc;                       // coarse coords after update
    out[((size_t)s * cN + n) * 2 + d] = cc * 8.0f;   // preds[0]
    cof[((size_t)s * cN + n) * 2 + d] = cc * 4.0f;   // fine coords init
  }
}

// fine MLP: 256 threads (K split in 2 halves of 294) + fused coords update.
__global__ __launch_bounds__(256) void k_mlp_fine(const float* __restrict__ fco, const float* __restrict__ LWc,
                                                  const float* __restrict__ b1e, const float* __restrict__ ffw,
                                                  const float* __restrict__ w1t, const float* __restrict__ w2,
                                                  const float* __restrict__ b2, const float* __restrict__ cof_cur,
                                                  float* __restrict__ cof_nxt, const float* __restrict__ xys,
                                                  float* __restrict__ out) {
  int n = blockIdx.x >> 2, sb = (blockIdx.x & 3) * 4;
  __shared__ float fc[4][588];
  __shared__ float hp[2][4][128];
  __shared__ float hl[4][128];
  int tid = threadIdx.x;
  int j = tid & 127, half = tid >> 7;
  #pragma unroll
  for (int r = 0; r < 4; r++)
    for (int k = tid; k < 588; k += 256) fc[r][k] = fco[((size_t)n * cS + sb + r) * 588 + k];
  __syncthreads();
  float h0 = 0.f, h1 = 0.f, h2 = 0.f, h3 = 0.f;
  int k0 = half * 294;
  for (int k = k0; k < k0 + 294; k++) {
    float wv = LWc[(size_t)k * 128 + j];
    h0 += fc[0][k] * wv; h1 += fc[1][k] * wv; h2 += fc[2][k] * wv; h3 += fc[3][k] * wv;
  }
  hp[half][0][j] = h0; hp[half][1][j] = h1; hp[half][2][j] = h2; hp[half][3][j] = h3;
  __syncthreads();
  if (half == 0) {
    const float* Wfl = w1t + (size_t)392 * 128;
    const float* Wxy = w1t + (size_t)3394 * 128;
    float xx = xys[n * 2 + 0], yy = xys[n * 2 + 1];
    #pragma unroll
    for (int r = 0; r < 4; r++) {
      int s = sb + r;
      int sA = min(s + 1, 15), sB = (s == 15) ? 14 : s;
      float flx = cof_cur[(sA * cN + n) * 2 + 0] - cof_cur[(sB * cN + n) * 2 + 0];
      float fly = cof_cur[(sA * cN + n) * 2 + 1] - cof_cur[(sB * cN + n) * 2 + 1];
      float v = hp[0][r][j] + hp[1][r][j] + b1e[j] + ffw[s * 128 + j] +
                flx * Wfl[j] + fly * Wfl[128 + j] + xx * Wxy[j] + yy * Wxy[128 + j];
      hl[r][j] = fmaxf(v, 0.f);
    }
  }
  __syncthreads();
  if (tid < 8) {
    int r = tid >> 1, d = tid & 1;
    float acc = b2[d];
    for (int k = 0; k < 128; k++) acc += hl[r][k] * w2[k * 2 + d];
    int s = sb + r;
    float cc = cof_cur[((size_t)s * cN + n) * 2 + d] + acc;
    cof_nxt[((size_t)s * cN + n) * 2 + d] = cc;
    out[((size_t)s * cN + n) * 2 + d] = cc * 2.0f;
  }
}

// ---------------------------------------------------------------------------
extern "C" void kernel_launch(void* const* d_in, const int* in_sizes, int n_in,
                              void* d_out, int out_size, void* d_ws, size_t ws_size,
                              hipStream_t stream) {
  (void)in_sizes; (void)n_in; (void)out_size; (void)ws_size;
  const float* rgbs = (const float*)d_in[0];
  const float* pts  = (const float*)d_in[1];
  const float* fnw  = (const float*)d_in[2];
  const float* fnfw = (const float*)d_in[3];
  const float* lw   = (const float*)d_in[4];
  const float* lb   = (const float*)d_in[5];
  const float* w1s  = (const float*)d_in[6];
  const float* b1s  = (const float*)d_in[7];
  const float* w2s  = (const float*)d_in[8];
  const float* b2s  = (const float*)d_in[9];
  const float* w1t  = (const float*)d_in[10];
  const float* b1t  = (const float*)d_in[11];
  const float* w2t  = (const float*)d_in[12];
  const float* b2t  = (const float*)d_in[13];
  float* out = (float*)d_out;

  float* p = (float*)d_ws;
  auto alloc = [&](size_t nf) { float* r = p; p += nf; return r; };
  float* ffp   = alloc((size_t)2 * cS * cNCH * 128);
  float* ffw_s = alloc(cS * 128);
  float* ffw_t = alloc(cS * 128);
  float* LWc   = alloc((size_t)588 * 128);
  float* b1te  = alloc(128);
  float* fmc   = alloc((size_t)cS * cHC * cWC * cC);
  float* arp   = alloc((size_t)cS * 196 * cC);
  float* fmf   = alloc((size_t)cS * cHF * cWF * cC);
  float* stats = alloc(cS * cC * 2);
  float* pf1   = alloc((size_t)cS * 50 * 60 * cC);
  float* pf2   = alloc((size_t)cS * 25 * 30 * cC);
  float* pf3   = alloc((size_t)cS * 12 * 15 * cC);
  float* f0f   = alloc((size_t)cN * cC);
  float* xys0  = alloc(cN * 2);
  float* cofA  = alloc((size_t)cS * cN * 2);
  float* cofB  = alloc((size_t)cS * cN * 2);
  float* fco   = alloc((size_t)cN * cS * 588);

  // frame_flow + shared MLP precomputes
  k_ffp<<<dim3(cS, cNCH, 2), 128, 0, stream>>>(rgbs, w1s, w1t, ffp);
  k_ffw_red<<<dim3(cS, 2), 128, 0, stream>>>(ffp, ffw_s, ffw_t);
  k_lwc<<<148, 128, 0, stream>>>(lw, lb, w1t, b1t, LWc, b1te);

  // ---- coarse stage ----
  k_convc<<<dim3(cS, cC), 256, 0, stream>>>(rgbs, fnw, fmc);
  k_pyrc<<<cS, 256, 0, stream>>>(fmc, arp);
  k_mlp_coarse<<<256, 128, 0, stream>>>(arp, fmc, w1s, b1s, ffw_s, w2s, b2s, pts, cofA, out);

  // ---- fine stage ----
  hipMemsetAsync(stats, 0, (size_t)cS * cC * 2 * sizeof(float), stream);
  k_convf<<<dim3(cS, cHF), 256, 0, stream>>>(rgbs, fnfw, fmf, stats);
  k_normf<<<2048, 256, 0, stream>>>(fmf, stats);
  k_pool<<<dim3(cS, 50), 256, 0, stream>>>(fmf, pf1, 100, 120, 50, 60);
  k_pool<<<dim3(cS, 25), 256, 0, stream>>>(pf1, pf2, 50, 60, 25, 30);
  k_pool<<<dim3(cS, 12), 256, 0, stream>>>(pf2, pf3, 25, 30, 12, 15);
  k_sample_f0<<<cN, 64, 0, stream>>>(fmf, cHF, cWF, cofA, 1.0f, f0f, xys0);

  float* cbuf[2] = {cofA, cofB};
  for (int it = 0; it < cITERS; it++) {
    float* cur = cbuf[it & 1];
    float* nxt = cbuf[(it & 1) ^ 1];
    k_corr<<<1024, 256, 0, stream>>>(fmf, pf1, pf2, pf3, f0f, cur, fco);
    k_mlp_fine<<<256, 256, 0, stream>>>(fco, LWc, b1te, ffw_t, w1t, w2t, b2t, cur, nxt,
                                        xys0, out + (size_t)(it + 1) * cS * cN * 2);
  }
}

// Round 5
// 271.410 us; speedup vs baseline: 2.5270x; 1.1374x over previous
//
#include <hip/hip_runtime.h>

// ---- problem constants (from reference setup_inputs) ----
constexpr int cS = 16, cN = 64, cH = 200, cW = 240;
constexpr int cHC = 25, cWC = 30;          // coarse fmap (stride 8)
constexpr int cHF = 100, cWF = 120;        // fine fmap (stride 2)
constexpr int cC = 64;                     // LAT
constexpr int cITERS = 4;                  // setup_inputs fixed
constexpr int cCHUNK = 60, cNCH = 50;      // ffw split

typedef _Float16 half8 __attribute__((ext_vector_type(8)));

// ---------------------------------------------------------------------------
// helpers
// ---------------------------------------------------------------------------
__device__ __forceinline__ float bilin_hwc(const float* __restrict__ fm, int Hh, int Ww,
                                           float x, float y, int c) {
  x = fminf(fmaxf(x, -2.0e6f), 2.0e6f);
  y = fminf(fmaxf(y, -2.0e6f), 2.0e6f);
  float x0f = floorf(x), y0f = floorf(y);
  int ix = (int)x0f, iy = (int)y0f;
  float wx = x - x0f, wy = y - y0f;
  float acc = 0.f;
  bool vx0 = (ix >= 0) && (ix < Ww), vx1 = (ix + 1 >= 0) && (ix + 1 < Ww);
  bool vy0 = (iy >= 0) && (iy < Hh), vy1 = (iy + 1 >= 0) && (iy + 1 < Hh);
  if (vy0 && vx0) acc += fm[(iy * Ww + ix) * cC + c] * (1.f - wy) * (1.f - wx);
  if (vy0 && vx1) acc += fm[(iy * Ww + ix + 1) * cC + c] * (1.f - wy) * wx;
  if (vy1 && vx0) acc += fm[((iy + 1) * Ww + ix) * cC + c] * wy * (1.f - wx);
  if (vy1 && vx1) acc += fm[((iy + 1) * Ww + ix + 1) * cC + c] * wy * wx;
  return acc;
}

// raw fp16 bilinear gather; also returns sum of in-bounds tap weights (for
// zero-padding-correct affine folding: featn = rstd*(raw - mean*wsum)).
__device__ __forceinline__ float bilin_raw_h(const _Float16* __restrict__ fm, int Hh, int Ww,
                                             float x, float y, int c, float& wsum) {
  x = fminf(fmaxf(x, -2.0e6f), 2.0e6f);
  y = fminf(fmaxf(y, -2.0e6f), 2.0e6f);
  float x0f = floorf(x), y0f = floorf(y);
  int ix = (int)x0f, iy = (int)y0f;
  float wx = x - x0f, wy = y - y0f;
  float acc = 0.f; wsum = 0.f;
  bool vx0 = (ix >= 0) && (ix < Ww), vx1 = (ix + 1 >= 0) && (ix + 1 < Ww);
  bool vy0 = (iy >= 0) && (iy < Hh), vy1 = (iy + 1 >= 0) && (iy + 1 < Hh);
  float w00 = (1.f - wy) * (1.f - wx), w01 = (1.f - wy) * wx;
  float w10 = wy * (1.f - wx), w11 = wy * wx;
  if (vy0 && vx0) { acc += (float)fm[(iy * Ww + ix) * cC + c] * w00; wsum += w00; }
  if (vy0 && vx1) { acc += (float)fm[(iy * Ww + ix + 1) * cC + c] * w01; wsum += w01; }
  if (vy1 && vx0) { acc += (float)fm[((iy + 1) * Ww + ix) * cC + c] * w10; wsum += w10; }
  if (vy1 && vx1) { acc += (float)fm[((iy + 1) * Ww + ix + 1) * cC + c] * w11; wsum += w11; }
  return acc;
}

// ---------------------------------------------------------------------------
// fused frame_flow + partial GEMV. block (s, ch, t): recompute ff row ch (60
// vals) in LDS, then partial dot into part[t][s][ch][j].
// ---------------------------------------------------------------------------
__global__ __launch_bounds__(128) void k_ffp(const float* __restrict__ rgbs,
                                             const float* __restrict__ w1s,
                                             const float* __restrict__ w1t,
                                             float* __restrict__ part) {
  int s = blockIdx.x, ch = blockIdx.y, t = blockIdx.z;
  int j = threadIdx.x;
  __shared__ float fr[cCHUNK];
  if (j < cCHUNK) {
    const float a = 2.0f / 255.0f;
    const float* cur = rgbs + (size_t)s * cH * cW;
    const float* prev = rgbs + (size_t)(s - 1) * cH * cW;
    const float* last = rgbs + (size_t)15 * cH * cW;
    int y = 4 * ch + 1, x = 4 * j + 1;
    float v = 0.f;
    #pragma unroll
    for (int dy = 0; dy < 2; dy++)
      #pragma unroll
      for (int dx = 0; dx < 2; dx++) {
        int id = (y + dy) * cW + (x + dx);
        float pv = (s == 0) ? (a * last[id] - 1.0f) : (a * (cur[id] - prev[id]));
        v += pv;
      }
    fr[j] = 0.25f * v;
  }
  __syncthreads();
  const float* w = (t == 0) ? (w1s + (size_t)198 * 128) : (w1t + (size_t)394 * 128);
  const float* wr = w + (size_t)ch * cCHUNK * 128 + j;
  float acc = 0.f;
  #pragma unroll 4
  for (int i = 0; i < cCHUNK; i++) acc += fr[i] * wr[(size_t)i * 128];
  part[(((size_t)t * cS + s) * cNCH + ch) * 128 + j] = acc;
}

__global__ void k_ffw_red(const float* __restrict__ part, float* __restrict__ ffw_s,
                          float* __restrict__ ffw_t) {
  int s = blockIdx.x, t = blockIdx.y, j = threadIdx.x;
  const float* p = part + (((size_t)t * cS + s) * cNCH) * 128 + j;
  float acc = 0.f;
  for (int c = 0; c < cNCH; c++) acc += p[(size_t)c * 128];
  ((t == 0) ? ffw_s : ffw_t)[s * 128 + j] = acc;
}

// LWc[k][j] = sum_m lw[k][m]*w1t[m][j]. 4 k-rows per block.
// block 147: b1te = dbt_b1 + lb @ W1[0:392]
__global__ __launch_bounds__(128) void k_lwc(const float* __restrict__ lw, const float* __restrict__ lb,
                                             const float* __restrict__ w1t, const float* __restrict__ b1t,
                                             float* __restrict__ LWc, float* __restrict__ b1te) {
  int bid = blockIdx.x, j = threadIdx.x;
  if (bid < 147) {
    int k0 = bid * 4;
    const float* l0 = lw + (size_t)(k0 + 0) * 392;
    const float* l1 = lw + (size_t)(k0 + 1) * 392;
    const float* l2 = lw + (size_t)(k0 + 2) * 392;
    const float* l3 = lw + (size_t)(k0 + 3) * 392;
    float a0 = 0.f, a1 = 0.f, a2 = 0.f, a3 = 0.f;
    for (int m = 0; m < 392; m++) {
      float wv = w1t[(size_t)m * 128 + j];
      a0 += l0[m] * wv; a1 += l1[m] * wv; a2 += l2[m] * wv; a3 += l3[m] * wv;
    }
    LWc[(size_t)(k0 + 0) * 128 + j] = a0;
    LWc[(size_t)(k0 + 1) * 128 + j] = a1;
    LWc[(size_t)(k0 + 2) * 128 + j] = a2;
    LWc[(size_t)(k0 + 3) * 128 + j] = a3;
  } else {
    float acc = b1t[j];
    for (int m = 0; m < 392; m++) acc += lb[m] * w1t[(size_t)m * 128 + j];
    b1te[j] = acc;
  }
}

// ---------------------------------------------------------------------------
// coarse encoder: conv 8x8 stride 8 + instance norm, output HWC [16][750][64]
// ---------------------------------------------------------------------------
__global__ __launch_bounds__(256) void k_convc(const float* __restrict__ rgbs,
                                               const float* __restrict__ wc,
                                               float* __restrict__ fm) {
  int q = blockIdx.x, c = blockIdx.y;
  int tid = threadIdx.x;
  __shared__ float wl[64];
  __shared__ float red[256];
  if (tid < 64) wl[tid] = wc[c * 64 + tid];
  __syncthreads();
  const float a = 2.0f / 255.0f;
  const float* img = rgbs + (size_t)q * cH * cW;
  float vals[3];
  float sum = 0.f, ss = 0.f;
  #pragma unroll
  for (int i = 0; i < 3; i++) {
    int pos = tid + i * 256;
    float v = 0.f;
    if (pos < 750) {
      int y = pos / cWC, x = pos % cWC;
      const float* base = img + (y * 8) * cW + x * 8;
      float acc = 0.f, wsum = 0.f;
      for (int ky = 0; ky < 8; ky++)
        #pragma unroll
        for (int kx = 0; kx < 8; kx++) {
          float wv = wl[ky * 8 + kx];
          acc += wv * base[ky * cW + kx];
          wsum += wv;
        }
      v = a * acc - wsum;  // b = -1 folded: conv(2p/255 - 1)
      sum += v; ss += v * v;
    }
    vals[i] = v;
  }
  red[tid] = sum; __syncthreads();
  for (int st = 128; st > 0; st >>= 1) { if (tid < st) red[tid] += red[tid + st]; __syncthreads(); }
  float tsum = red[0]; __syncthreads();
  red[tid] = ss; __syncthreads();
  for (int st = 128; st > 0; st >>= 1) { if (tid < st) red[tid] += red[tid + st]; __syncthreads(); }
  float tss = red[0];
  float mean = tsum / 750.0f;
  float var = tss / 750.0f - mean * mean;
  float rstd = rsqrtf(var + 1e-5f);
  #pragma unroll
  for (int i = 0; i < 3; i++) {
    int pos = tid + i * 256;
    if (pos < 750) fm[((size_t)q * 750 + pos) * cC + c] = (vals[i] - mean) * rstd;
  }
}

// ---------------------------------------------------------------------------
// fused coarse pyramid (3 pools in LDS) + averaged-resize (arp). block = q.
// ---------------------------------------------------------------------------
__global__ __launch_bounds__(256) void k_pyrc(const float* __restrict__ fmc,
                                              float* __restrict__ arp) {
  int q = blockIdx.x, tid = threadIdx.x;
  __shared__ float pc1[12 * 15 * 64];
  __shared__ float pc2[6 * 7 * 64];
  __shared__ float pc3[3 * 3 * 64];
  const float* L0 = fmc + (size_t)q * 750 * cC;
  for (int i = tid; i < 12 * 15 * 64; i += 256) {
    int c = i & 63, pos = i >> 6, oy = pos / 15, ox = pos % 15;
    const float* b = L0 + ((2 * oy) * 30 + 2 * ox) * cC + c;
    pc1[i] = 0.25f * (b[0] + b[cC] + b[30 * cC] + b[30 * cC + cC]);
  }
  __syncthreads();
  for (int i = tid; i < 6 * 7 * 64; i += 256) {
    int c = i & 63, pos = i >> 6, oy = pos / 7, ox = pos % 7;
    const float* b = pc1 + ((2 * oy) * 15 + 2 * ox) * cC + c;
    pc2[i] = 0.25f * (b[0] + b[cC] + b[15 * cC] + b[15 * cC + cC]);
  }
  __syncthreads();
  for (int i = tid; i < 3 * 3 * 64; i += 256) {
    int c = i & 63, pos = i >> 6, oy = pos / 3, ox = pos % 3;
    const float* b = pc2 + ((2 * oy) * 7 + 2 * ox) * cC + c;
    pc3[i] = 0.25f * (b[0] + b[cC] + b[7 * cC] + b[7 * cC + cC]);
  }
  __syncthreads();
  const int Hs[4] = {25, 12, 6, 3}, Ws[4] = {30, 15, 7, 3};
  for (int i = tid; i < 196 * 64; i += 256) {
    int c = i & 63, pos = i >> 6, o = pos / 14, p = pos % 14;
    float acc = 0.f;
    #pragma unroll
    for (int l = 0; l < 4; l++) {
      float yy = (float)(o * (Hs[l] - 1)) / 13.0f;
      float xx = (float)(p * (Ws[l] - 1)) / 13.0f;
      int y0 = (int)floorf(yy); int y1 = min(y0 + 1, Hs[l] - 1); float wy = yy - (float)y0;
      int x0 = (int)floorf(xx); int x1 = min(x0 + 1, Ws[l] - 1); float wx = xx - (float)x0;
      const float* L = (l == 0) ? L0 : ((l == 1) ? pc1 : ((l == 2) ? pc2 : pc3));
      float v00 = L[(y0 * Ws[l] + x0) * cC + c], v01 = L[(y0 * Ws[l] + x1) * cC + c];
      float v10 = L[(y1 * Ws[l] + x0) * cC + c], v11 = L[(y1 * Ws[l] + x1) * cC + c];
      acc += (v00 * (1.f - wy) + v10 * wy) * (1.f - wx) + (v01 * (1.f - wy) + v11 * wy) * wx;
    }
    arp[((size_t)q * 196 + pos) * cC + c] = acc * 0.25f * 0.125f;
  }
}

// ---------------------------------------------------------------------------
// fine encoder: conv 2x2 stride 2, RAW fp16 HWC output + per-(q,c) stats atomics
// (instance norm is affine-folded downstream; pooling commutes with it).
// ---------------------------------------------------------------------------
__global__ __launch_bounds__(256) void k_convf(const float* __restrict__ rgbs,
                                               const float* __restrict__ wf,
                                               _Float16* __restrict__ fm,
                                               float* __restrict__ stats) {
  int q = blockIdx.x, y = blockIdx.y;
  int lane = threadIdx.x & 63, wv = threadIdx.x >> 6;
  float w0 = wf[lane * 4 + 0], w1 = wf[lane * 4 + 1], w2 = wf[lane * 4 + 2], w3 = wf[lane * 4 + 3];
  float wsum = w0 + w1 + w2 + w3;
  const float a = 2.0f / 255.0f;
  const float* img = rgbs + (size_t)q * cH * cW;
  float sum = 0.f, ss = 0.f;
  for (int x = wv; x < cWF; x += 4) {
    const float* b = img + (2 * y) * cW + 2 * x;
    float v = a * (w0 * b[0] + w1 * b[1] + w2 * b[cW] + w3 * b[cW + 1]) - wsum;
    fm[(((size_t)q * cHF + y) * cWF + x) * cC + lane] = (_Float16)v;
    sum += v; ss += v * v;
  }
  __shared__ float red[2][4][64];
  red[0][wv][lane] = sum; red[1][wv][lane] = ss;
  __syncthreads();
  if (wv == 0) {
    float s4 = red[0][0][lane] + red[0][1][lane] + red[0][2][lane] + red[0][3][lane];
    float q4 = red[1][0][lane] + red[1][1][lane] + red[1][2][lane] + red[1][3][lane];
    atomicAdd(&stats[(q * 64 + lane) * 2 + 0], s4);
    atomicAdd(&stats[(q * 64 + lane) * 2 + 1], q4);
  }
}

// ---------------------------------------------------------------------------
// fused fine pyramid: one read of fmf -> pf1 (50x60), pf2 (25x30), pf3 (12x15),
// all raw fp16 (pf1/pf2 exact 2x/4x avgs; pf3 8x avg of rows 0..95).
// grid (q, 13): block b<12 -> pf1 rows 4b..4b+3, pf2 rows 2b..2b+1, pf3 row b;
// block 12 -> pf1 rows 48,49 + pf2 row 24.
// ---------------------------------------------------------------------------
__global__ __launch_bounds__(256) void k_pyrf(const _Float16* __restrict__ fmf,
                                              _Float16* __restrict__ pf1,
                                              _Float16* __restrict__ pf2,
                                              _Float16* __restrict__ pf3) {
  int q = blockIdx.x, b = blockIdx.y, tid = threadIdx.x;
  __shared__ _Float16 l1[4 * 60 * 64];
  __shared__ _Float16 l2[2 * 30 * 64];
  int nr1 = (b == 12) ? 2 : 4;
  const _Float16* F = fmf + (size_t)q * cHF * cWF * cC;
  for (int i = tid; i < nr1 * 60 * 64; i += 256) {
    int c = i & 63, pos = i >> 6, rl = pos / 60, ox = pos % 60;
    int r1 = 4 * b + rl;
    const _Float16* p = F + ((size_t)(2 * r1) * cWF + 2 * ox) * cC + c;
    float v = 0.25f * ((float)p[0] + (float)p[cC] + (float)p[cWF * cC] + (float)p[cWF * cC + cC]);
    _Float16 h = (_Float16)v;
    l1[i] = h;
    pf1[(((size_t)q * 50 + r1) * 60 + ox) * cC + c] = h;
  }
  __syncthreads();
  int nr2 = (b == 12) ? 1 : 2;
  for (int i = tid; i < nr2 * 30 * 64; i += 256) {
    int c = i & 63, pos = i >> 6, rl = pos / 30, ox = pos % 30;
    const _Float16* p = l1 + ((2 * rl) * 60 + 2 * ox) * 64 + c;
    float v = 0.25f * ((float)p[0] + (float)p[64] + (float)p[60 * 64] + (float)p[60 * 64 + 64]);
    _Float16 h = (_Float16)v;
    l2[i] = h;
    pf2[(((size_t)q * 25 + 2 * b + rl) * 30 + ox) * cC + c] = h;
  }
  __syncthreads();
  if (b < 12) {
    for (int i = tid; i < 15 * 64; i += 256) {
      int c = i & 63, ox = i >> 6;
      const _Float16* p = l2 + (2 * ox) * 64 + c;
      float v = 0.25f * ((float)p[0] + (float)p[64] + (float)p[30 * 64] + (float)p[30 * 64 + 64]);
      pf3[(((size_t)q * 12 + b) * 15 + ox) * cC + c] = (_Float16)v;
    }
  }
}

// sample frame-0 normalized features from raw fp16 fmf + stats
__global__ void k_sample_f0(const _Float16* __restrict__ fm, const float* __restrict__ stats,
                            const float* __restrict__ psrc, float* __restrict__ out,
                            float* __restrict__ xys) {
  int n = blockIdx.x, c = threadIdx.x;
  float x = psrc[n * 2 + 0], y = psrc[n * 2 + 1];
  float ws;
  float raw = bilin_raw_h(fm, cHF, cWF, x, y, c, ws);
  float su = stats[c * 2 + 0], qq = stats[c * 2 + 1];
  float mean = su / 12000.f, var = qq / 12000.f - mean * mean;
  float rstd = rsqrtf(var + 1e-5f);
  out[n * cC + c] = (raw - mean * ws) * rstd;
  if (c < 2) xys[n * 2 + c] = (c == 0) ? x : y;
}

// fused corr + in-block shifted feats + window-sample, raw fp16 pyramid with
// instance-norm affine folded into the feature vectors + per-level bias.
// grid = 1024 (XCD swizzle), block = 256 = 4 waves = 4 pyramid levels.
__global__ __launch_bounds__(256) void k_corr(const _Float16* __restrict__ p0, const _Float16* __restrict__ p1,
                                              const _Float16* __restrict__ p2, const _Float16* __restrict__ p3,
                                              const float* __restrict__ f0, const float* __restrict__ stats,
                                              const float* __restrict__ coords, float* __restrict__ fco) {
  int bid = blockIdx.x;
  int w = (bid & 7) * 128 + (bid >> 3);
  int s = w >> 6, n = w & 63;
  __shared__ float feat2[3][64];
  __shared__ float biasS[3];
  int tid = threadIdx.x;
  {
    int t = tid >> 6, c = tid & 63;
    if (t < 3) {
      float sS = stats[(s * 64 + c) * 2 + 0], qS = stats[(s * 64 + c) * 2 + 1];
      float meanS = sS / 12000.f, varS = qS / 12000.f - meanS * meanS;
      float rstdS = rsqrtf(varS + 1e-5f);
      float featn;
      if (t == 0) {
        featn = f0[(size_t)n * cC + c];
      } else {
        int ssrc = max(s - 2 * t, 0);
        float s2 = stats[(ssrc * 64 + c) * 2 + 0], q2 = stats[(ssrc * 64 + c) * 2 + 1];
        float m2 = s2 / 12000.f, v2 = q2 / 12000.f - m2 * m2;
        float r2 = rsqrtf(v2 + 1e-5f);
        float fx = coords[((size_t)ssrc * cN + n) * 2 + 0];
        float fy = coords[((size_t)ssrc * cN + n) * 2 + 1];
        float ws;
        float raw = bilin_raw_h(p0 + (size_t)ssrc * cHF * cWF * cC, cHF, cWF, fx, fy, c, ws);
        featn = (raw - m2 * ws) * r2;
      }
      feat2[t][c] = featn * rstdS * 0.125f;        // 1/sqrt(64) folded
      float bc = featn * (-meanS * rstdS) * 0.125f;
      #pragma unroll
      for (int o = 32; o; o >>= 1) bc += __shfl_xor(bc, o);
      if (c == 0) biasS[t] = bc;
    }
  }
  __syncthreads();
  int l = tid >> 6, lane = tid & 63;
  const _Float16* Ls[4] = {p0, p1, p2, p3};
  const int Hs[4] = {cHF, 50, 25, 12}, Ws[4] = {cWF, 60, 30, 15};
  float cx = coords[((size_t)s * cN + n) * 2 + 0];
  float cy = coords[((size_t)s * cN + n) * 2 + 1];
  float sc = 1.0f / (float)(1 << l);
  float x = fminf(fmaxf(cx * sc, -2.0e6f), 2.0e6f);
  float y = fminf(fmaxf(cy * sc, -2.0e6f), 2.0e6f);
  float x0f = floorf(x), y0f = floorf(y);
  float wx = x - x0f, wy = y - y0f;
  int dxi = lane & 7, dyi = lane >> 3;
  int ix = (int)x0f + dxi - 3, iy = (int)y0f + dyi - 3;
  int Hl = Hs[l], Wl = Ws[l];
  float d[3] = {0.f, 0.f, 0.f};
  if (ix >= 0 && ix < Wl && iy >= 0 && iy < Hl) {
    const _Float16* row = Ls[l] + (((size_t)s * Hl + iy) * Wl + ix) * cC;
    float a0 = 0.f, a1 = 0.f, a2 = 0.f;
    #pragma unroll
    for (int c8 = 0; c8 < 8; c8++) {
      half8 v = *(const half8*)(row + c8 * 8);
      #pragma unroll
      for (int e = 0; e < 8; e++) {
        float f = (float)v[e];
        a0 += f * feat2[0][c8 * 8 + e];
        a1 += f * feat2[1][c8 * 8 + e];
        a2 += f * feat2[2][c8 * 8 + e];
      }
    }
    d[0] = a0 + biasS[0]; d[1] = a1 + biasS[1]; d[2] = a2 + biasS[2];
  }
  int dy = lane / 7, dx = lane - dy * 7;
  int bb = (lane < 49) ? (dy * 8 + dx) : 0;
  float w00 = (1.f - wy) * (1.f - wx), w01 = (1.f - wy) * wx;
  float w10 = wy * (1.f - wx), w11 = wy * wx;
  float* dst = fco + ((size_t)n * cS + s) * 588 + l * 49 + lane;
  #pragma unroll
  for (int t = 0; t < 3; t++) {
    float d00 = __shfl(d[t], bb, 64);
    float d01 = __shfl(d[t], bb + 1, 64);
    float d10 = __shfl(d[t], bb + 8, 64);
    float d11 = __shfl(d[t], bb + 9, 64);
    if (lane < 49) dst[t * 196] = w00 * d00 + w01 * d01 + w10 * d10 + w11 * d11;
  }
}

// ---------------------------------------------------------------------------
// coarse MLP (fused f0-sample + coords update). Each block: 4 rows (n, sb..sb+3).
// NOTE: coarse flow term is exactly zero (coords are a broadcast pre-update).
// ---------------------------------------------------------------------------
__global__ __launch_bounds__(128) void k_mlp_coarse(const float* __restrict__ arp, const float* __restrict__ fmc,
                                                    const float* __restrict__ w1, const float* __restrict__ b1,
                                                    const float* __restrict__ ffw, const float* __restrict__ w2,
                                                    const float* __restrict__ b2,
                                                    const float* __restrict__ pts, float* __restrict__ cof,
                                                    float* __restrict__ out) {
  int n = blockIdx.x >> 2, sb = (blockIdx.x & 3) * 4;
  __shared__ float fc[4][196];
  __shared__ float f0l[64];
  __shared__ float hl[4][128];
  int j = threadIdx.x;
  float xx = pts[n * 2 + 0] * 0.125f, yy = pts[n * 2 + 1] * 0.125f;
  if (j < 64) f0l[j] = bilin_hwc(fmc, cHC, cWC, xx, yy, j);
  __syncthreads();
  #pragma unroll
  for (int r = 0; r < 4; r++) {
    int s = sb + r;
    for (int k = j; k < 196; k += 128) {
      const float4* b4 = (const float4*)(arp + ((size_t)s * 196 + k) * cC);
      float acc = 0.f;
      #pragma unroll
      for (int c4 = 0; c4 < 16; c4++) {
        float4 v = b4[c4];
        acc += v.x * f0l[c4 * 4 + 0] + v.y * f0l[c4 * 4 + 1] +
               v.z * f0l[c4 * 4 + 2] + v.w * f0l[c4 * 4 + 3];
      }
      fc[r][k] = acc;
    }
  }
  __syncthreads();
  float h0 = 0.f, h1 = 0.f, h2 = 0.f, h3 = 0.f;
  for (int k = 0; k < 196; k++) {
    float wv = w1[(size_t)k * 128 + j];
    h0 += fc[0][k] * wv; h1 += fc[1][k] * wv; h2 += fc[2][k] * wv; h3 += fc[3][k] * wv;
  }
  float hh[4] = {h0, h1, h2, h3};
  const float* Wxy = w1 + (size_t)3198 * 128;
  #pragma unroll
  for (int r = 0; r < 4; r++) {
    int s = sb + r;
    float v = hh[r] + b1[j] + ffw[s * 128 + j] + xx * Wxy[j] + yy * Wxy[128 + j];
    hl[r][j] = fmaxf(v, 0.f);
  }
  __syncthreads();
  if (j < 8) {
    int r = j >> 1, d = j & 1;
    float acc = b2[d];
    for (int k = 0; k < 128; k++) acc += hl[r][k] * w2[k * 2 + d];
    int s = sb + r;
    float base = pts[n * 2 + d] * 0.125f;
    float cc = base + acc;
    out[((size_t)s * cN + n) * 2 + d] = cc * 8.0f;   // preds[0]
    cof[((size_t)s * cN + n) * 2 + d] = cc * 4.0f;   // fine coords init
  }
}

// fine MLP: 256 threads (K split in 2 halves of 294) + fused coords update.
__global__ __launch_bounds__(256) void k_mlp_fine(const float* __restrict__ fco, const float* __restrict__ LWc,
                                                  const float* __restrict__ b1e, const float* __restrict__ ffw,
                                                  const float* __restrict__ w1t, const float* __restrict__ w2,
                                                  const float* __restrict__ b2, const float* __restrict__ cof_cur,
                                                  float* __restrict__ cof_nxt, const float* __restrict__ xys,
                                                  float* __restrict__ out) {
  int n = blockIdx.x >> 2, sb = (blockIdx.x & 3) * 4;
  __shared__ float fc[4][588];
  __shared__ float hp[2][4][128];
  __shared__ float hl[4][128];
  int tid = threadIdx.x;
  int j = tid & 127, half = tid >> 7;
  #pragma unroll
  for (int r = 0; r < 4; r++)
    for (int k = tid; k < 588; k += 256) fc[r][k] = fco[((size_t)n * cS + sb + r) * 588 + k];
  __syncthreads();
  float h0 = 0.f, h1 = 0.f, h2 = 0.f, h3 = 0.f;
  int k0 = half * 294;
  for (int k = k0; k < k0 + 294; k++) {
    float wv = LWc[(size_t)k * 128 + j];
    h0 += fc[0][k] * wv; h1 += fc[1][k] * wv; h2 += fc[2][k] * wv; h3 += fc[3][k] * wv;
  }
  hp[half][0][j] = h0; hp[half][1][j] = h1; hp[half][2][j] = h2; hp[half][3][j] = h3;
  __syncthreads();
  if (half == 0) {
    const float* Wfl = w1t + (size_t)392 * 128;
    const float* Wxy = w1t + (size_t)3394 * 128;
    float xx = xys[n * 2 + 0], yy = xys[n * 2 + 1];
    #pragma unroll
    for (int r = 0; r < 4; r++) {
      int s = sb + r;
      int sA = min(s + 1, 15), sB = (s == 15) ? 14 : s;
      float flx = cof_cur[(sA * cN + n) * 2 + 0] - cof_cur[(sB * cN + n) * 2 + 0];
      float fly = cof_cur[(sA * cN + n) * 2 + 1] - cof_cur[(sB * cN + n) * 2 + 1];
      float v = hp[0][r][j] + hp[1][r][j] + b1e[j] + ffw[s * 128 + j] +
                flx * Wfl[j] + fly * Wfl[128 + j] + xx * Wxy[j] + yy * Wxy[128 + j];
      hl[r][j] = fmaxf(v, 0.f);
    }
  }
  __syncthreads();
  if (tid < 8) {
    int r = tid >> 1, d = tid & 1;
    float acc = b2[d];
    for (int k = 0; k < 128; k++) acc += hl[r][k] * w2[k * 2 + d];
    int s = sb + r;
    float cc = cof_cur[((size_t)s * cN + n) * 2 + d] + acc;
    cof_nxt[((size_t)s * cN + n) * 2 + d] = cc;
    out[((size_t)s * cN + n) * 2 + d] = cc * 2.0f;
  }
}

// ---------------------------------------------------------------------------
extern "C" void kernel_launch(void* const* d_in, const int* in_sizes, int n_in,
                              void* d_out, int out_size, void* d_ws, size_t ws_size,
                              hipStream_t stream) {
  (void)in_sizes; (void)n_in; (void)out_size; (void)ws_size;
  const float* rgbs = (const float*)d_in[0];
  const float* pts  = (const float*)d_in[1];
  const float* fnw  = (const float*)d_in[2];
  const float* fnfw = (const float*)d_in[3];
  const float* lw   = (const float*)d_in[4];
  const float* lb   = (const float*)d_in[5];
  const float* w1s  = (const float*)d_in[6];
  const float* b1s  = (const float*)d_in[7];
  const float* w2s  = (const float*)d_in[8];
  const float* b2s  = (const float*)d_in[9];
  const float* w1t  = (const float*)d_in[10];
  const float* b1t  = (const float*)d_in[11];
  const float* w2t  = (const float*)d_in[12];
  const float* b2t  = (const float*)d_in[13];
  float* out = (float*)d_out;

  float* p = (float*)d_ws;
  auto alloc = [&](size_t nf) { float* r = p; p += nf; return r; };
  float* ffp   = alloc((size_t)2 * cS * cNCH * 128);
  float* ffw_s = alloc(cS * 128);
  float* ffw_t = alloc(cS * 128);
  float* LWc   = alloc((size_t)588 * 128);
  float* b1te  = alloc(128);
  float* fmc   = alloc((size_t)cS * cHC * cWC * cC);
  float* arp   = alloc((size_t)cS * 196 * cC);
  float* stats = alloc(cS * cC * 2);
  _Float16* fmf = (_Float16*)alloc((size_t)cS * cHF * cWF * cC / 2);
  _Float16* pf1 = (_Float16*)alloc((size_t)cS * 50 * 60 * cC / 2);
  _Float16* pf2 = (_Float16*)alloc((size_t)cS * 25 * 30 * cC / 2);
  _Float16* pf3 = (_Float16*)alloc((size_t)cS * 12 * 15 * cC / 2);
  float* f0f   = alloc((size_t)cN * cC);
  float* xys0  = alloc(cN * 2);
  float* cofA  = alloc((size_t)cS * cN * 2);
  float* cofB  = alloc((size_t)cS * cN * 2);
  float* fco   = alloc((size_t)cN * cS * 588);

  // frame_flow + shared MLP precomputes
  k_ffp<<<dim3(cS, cNCH, 2), 128, 0, stream>>>(rgbs, w1s, w1t, ffp);
  k_ffw_red<<<dim3(cS, 2), 128, 0, stream>>>(ffp, ffw_s, ffw_t);
  k_lwc<<<148, 128, 0, stream>>>(lw, lb, w1t, b1t, LWc, b1te);

  // ---- coarse stage ----
  k_convc<<<dim3(cS, cC), 256, 0, stream>>>(rgbs, fnw, fmc);
  k_pyrc<<<cS, 256, 0, stream>>>(fmc, arp);
  k_mlp_coarse<<<256, 128, 0, stream>>>(arp, fmc, w1s, b1s, ffw_s, w2s, b2s, pts, cofA, out);

  // ---- fine stage ----
  hipMemsetAsync(stats, 0, (size_t)cS * cC * 2 * sizeof(float), stream);
  k_convf<<<dim3(cS, cHF), 256, 0, stream>>>(rgbs, fnfw, fmf, stats);
  k_pyrf<<<dim3(cS, 13), 256, 0, stream>>>(fmf, pf1, pf2, pf3);
  k_sample_f0<<<cN, 64, 0, stream>>>(fmf, stats, cofA, f0f, xys0);

  float* cbuf[2] = {cofA, cofB};
  for (int it = 0; it < cITERS; it++) {
    float* cur = cbuf[it & 1];
    float* nxt = cbuf[(it & 1) ^ 1];
    k_corr<<<1024, 256, 0, stream>>>(fmf, pf1, pf2, pf3, f0f, stats, cur, fco);
    k_mlp_fine<<<256, 256, 0, stream>>>(fco, LWc, b1te, ffw_t, w1t, w2t, b2t, cur, nxt,
                                        xys0, out + (size_t)(it + 1) * cS * cN * 2);
  }
}

// Round 6
// 192.884 us; speedup vs baseline: 3.5558x; 1.4071x over previous
//
#include <hip/hip_runtime.h>

// ---- problem constants (from reference setup_inputs) ----
constexpr int cS = 16, cN = 64, cH = 200, cW = 240;
constexpr int cHC = 25, cWC = 30;          // coarse fmap (stride 8)
constexpr int cHF = 100, cWF = 120;        // fine fmap (stride 2)
constexpr int cC = 64;                     // LAT
constexpr int cITERS = 4;                  // setup_inputs fixed
constexpr int cNCH = 50, cCHUNK = 60;      // ffw split

typedef _Float16 half8 __attribute__((ext_vector_type(8)));

// ---------------------------------------------------------------------------
// helpers
// ---------------------------------------------------------------------------
__device__ __forceinline__ float bilin_hwc(const float* __restrict__ fm, int Hh, int Ww,
                                           float x, float y, int c) {
  x = fminf(fmaxf(x, -2.0e6f), 2.0e6f);
  y = fminf(fmaxf(y, -2.0e6f), 2.0e6f);
  float x0f = floorf(x), y0f = floorf(y);
  int ix = (int)x0f, iy = (int)y0f;
  float wx = x - x0f, wy = y - y0f;
  float acc = 0.f;
  bool vx0 = (ix >= 0) && (ix < Ww), vx1 = (ix + 1 >= 0) && (ix + 1 < Ww);
  bool vy0 = (iy >= 0) && (iy < Hh), vy1 = (iy + 1 >= 0) && (iy + 1 < Hh);
  if (vy0 && vx0) acc += fm[(iy * Ww + ix) * cC + c] * (1.f - wy) * (1.f - wx);
  if (vy0 && vx1) acc += fm[(iy * Ww + ix + 1) * cC + c] * (1.f - wy) * wx;
  if (vy1 && vx0) acc += fm[((iy + 1) * Ww + ix) * cC + c] * wy * (1.f - wx);
  if (vy1 && vx1) acc += fm[((iy + 1) * Ww + ix + 1) * cC + c] * wy * wx;
  return acc;
}

// raw fp16 bilinear gather; returns sum of in-bounds tap weights (for
// zero-padding-correct affine folding: featn = rstd*(raw - mean*wsum)).
__device__ __forceinline__ float bilin_raw_h(const _Float16* __restrict__ fm, int Hh, int Ww,
                                             float x, float y, int c, float& wsum) {
  x = fminf(fmaxf(x, -2.0e6f), 2.0e6f);
  y = fminf(fmaxf(y, -2.0e6f), 2.0e6f);
  float x0f = floorf(x), y0f = floorf(y);
  int ix = (int)x0f, iy = (int)y0f;
  float wx = x - x0f, wy = y - y0f;
  float acc = 0.f; wsum = 0.f;
  bool vx0 = (ix >= 0) && (ix < Ww), vx1 = (ix + 1 >= 0) && (ix + 1 < Ww);
  bool vy0 = (iy >= 0) && (iy < Hh), vy1 = (iy + 1 >= 0) && (iy + 1 < Hh);
  float w00 = (1.f - wy) * (1.f - wx), w01 = (1.f - wy) * wx;
  float w10 = wy * (1.f - wx), w11 = wy * wx;
  if (vy0 && vx0) { acc += (float)fm[(iy * Ww + ix) * cC + c] * w00; wsum += w00; }
  if (vy0 && vx1) { acc += (float)fm[(iy * Ww + ix + 1) * cC + c] * w01; wsum += w01; }
  if (vy1 && vx0) { acc += (float)fm[((iy + 1) * Ww + ix) * cC + c] * w10; wsum += w10; }
  if (vy1 && vx1) { acc += (float)fm[((iy + 1) * Ww + ix + 1) * cC + c] * w11; wsum += w11; }
  return acc;
}

// ---------------------------------------------------------------------------
// k_front: role-partitioned mega-kernel. [0,800) ffp; [800,1824) convc;
// [1824,3424) convf.
// ---------------------------------------------------------------------------
constexpr int NB_FFP = 800, NB_CONVC = 1024, NB_CONVF = 1600;

__global__ __launch_bounds__(256) void k_front(const float* __restrict__ rgbs,
                                               const float* __restrict__ w1s,
                                               const float* __restrict__ w1t,
                                               const float* __restrict__ fnw,
                                               const float* __restrict__ fnfw,
                                               float* __restrict__ part,
                                               float* __restrict__ fmc,
                                               _Float16* __restrict__ fmf,
                                               float* __restrict__ partf) {
  __shared__ float smem[512];
  int bid = blockIdx.x, tid = threadIdx.x;
  const float a = 2.0f / 255.0f;

  if (bid < NB_FFP) {
    // ---- frame_flow row + partial GEMV (both t in one block) ----
    int s = bid / cNCH, ch = bid % cNCH;
    if (tid < cCHUNK) {
      const float* cur = rgbs + (size_t)s * cH * cW;
      const float* prev = rgbs + (size_t)(s - 1) * cH * cW;
      const float* last = rgbs + (size_t)15 * cH * cW;
      int y = 4 * ch + 1, x = 4 * tid + 1;
      float v = 0.f;
      #pragma unroll
      for (int dy = 0; dy < 2; dy++)
        #pragma unroll
        for (int dx = 0; dx < 2; dx++) {
          int id = (y + dy) * cW + (x + dx);
          float pv = (s == 0) ? (a * last[id] - 1.0f) : (a * (cur[id] - prev[id]));
          v += pv;
        }
      smem[tid] = 0.25f * v;
    }
    __syncthreads();
    int t = tid >> 7, j = tid & 127;
    const float* w = (t == 0) ? (w1s + (size_t)198 * 128) : (w1t + (size_t)394 * 128);
    const float* wr = w + (size_t)ch * cCHUNK * 128 + j;
    float acc = 0.f;
    #pragma unroll 4
    for (int i = 0; i < cCHUNK; i++) acc += smem[i] * wr[(size_t)i * 128];
    part[(((size_t)t * cS + s) * cNCH + ch) * 128 + j] = acc;

  } else if (bid < NB_FFP + NB_CONVC) {
    // ---- coarse conv 8x8 s8 + instance norm, HWC ----
    int idx = bid - NB_FFP;
    int q = idx >> 6, c = idx & 63;
    float* wl = smem;            // [64]
    float* red = smem + 64;      // [256]
    if (tid < 64) wl[tid] = fnw[c * 64 + tid];
    __syncthreads();
    const float* img = rgbs + (size_t)q * cH * cW;
    float vals[3];
    float sum = 0.f, ss = 0.f;
    #pragma unroll
    for (int i = 0; i < 3; i++) {
      int pos = tid + i * 256;
      float v = 0.f;
      if (pos < 750) {
        int y = pos / cWC, x = pos % cWC;
        const float* base = img + (y * 8) * cW + x * 8;
        float acc = 0.f, wsum = 0.f;
        for (int ky = 0; ky < 8; ky++)
          #pragma unroll
          for (int kx = 0; kx < 8; kx++) {
            float wv = wl[ky * 8 + kx];
            acc += wv * base[ky * cW + kx];
            wsum += wv;
          }
        v = a * acc - wsum;
        sum += v; ss += v * v;
      }
      vals[i] = v;
    }
    red[tid] = sum; __syncthreads();
    for (int st = 128; st > 0; st >>= 1) { if (tid < st) red[tid] += red[tid + st]; __syncthreads(); }
    float tsum = red[0]; __syncthreads();
    red[tid] = ss; __syncthreads();
    for (int st = 128; st > 0; st >>= 1) { if (tid < st) red[tid] += red[tid + st]; __syncthreads(); }
    float tss = red[0];
    float mean = tsum / 750.0f;
    float var = tss / 750.0f - mean * mean;
    float rstd = rsqrtf(var + 1e-5f);
    #pragma unroll
    for (int i = 0; i < 3; i++) {
      int pos = tid + i * 256;
      if (pos < 750) fmc[((size_t)q * 750 + pos) * cC + c] = (vals[i] - mean) * rstd;
    }

  } else {
    // ---- fine conv 2x2 s2, raw fp16 HWC + per-row (sum,ss) partials ----
    int idx = bid - NB_FFP - NB_CONVC;
    int q = idx / cHF, y = idx % cHF;
    int lane = tid & 63, wv = tid >> 6;
    float w0 = fnfw[lane * 4 + 0], w1 = fnfw[lane * 4 + 1];
    float w2 = fnfw[lane * 4 + 2], w3 = fnfw[lane * 4 + 3];
    float wsum = w0 + w1 + w2 + w3;
    const float* img = rgbs + (size_t)q * cH * cW;
    float sum = 0.f, ss = 0.f;
    for (int x = wv; x < cWF; x += 4) {
      const float* b = img + (2 * y) * cW + 2 * x;
      float v = a * (w0 * b[0] + w1 * b[1] + w2 * b[cW] + w3 * b[cW + 1]) - wsum;
      fmf[(((size_t)q * cHF + y) * cWF + x) * cC + lane] = (_Float16)v;
      sum += v; ss += v * v;
    }
    float* red = smem;  // [2][4][64]
    red[(0 * 4 + wv) * 64 + lane] = sum;
    red[(1 * 4 + wv) * 64 + lane] = ss;
    __syncthreads();
    if (wv == 0) {
      float s4 = red[0 * 64 + lane] + red[1 * 64 + lane] + red[2 * 64 + lane] + red[3 * 64 + lane];
      float q4 = red[(4 + 0) * 64 + lane] + red[(4 + 1) * 64 + lane] +
                 red[(4 + 2) * 64 + lane] + red[(4 + 3) * 64 + lane];
      size_t o = ((size_t)q * cHF + y) * 64 + lane;
      partf[o * 2 + 0] = s4;
      partf[o * 2 + 1] = q4;
    }
  }
}

// ---------------------------------------------------------------------------
// k_mid: [0,16) ffw_red; [16,91) LWc + b1te; [91,107) stats reduce;
// [107,123) coarse pyramid + arp.
// ---------------------------------------------------------------------------
__global__ __launch_bounds__(256) void k_mid(const float* __restrict__ part,
                                             float* __restrict__ ffw_s, float* __restrict__ ffw_t,
                                             const float* __restrict__ lw, const float* __restrict__ lb,
                                             const float* __restrict__ w1t, const float* __restrict__ b1t,
                                             _Float16* __restrict__ LWc, float* __restrict__ b1te,
                                             const float* __restrict__ partf, float* __restrict__ stats,
                                             const float* __restrict__ fmc, float* __restrict__ arp) {
  __shared__ float smem[14784];
  int bid = blockIdx.x, tid = threadIdx.x;

  if (bid < 16) {
    // ---- ffw reduce ----
    int s = bid, t = tid >> 7, j = tid & 127;
    const float* p = part + (((size_t)t * cS + s) * cNCH) * 128 + j;
    float acc = 0.f;
    for (int c = 0; c < cNCH; c++) acc += p[(size_t)c * 128];
    ((t == 0) ? ffw_s : ffw_t)[s * 128 + j] = acc;

  } else if (bid < 91) {
    // ---- LWc (fp16) : 8 k-rows per block (4 per half) ----
    int b2 = bid - 16, g = tid >> 7, j = tid & 127;
    if (b2 < 74) {
      int k0 = b2 * 8 + g * 4;
      if (k0 < 588) {
        const float* l0 = lw + (size_t)(k0 + 0) * 392;
        const float* l1 = lw + (size_t)(k0 + 1) * 392;
        const float* l2 = lw + (size_t)(k0 + 2) * 392;
        const float* l3 = lw + (size_t)(k0 + 3) * 392;
        float a0 = 0.f, a1 = 0.f, a2 = 0.f, a3 = 0.f;
        for (int m = 0; m < 392; m++) {
          float wv = w1t[(size_t)m * 128 + j];
          a0 += l0[m] * wv; a1 += l1[m] * wv; a2 += l2[m] * wv; a3 += l3[m] * wv;
        }
        LWc[(size_t)(k0 + 0) * 128 + j] = (_Float16)a0;
        LWc[(size_t)(k0 + 1) * 128 + j] = (_Float16)a1;
        LWc[(size_t)(k0 + 2) * 128 + j] = (_Float16)a2;
        LWc[(size_t)(k0 + 3) * 128 + j] = (_Float16)a3;
      }
    } else if (g == 0) {
      float acc = b1t[j];
      for (int m = 0; m < 392; m++) acc += lb[m] * w1t[(size_t)m * 128 + j];
      b1te[j] = acc;
    }

  } else if (bid < 107) {
    // ---- stats reduce: 100 row-partials -> stats[(q*64+c)*2] ----
    int q = bid - 91, c = tid & 63, g = tid >> 6;
    float s0 = 0.f, s1 = 0.f;
    for (int yy = 0; yy < 25; yy++) {
      size_t o = ((size_t)q * cHF + g * 25 + yy) * 64 + c;
      s0 += partf[o * 2 + 0];
      s1 += partf[o * 2 + 1];
    }
    smem[g * 64 + c] = s0;
    smem[256 + g * 64 + c] = s1;
    __syncthreads();
    if (g == 0) {
      stats[(q * 64 + c) * 2 + 0] = smem[c] + smem[64 + c] + smem[128 + c] + smem[192 + c];
      stats[(q * 64 + c) * 2 + 1] = smem[256 + c] + smem[320 + c] + smem[384 + c] + smem[448 + c];
    }

  } else {
    // ---- coarse pyramid (3 pools in LDS) + averaged-resize arp ----
    int q = bid - 107;
    float* pc1 = smem;            // 12*15*64
    float* pc2 = smem + 11520;    // 6*7*64
    float* pc3 = smem + 14208;    // 3*3*64
    const float* L0 = fmc + (size_t)q * 750 * cC;
    for (int i = tid; i < 12 * 15 * 64; i += 256) {
      int c = i & 63, pos = i >> 6, oy = pos / 15, ox = pos % 15;
      const float* b = L0 + ((2 * oy) * 30 + 2 * ox) * cC + c;
      pc1[i] = 0.25f * (b[0] + b[cC] + b[30 * cC] + b[30 * cC + cC]);
    }
    __syncthreads();
    for (int i = tid; i < 6 * 7 * 64; i += 256) {
      int c = i & 63, pos = i >> 6, oy = pos / 7, ox = pos % 7;
      const float* b = pc1 + ((2 * oy) * 15 + 2 * ox) * cC + c;
      pc2[i] = 0.25f * (b[0] + b[cC] + b[15 * cC] + b[15 * cC + cC]);
    }
    __syncthreads();
    for (int i = tid; i < 3 * 3 * 64; i += 256) {
      int c = i & 63, pos = i >> 6, oy = pos / 3, ox = pos % 3;
      const float* b = pc2 + ((2 * oy) * 7 + 2 * ox) * cC + c;
      pc3[i] = 0.25f * (b[0] + b[cC] + b[7 * cC] + b[7 * cC + cC]);
    }
    __syncthreads();
    const int Hs[4] = {25, 12, 6, 3}, Ws[4] = {30, 15, 7, 3};
    for (int i = tid; i < 196 * 64; i += 256) {
      int c = i & 63, pos = i >> 6, o = pos / 14, p = pos % 14;
      float acc = 0.f;
      #pragma unroll
      for (int l = 0; l < 4; l++) {
        float yy = (float)(o * (Hs[l] - 1)) / 13.0f;
        float xx = (float)(p * (Ws[l] - 1)) / 13.0f;
        int y0 = (int)floorf(yy); int y1 = min(y0 + 1, Hs[l] - 1); float wy = yy - (float)y0;
        int x0 = (int)floorf(xx); int x1 = min(x0 + 1, Ws[l] - 1); float wx = xx - (float)x0;
        const float* L = (l == 0) ? L0 : ((l == 1) ? pc1 : ((l == 2) ? pc2 : pc3));
        float v00 = L[(y0 * Ws[l] + x0) * cC + c], v01 = L[(y0 * Ws[l] + x1) * cC + c];
        float v10 = L[(y1 * Ws[l] + x0) * cC + c], v11 = L[(y1 * Ws[l] + x1) * cC + c];
        acc += (v00 * (1.f - wy) + v10 * wy) * (1.f - wx) + (v01 * (1.f - wy) + v11 * wy) * wx;
      }
      arp[((size_t)q * 196 + pos) * cC + c] = acc * 0.25f * 0.125f;
    }
  }
}

// ---------------------------------------------------------------------------
// coarse MLP (fused f0-sample + coords update). Each block: 4 rows (n, sb..sb+3).
// coarse flow term is exactly zero (coords are a broadcast pre-update).
// ---------------------------------------------------------------------------
__global__ __launch_bounds__(128) void k_mlp_coarse(const float* __restrict__ arp, const float* __restrict__ fmc,
                                                    const float* __restrict__ w1, const float* __restrict__ b1,
                                                    const float* __restrict__ ffw, const float* __restrict__ w2,
                                                    const float* __restrict__ b2,
                                                    const float* __restrict__ pts, float* __restrict__ cof,
                                                    float* __restrict__ out) {
  int n = blockIdx.x >> 2, sb = (blockIdx.x & 3) * 4;
  __shared__ float fc[4][196];
  __shared__ float f0l[64];
  __shared__ float hl[4][128];
  int j = threadIdx.x;
  float xx = pts[n * 2 + 0] * 0.125f, yy = pts[n * 2 + 1] * 0.125f;
  if (j < 64) f0l[j] = bilin_hwc(fmc, cHC, cWC, xx, yy, j);
  __syncthreads();
  #pragma unroll
  for (int r = 0; r < 4; r++) {
    int s = sb + r;
    for (int k = j; k < 196; k += 128) {
      const float4* b4 = (const float4*)(arp + ((size_t)s * 196 + k) * cC);
      float acc = 0.f;
      #pragma unroll
      for (int c4 = 0; c4 < 16; c4++) {
        float4 v = b4[c4];
        acc += v.x * f0l[c4 * 4 + 0] + v.y * f0l[c4 * 4 + 1] +
               v.z * f0l[c4 * 4 + 2] + v.w * f0l[c4 * 4 + 3];
      }
      fc[r][k] = acc;
    }
  }
  __syncthreads();
  float h0 = 0.f, h1 = 0.f, h2 = 0.f, h3 = 0.f;
  for (int k = 0; k < 196; k++) {
    float wv = w1[(size_t)k * 128 + j];
    h0 += fc[0][k] * wv; h1 += fc[1][k] * wv; h2 += fc[2][k] * wv; h3 += fc[3][k] * wv;
  }
  float hh[4] = {h0, h1, h2, h3};
  const float* Wxy = w1 + (size_t)3198 * 128;
  #pragma unroll
  for (int r = 0; r < 4; r++) {
    int s = sb + r;
    float v = hh[r] + b1[j] + ffw[s * 128 + j] + xx * Wxy[j] + yy * Wxy[128 + j];
    hl[r][j] = fmaxf(v, 0.f);
  }
  __syncthreads();
  if (j < 8) {
    int r = j >> 1, d = j & 1;
    float acc = b2[d];
    for (int k = 0; k < 128; k++) acc += hl[r][k] * w2[k * 2 + d];
    int s = sb + r;
    float base = pts[n * 2 + d] * 0.125f;
    float cc = base + acc;
    out[((size_t)s * cN + n) * 2 + d] = cc * 8.0f;   // preds[0]
    cof[((size_t)s * cN + n) * 2 + d] = cc * 4.0f;   // fine coords init
  }
}

// ---------------------------------------------------------------------------
// k_pyrf: grid (16, 14). b<13: fused fine pyramid; b==13: f0-sample role
// (block x = n-group of 4, needs stats + cofA from prior dispatches).
// ---------------------------------------------------------------------------
__global__ __launch_bounds__(256) void k_pyrf(const _Float16* __restrict__ fmf,
                                              _Float16* __restrict__ pf1,
                                              _Float16* __restrict__ pf2,
                                              _Float16* __restrict__ pf3,
                                              const float* __restrict__ stats,
                                              const float* __restrict__ cof,
                                              float* __restrict__ f0f,
                                              float* __restrict__ xys) {
  int q = blockIdx.x, b = blockIdx.y, tid = threadIdx.x;
  if (b == 13) {
    int n = q * 4 + (tid >> 6), c = tid & 63;
    float x = cof[n * 2 + 0], y = cof[n * 2 + 1];  // s=0 rows
    float ws;
    float raw = bilin_raw_h(fmf, cHF, cWF, x, y, c, ws);
    float su = stats[c * 2 + 0], qq = stats[c * 2 + 1];
    float mean = su / 12000.f, var = qq / 12000.f - mean * mean;
    float rstd = rsqrtf(var + 1e-5f);
    f0f[n * cC + c] = (raw - mean * ws) * rstd;
    if (c < 2) xys[n * 2 + c] = (c == 0) ? x : y;
    return;
  }
  __shared__ _Float16 l1[4 * 60 * 64];
  __shared__ _Float16 l2[2 * 30 * 64];
  int nr1 = (b == 12) ? 2 : 4;
  const _Float16* F = fmf + (size_t)q * cHF * cWF * cC;
  for (int i = tid; i < nr1 * 60 * 64; i += 256) {
    int c = i & 63, pos = i >> 6, rl = pos / 60, ox = pos % 60;
    int r1 = 4 * b + rl;
    const _Float16* p = F + ((size_t)(2 * r1) * cWF + 2 * ox) * cC + c;
    float v = 0.25f * ((float)p[0] + (float)p[cC] + (float)p[cWF * cC] + (float)p[cWF * cC + cC]);
    _Float16 h = (_Float16)v;
    l1[i] = h;
    pf1[(((size_t)q * 50 + r1) * 60 + ox) * cC + c] = h;
  }
  __syncthreads();
  int nr2 = (b == 12) ? 1 : 2;
  for (int i = tid; i < nr2 * 30 * 64; i += 256) {
    int c = i & 63, pos = i >> 6, rl = pos / 30, ox = pos % 30;
    const _Float16* p = l1 + ((2 * rl) * 60 + 2 * ox) * 64 + c;
    float v = 0.25f * ((float)p[0] + (float)p[64] + (float)p[60 * 64] + (float)p[60 * 64 + 64]);
    _Float16 h = (_Float16)v;
    l2[i] = h;
    pf2[(((size_t)q * 25 + 2 * b + rl) * 30 + ox) * cC + c] = h;
  }
  __syncthreads();
  if (b < 12) {
    for (int i = tid; i < 15 * 64; i += 256) {
      int c = i & 63, ox = i >> 6;
      const _Float16* p = l2 + (2 * ox) * 64 + c;
      float v = 0.25f * ((float)p[0] + (float)p[64] + (float)p[30 * 64] + (float)p[30 * 64 + 64]);
      pf3[(((size_t)q * 12 + b) * 15 + ox) * cC + c] = (_Float16)v;
    }
  }
}

// ---------------------------------------------------------------------------
// k_iter: fused corr + window-sample + fine MLP + coords update.
// grid = 1024 (XCD-swizzled), block = 256. Phase A: 4 waves = 4 pyramid levels,
// lane = 8x8 grid point; fc[588] stays in LDS. Phase B: 588x128 GEMV split in
// 2 halves; then flow/xy/ffw affine, relu, 128->2 head, coords update.
// ---------------------------------------------------------------------------
__global__ __launch_bounds__(256) void k_iter(const _Float16* __restrict__ p0, const _Float16* __restrict__ p1,
                                              const _Float16* __restrict__ p2, const _Float16* __restrict__ p3,
                                              const float* __restrict__ f0, const float* __restrict__ stats,
                                              const _Float16* __restrict__ LWc, const float* __restrict__ b1e,
                                              const float* __restrict__ ffw, const float* __restrict__ w1t,
                                              const float* __restrict__ w2, const float* __restrict__ b2,
                                              const float* __restrict__ cof_cur, float* __restrict__ cof_nxt,
                                              const float* __restrict__ xys, float* __restrict__ out) {
  int bid = blockIdx.x;
  int w = (bid & 7) * 128 + (bid >> 3);
  int s = w >> 6, n = w & 63;
  __shared__ float feat2[3][64];
  __shared__ float biasS[3];
  __shared__ float fcL[588];
  __shared__ float hp[2][128];
  __shared__ float hl[128];
  int tid = threadIdx.x;

  // ---- phase A: normalized feature vectors (norm affine folded) ----
  {
    int t = tid >> 6, c = tid & 63;
    if (t < 3) {
      float sS = stats[(s * 64 + c) * 2 + 0], qS = stats[(s * 64 + c) * 2 + 1];
      float meanS = sS / 12000.f, varS = qS / 12000.f - meanS * meanS;
      float rstdS = rsqrtf(varS + 1e-5f);
      float featn;
      if (t == 0) {
        featn = f0[(size_t)n * cC + c];
      } else {
        int ssrc = max(s - 2 * t, 0);
        float s2 = stats[(ssrc * 64 + c) * 2 + 0], q2 = stats[(ssrc * 64 + c) * 2 + 1];
        float m2 = s2 / 12000.f, v2 = q2 / 12000.f - m2 * m2;
        float r2 = rsqrtf(v2 + 1e-5f);
        float fx = cof_cur[((size_t)ssrc * cN + n) * 2 + 0];
        float fy = cof_cur[((size_t)ssrc * cN + n) * 2 + 1];
        float ws;
        float raw = bilin_raw_h(p0 + (size_t)ssrc * cHF * cWF * cC, cHF, cWF, fx, fy, c, ws);
        featn = (raw - m2 * ws) * r2;
      }
      feat2[t][c] = featn * rstdS * 0.125f;        // 1/sqrt(64) folded
      float bc = featn * (-meanS * rstdS) * 0.125f;
      #pragma unroll
      for (int o = 32; o; o >>= 1) bc += __shfl_xor(bc, o);
      if (c == 0) biasS[t] = bc;
    }
  }
  __syncthreads();

  // ---- gather + 3 dots per 8x8 grid point, bilinear combine -> fcL ----
  {
    int l = tid >> 6, lane = tid & 63;
    const _Float16* Ls[4] = {p0, p1, p2, p3};
    const int Hs[4] = {cHF, 50, 25, 12}, Ws[4] = {cWF, 60, 30, 15};
    float cx = cof_cur[((size_t)s * cN + n) * 2 + 0];
    float cy = cof_cur[((size_t)s * cN + n) * 2 + 1];
    float sc = 1.0f / (float)(1 << l);
    float x = fminf(fmaxf(cx * sc, -2.0e6f), 2.0e6f);
    float y = fminf(fmaxf(cy * sc, -2.0e6f), 2.0e6f);
    float x0f = floorf(x), y0f = floorf(y);
    float wx = x - x0f, wy = y - y0f;
    int dxi = lane & 7, dyi = lane >> 3;
    int ix = (int)x0f + dxi - 3, iy = (int)y0f + dyi - 3;
    int Hl = Hs[l], Wl = Ws[l];
    float d[3] = {0.f, 0.f, 0.f};
    if (ix >= 0 && ix < Wl && iy >= 0 && iy < Hl) {
      const _Float16* row = Ls[l] + (((size_t)s * Hl + iy) * Wl + ix) * cC;
      float a0 = 0.f, a1 = 0.f, a2 = 0.f;
      #pragma unroll
      for (int c8 = 0; c8 < 8; c8++) {
        half8 v = *(const half8*)(row + c8 * 8);
        #pragma unroll
        for (int e = 0; e < 8; e++) {
          float f = (float)v[e];
          a0 += f * feat2[0][c8 * 8 + e];
          a1 += f * feat2[1][c8 * 8 + e];
          a2 += f * feat2[2][c8 * 8 + e];
        }
      }
      d[0] = a0 + biasS[0]; d[1] = a1 + biasS[1]; d[2] = a2 + biasS[2];
    }
    int dy = lane / 7, dx = lane - dy * 7;
    int bb = (lane < 49) ? (dy * 8 + dx) : 0;
    float w00 = (1.f - wy) * (1.f - wx), w01 = (1.f - wy) * wx;
    float w10 = wy * (1.f - wx), w11 = wy * wx;
    #pragma unroll
    for (int t = 0; t < 3; t++) {
      float d00 = __shfl(d[t], bb, 64);
      float d01 = __shfl(d[t], bb + 1, 64);
      float d10 = __shfl(d[t], bb + 8, 64);
      float d11 = __shfl(d[t], bb + 9, 64);
      if (lane < 49)
        fcL[t * 196 + l * 49 + lane] = w00 * d00 + w01 * d01 + w10 * d10 + w11 * d11;
    }
  }
  __syncthreads();

  // ---- phase B: MLP ----
  int j = tid & 127, half = tid >> 7;
  {
    float h = 0.f;
    int k0 = half * 294;
    const _Float16* Lw = LWc + (size_t)k0 * 128 + j;
    for (int k = 0; k < 294; k++) h += fcL[k0 + k] * (float)Lw[(size_t)k * 128];
    hp[half][j] = h;
  }
  __syncthreads();
  if (half == 0) {
    const float* Wfl = w1t + (size_t)392 * 128;
    const float* Wxy = w1t + (size_t)3394 * 128;
    float xx = xys[n * 2 + 0], yy = xys[n * 2 + 1];
    int sA = min(s + 1, 15), sB = (s == 15) ? 14 : s;
    float flx = cof_cur[(sA * cN + n) * 2 + 0] - cof_cur[(sB * cN + n) * 2 + 0];
    float fly = cof_cur[(sA * cN + n) * 2 + 1] - cof_cur[(sB * cN + n) * 2 + 1];
    float v = hp[0][j] + hp[1][j] + b1e[j] + ffw[s * 128 + j] +
              flx * Wfl[j] + fly * Wfl[128 + j] + xx * Wxy[j] + yy * Wxy[128 + j];
    hl[j] = fmaxf(v, 0.f);
  }
  __syncthreads();
  if (tid < 2) {
    int d = tid;
    float acc = b2[d];
    for (int k = 0; k < 128; k++) acc += hl[k] * w2[k * 2 + d];
    float cc = cof_cur[((size_t)s * cN + n) * 2 + d] + acc;
    cof_nxt[((size_t)s * cN + n) * 2 + d] = cc;
    out[((size_t)s * cN + n) * 2 + d] = cc * 2.0f;
  }
}

// ---------------------------------------------------------------------------
extern "C" void kernel_launch(void* const* d_in, const int* in_sizes, int n_in,
                              void* d_out, int out_size, void* d_ws, size_t ws_size,
                              hipStream_t stream) {
  (void)in_sizes; (void)n_in; (void)out_size; (void)ws_size;
  const float* rgbs = (const float*)d_in[0];
  const float* pts  = (const float*)d_in[1];
  const float* fnw  = (const float*)d_in[2];
  const float* fnfw = (const float*)d_in[3];
  const float* lw   = (const float*)d_in[4];
  const float* lb   = (const float*)d_in[5];
  const float* w1s  = (const float*)d_in[6];
  const float* b1s  = (const float*)d_in[7];
  const float* w2s  = (const float*)d_in[8];
  const float* b2s  = (const float*)d_in[9];
  const float* w1t  = (const float*)d_in[10];
  const float* b1t  = (const float*)d_in[11];
  const float* w2t  = (const float*)d_in[12];
  const float* b2t  = (const float*)d_in[13];
  float* out = (float*)d_out;

  float* p = (float*)d_ws;
  auto alloc = [&](size_t nf) { float* r = p; p += nf; return r; };
  float* part  = alloc((size_t)2 * cS * cNCH * 128);
  float* ffw_s = alloc(cS * 128);
  float* ffw_t = alloc(cS * 128);
  _Float16* LWc = (_Float16*)alloc((size_t)588 * 128 / 2);
  float* b1te  = alloc(128);
  float* fmc   = alloc((size_t)cS * cHC * cWC * cC);
  float* arp   = alloc((size_t)cS * 196 * cC);
  float* partf = alloc((size_t)cS * cHF * cC * 2);
  float* stats = alloc(cS * cC * 2);
  _Float16* fmf = (_Float16*)alloc((size_t)cS * cHF * cWF * cC / 2);
  _Float16* pf1 = (_Float16*)alloc((size_t)cS * 50 * 60 * cC / 2);
  _Float16* pf2 = (_Float16*)alloc((size_t)cS * 25 * 30 * cC / 2);
  _Float16* pf3 = (_Float16*)alloc((size_t)cS * 12 * 15 * cC / 2);
  float* f0f   = alloc((size_t)cN * cC);
  float* xys0  = alloc(cN * 2);
  float* cofA  = alloc((size_t)cS * cN * 2);
  float* cofB  = alloc((size_t)cS * cN * 2);

  // 1) independent front work: frame_flow GEMV parts + both encoders
  k_front<<<NB_FFP + NB_CONVC + NB_CONVF, 256, 0, stream>>>(
      rgbs, w1s, w1t, fnw, fnfw, part, fmc, fmf, partf);
  // 2) reductions + precomputes: ffw, LWc/b1te, stats, coarse pyramid/arp
  k_mid<<<123, 256, 0, stream>>>(part, ffw_s, ffw_t, lw, lb, w1t, b1t, LWc, b1te,
                                 partf, stats, fmc, arp);
  // 3) coarse MLP -> preds[0] + fine coords init
  k_mlp_coarse<<<256, 128, 0, stream>>>(arp, fmc, w1s, b1s, ffw_s, w2s, b2s, pts, cofA, out);
  // 4) fine pyramid + f0 feature sample
  k_pyrf<<<dim3(16, 14), 256, 0, stream>>>(fmf, pf1, pf2, pf3, stats, cofA, f0f, xys0);
  // 5-8) fused fine iterations
  float* cbuf[2] = {cofA, cofB};
  for (int it = 0; it < cITERS; it++) {
    float* cur = cbuf[it & 1];
    float* nxt = cbuf[(it & 1) ^ 1];
    k_iter<<<1024, 256, 0, stream>>>(fmf, pf1, pf2, pf3, f0f, stats, LWc, b1te, ffw_t,
                                     w1t, w2t, b2t, cur, nxt, xys0,
                                     out + (size_t)(it + 1) * cS * cN * 2);
  }
}

// Round 8
// 172.339 us; speedup vs baseline: 3.9797x; 1.1192x over previous
//
#include <hip/hip_runtime.h>

// ---- problem constants (from reference setup_inputs) ----
constexpr int cS = 16, cN = 64, cH = 200, cW = 240;
constexpr int cHC = 25, cWC = 30;          // coarse fmap (stride 8)
constexpr int cHF = 100, cWF = 120;        // fine fmap (stride 2)
constexpr int cC = 64;                     // LAT
constexpr int cITERS = 4;                  // setup_inputs fixed
constexpr int cNCH = 50, cCHUNK = 60;      // ffw split

typedef _Float16 half8 __attribute__((ext_vector_type(8)));

// NOTE (round 7 lesson): hipLaunchCooperativeKernel fails under this harness's
// graph capture (output never written). Stay with normal stream launches.

// ---------------------------------------------------------------------------
// helpers
// ---------------------------------------------------------------------------
__device__ __forceinline__ float bilin_hwc(const float* __restrict__ fm, int Hh, int Ww,
                                           float x, float y, int c) {
  x = fminf(fmaxf(x, -2.0e6f), 2.0e6f);
  y = fminf(fmaxf(y, -2.0e6f), 2.0e6f);
  float x0f = floorf(x), y0f = floorf(y);
  int ix = (int)x0f, iy = (int)y0f;
  float wx = x - x0f, wy = y - y0f;
  float acc = 0.f;
  bool vx0 = (ix >= 0) && (ix < Ww), vx1 = (ix + 1 >= 0) && (ix + 1 < Ww);
  bool vy0 = (iy >= 0) && (iy < Hh), vy1 = (iy + 1 >= 0) && (iy + 1 < Hh);
  if (vy0 && vx0) acc += fm[(iy * Ww + ix) * cC + c] * (1.f - wy) * (1.f - wx);
  if (vy0 && vx1) acc += fm[(iy * Ww + ix + 1) * cC + c] * (1.f - wy) * wx;
  if (vy1 && vx0) acc += fm[((iy + 1) * Ww + ix) * cC + c] * wy * (1.f - wx);
  if (vy1 && vx1) acc += fm[((iy + 1) * Ww + ix + 1) * cC + c] * wy * wx;
  return acc;
}

// raw fp16 bilinear gather; returns in-bounds tap-weight sum (affine folding:
// featn = rstd*(raw - mean*wsum), zero-padding-correct).
__device__ __forceinline__ float bilin_raw_h(const _Float16* __restrict__ fm, int Hh, int Ww,
                                             float x, float y, int c, float& wsum) {
  x = fminf(fmaxf(x, -2.0e6f), 2.0e6f);
  y = fminf(fmaxf(y, -2.0e6f), 2.0e6f);
  float x0f = floorf(x), y0f = floorf(y);
  int ix = (int)x0f, iy = (int)y0f;
  float wx = x - x0f, wy = y - y0f;
  float acc = 0.f; wsum = 0.f;
  bool vx0 = (ix >= 0) && (ix < Ww), vx1 = (ix + 1 >= 0) && (ix + 1 < Ww);
  bool vy0 = (iy >= 0) && (iy < Hh), vy1 = (iy + 1 >= 0) && (iy + 1 < Hh);
  float w00 = (1.f - wy) * (1.f - wx), w01 = (1.f - wy) * wx;
  float w10 = wy * (1.f - wx), w11 = wy * wx;
  if (vy0 && vx0) { acc += (float)fm[(iy * Ww + ix) * cC + c] * w00; wsum += w00; }
  if (vy0 && vx1) { acc += (float)fm[(iy * Ww + ix + 1) * cC + c] * w01; wsum += w01; }
  if (vy1 && vx0) { acc += (float)fm[((iy + 1) * Ww + ix) * cC + c] * w10; wsum += w10; }
  if (vy1 && vx1) { acc += (float)fm[((iy + 1) * Ww + ix + 1) * cC + c] * w11; wsum += w11; }
  return acc;
}

// ---------------------------------------------------------------------------
// k_front: role-partitioned. [0,800) ffp; [800,1824) convc; [1824,3424) convf.
// ---------------------------------------------------------------------------
constexpr int NB_FFP = 800, NB_CONVC = 1024, NB_CONVF = 1600;

__global__ __launch_bounds__(256) void k_front(const float* __restrict__ rgbs,
                                               const float* __restrict__ w1s,
                                               const float* __restrict__ w1t,
                                               const float* __restrict__ fnw,
                                               const float* __restrict__ fnfw,
                                               float* __restrict__ part,
                                               float* __restrict__ fmc,
                                               _Float16* __restrict__ fmf,
                                               float* __restrict__ partf) {
  __shared__ float smem[512];
  int bid = blockIdx.x, tid = threadIdx.x;
  const float a = 2.0f / 255.0f;

  if (bid < NB_FFP) {
    int s = bid / cNCH, ch = bid % cNCH;
    if (tid < cCHUNK) {
      const float* cur = rgbs + (size_t)s * cH * cW;
      const float* prev = rgbs + (size_t)(s - 1) * cH * cW;
      const float* last = rgbs + (size_t)15 * cH * cW;
      int y = 4 * ch + 1, x = 4 * tid + 1;
      float v = 0.f;
      #pragma unroll
      for (int dy = 0; dy < 2; dy++)
        #pragma unroll
        for (int dx = 0; dx < 2; dx++) {
          int id = (y + dy) * cW + (x + dx);
          float pv = (s == 0) ? (a * last[id] - 1.0f) : (a * (cur[id] - prev[id]));
          v += pv;
        }
      smem[tid] = 0.25f * v;
    }
    __syncthreads();
    int t = tid >> 7, j = tid & 127;
    const float* w = (t == 0) ? (w1s + (size_t)198 * 128) : (w1t + (size_t)394 * 128);
    const float* wr = w + (size_t)ch * cCHUNK * 128 + j;
    float acc = 0.f;
    #pragma unroll 4
    for (int i = 0; i < cCHUNK; i++) acc += smem[i] * wr[(size_t)i * 128];
    part[(((size_t)t * cS + s) * cNCH + ch) * 128 + j] = acc;

  } else if (bid < NB_FFP + NB_CONVC) {
    int idx = bid - NB_FFP;
    int q = idx >> 6, c = idx & 63;
    float* wl = smem;
    float* red = smem + 64;
    if (tid < 64) wl[tid] = fnw[c * 64 + tid];
    __syncthreads();
    const float* img = rgbs + (size_t)q * cH * cW;
    float vals[3];
    float sum = 0.f, ss = 0.f;
    #pragma unroll
    for (int i = 0; i < 3; i++) {
      int pos = tid + i * 256;
      float v = 0.f;
      if (pos < 750) {
        int y = pos / cWC, x = pos % cWC;
        const float* base = img + (y * 8) * cW + x * 8;
        float acc = 0.f, wsum = 0.f;
        for (int ky = 0; ky < 8; ky++)
          #pragma unroll
          for (int kx = 0; kx < 8; kx++) {
            float wv = wl[ky * 8 + kx];
            acc += wv * base[ky * cW + kx];
            wsum += wv;
          }
        v = a * acc - wsum;
        sum += v; ss += v * v;
      }
      vals[i] = v;
    }
    red[tid] = sum; __syncthreads();
    for (int st = 128; st > 0; st >>= 1) { if (tid < st) red[tid] += red[tid + st]; __syncthreads(); }
    float tsum = red[0]; __syncthreads();
    red[tid] = ss; __syncthreads();
    for (int st = 128; st > 0; st >>= 1) { if (tid < st) red[tid] += red[tid + st]; __syncthreads(); }
    float tss = red[0];
    float mean = tsum / 750.0f;
    float var = tss / 750.0f - mean * mean;
    float rstd = rsqrtf(var + 1e-5f);
    #pragma unroll
    for (int i = 0; i < 3; i++) {
      int pos = tid + i * 256;
      if (pos < 750) fmc[((size_t)q * 750 + pos) * cC + c] = (vals[i] - mean) * rstd;
    }

  } else {
    int idx = bid - NB_FFP - NB_CONVC;
    int q = idx / cHF, y = idx % cHF;
    int lane = tid & 63, wv = tid >> 6;
    float w0 = fnfw[lane * 4 + 0], w1 = fnfw[lane * 4 + 1];
    float w2 = fnfw[lane * 4 + 2], w3 = fnfw[lane * 4 + 3];
    float wsum = w0 + w1 + w2 + w3;
    const float* img = rgbs + (size_t)q * cH * cW;
    float sum = 0.f, ss = 0.f;
    for (int x = wv; x < cWF; x += 4) {
      const float* b = img + (2 * y) * cW + 2 * x;
      float v = a * (w0 * b[0] + w1 * b[1] + w2 * b[cW] + w3 * b[cW + 1]) - wsum;
      fmf[(((size_t)q * cHF + y) * cWF + x) * cC + lane] = (_Float16)v;
      sum += v; ss += v * v;
    }
    float* red = smem;
    red[(0 * 4 + wv) * 64 + lane] = sum;
    red[(1 * 4 + wv) * 64 + lane] = ss;
    __syncthreads();
    if (wv == 0) {
      float s4 = red[0 * 64 + lane] + red[1 * 64 + lane] + red[2 * 64 + lane] + red[3 * 64 + lane];
      float q4 = red[(4 + 0) * 64 + lane] + red[(4 + 1) * 64 + lane] +
                 red[(4 + 2) * 64 + lane] + red[(4 + 3) * 64 + lane];
      size_t o = ((size_t)q * cHF + y) * 64 + lane;
      partf[o * 2 + 0] = s4;
      partf[o * 2 + 1] = q4;
    }
  }
}

// ---------------------------------------------------------------------------
// k_mid: [0,16) ffw_red; [16,91) LWc + b1te; [91,107) stats reduce;
// [107,123) coarse pyramid + arp.
// ---------------------------------------------------------------------------
__global__ __launch_bounds__(256) void k_mid(const float* __restrict__ part,
                                             float* __restrict__ ffw_s, float* __restrict__ ffw_t,
                                             const float* __restrict__ lw, const float* __restrict__ lb,
                                             const float* __restrict__ w1t, const float* __restrict__ b1t,
                                             _Float16* __restrict__ LWc, float* __restrict__ b1te,
                                             const float* __restrict__ partf, float* __restrict__ stats,
                                             const float* __restrict__ fmc, float* __restrict__ arp) {
  __shared__ float smem[14784];
  int bid = blockIdx.x, tid = threadIdx.x;

  if (bid < 16) {
    int s = bid, t = tid >> 7, j = tid & 127;
    const float* p = part + (((size_t)t * cS + s) * cNCH) * 128 + j;
    float acc = 0.f;
    for (int c = 0; c < cNCH; c++) acc += p[(size_t)c * 128];
    ((t == 0) ? ffw_s : ffw_t)[s * 128 + j] = acc;

  } else if (bid < 91) {
    int b2 = bid - 16, g = tid >> 7, j = tid & 127;
    if (b2 < 74) {
      int k0 = b2 * 8 + g * 4;
      if (k0 < 588) {
        const float* l0 = lw + (size_t)(k0 + 0) * 392;
        const float* l1 = lw + (size_t)(k0 + 1) * 392;
        const float* l2 = lw + (size_t)(k0 + 2) * 392;
        const float* l3 = lw + (size_t)(k0 + 3) * 392;
        float a0 = 0.f, a1 = 0.f, a2 = 0.f, a3 = 0.f;
        for (int m = 0; m < 392; m++) {
          float wv = w1t[(size_t)m * 128 + j];
          a0 += l0[m] * wv; a1 += l1[m] * wv; a2 += l2[m] * wv; a3 += l3[m] * wv;
        }
        LWc[(size_t)(k0 + 0) * 128 + j] = (_Float16)a0;
        LWc[(size_t)(k0 + 1) * 128 + j] = (_Float16)a1;
        LWc[(size_t)(k0 + 2) * 128 + j] = (_Float16)a2;
        LWc[(size_t)(k0 + 3) * 128 + j] = (_Float16)a3;
      }
    } else if (g == 0) {
      float acc = b1t[j];
      for (int m = 0; m < 392; m++) acc += lb[m] * w1t[(size_t)m * 128 + j];
      b1te[j] = acc;
    }

  } else if (bid < 107) {
    int q = bid - 91, c = tid & 63, g = tid >> 6;
    float s0 = 0.f, s1 = 0.f;
    for (int yy = 0; yy < 25; yy++) {
      size_t o = ((size_t)q * cHF + g * 25 + yy) * 64 + c;
      s0 += partf[o * 2 + 0];
      s1 += partf[o * 2 + 1];
    }
    smem[g * 64 + c] = s0;
    smem[256 + g * 64 + c] = s1;
    __syncthreads();
    if (g == 0) {
      stats[(q * 64 + c) * 2 + 0] = smem[c] + smem[64 + c] + smem[128 + c] + smem[192 + c];
      stats[(q * 64 + c) * 2 + 1] = smem[256 + c] + smem[320 + c] + smem[384 + c] + smem[448 + c];
    }

  } else {
    int q = bid - 107;
    float* pc1 = smem;            // 12*15*64
    float* pc2 = smem + 11520;    // 6*7*64
    float* pc3 = smem + 14208;    // 3*3*64
    const float* L0 = fmc + (size_t)q * 750 * cC;
    for (int i = tid; i < 12 * 15 * 64; i += 256) {
      int c = i & 63, pos = i >> 6, oy = pos / 15, ox = pos % 15;
      const float* b = L0 + ((2 * oy) * 30 + 2 * ox) * cC + c;
      pc1[i] = 0.25f * (b[0] + b[cC] + b[30 * cC] + b[30 * cC + cC]);
    }
    __syncthreads();
    for (int i = tid; i < 6 * 7 * 64; i += 256) {
      int c = i & 63, pos = i >> 6, oy = pos / 7, ox = pos % 7;
      const float* b = pc1 + ((2 * oy) * 15 + 2 * ox) * cC + c;
      pc2[i] = 0.25f * (b[0] + b[cC] + b[15 * cC] + b[15 * cC + cC]);
    }
    __syncthreads();
    for (int i = tid; i < 3 * 3 * 64; i += 256) {
      int c = i & 63, pos = i >> 6, oy = pos / 3, ox = pos % 3;
      const float* b = pc2 + ((2 * oy) * 7 + 2 * ox) * cC + c;
      pc3[i] = 0.25f * (b[0] + b[cC] + b[7 * cC] + b[7 * cC + cC]);
    }
    __syncthreads();
    const int Hs[4] = {25, 12, 6, 3}, Ws[4] = {30, 15, 7, 3};
    for (int i = tid; i < 196 * 64; i += 256) {
      int c = i & 63, pos = i >> 6, o = pos / 14, p = pos % 14;
      float acc = 0.f;
      #pragma unroll
      for (int l = 0; l < 4; l++) {
        float yy = (float)(o * (Hs[l] - 1)) / 13.0f;
        float xx = (float)(p * (Ws[l] - 1)) / 13.0f;
        int y0 = (int)floorf(yy); int y1 = min(y0 + 1, Hs[l] - 1); float wy = yy - (float)y0;
        int x0 = (int)floorf(xx); int x1 = min(x0 + 1, Ws[l] - 1); float wx = xx - (float)x0;
        const float* L = (l == 0) ? L0 : ((l == 1) ? pc1 : ((l == 2) ? pc2 : pc3));
        float v00 = L[(y0 * Ws[l] + x0) * cC + c], v01 = L[(y0 * Ws[l] + x1) * cC + c];
        float v10 = L[(y1 * Ws[l] + x0) * cC + c], v11 = L[(y1 * Ws[l] + x1) * cC + c];
        acc += (v00 * (1.f - wy) + v10 * wy) * (1.f - wx) + (v01 * (1.f - wy) + v11 * wy) * wx;
      }
      arp[((size_t)q * 196 + pos) * cC + c] = acc * 0.25f * 0.125f;
    }
  }
}

// ---------------------------------------------------------------------------
// k_mix: [0,256) coarse MLP (4 rows per block, 256 threads, K-split GEMV);
//        [256,464) fine pyramid. Independent roles (MLP needs k_mid's arp/ffw;
//        pyramid needs k_front's fmf) -> one dispatch.
// ---------------------------------------------------------------------------
__global__ __launch_bounds__(256) void k_mix(const float* __restrict__ arp, const float* __restrict__ fmc,
                                             const float* __restrict__ w1, const float* __restrict__ b1,
                                             const float* __restrict__ ffw, const float* __restrict__ w2,
                                             const float* __restrict__ b2, const float* __restrict__ pts,
                                             float* __restrict__ cof, float* __restrict__ xys,
                                             float* __restrict__ out,
                                             const _Float16* __restrict__ fmf,
                                             _Float16* __restrict__ pf1, _Float16* __restrict__ pf2,
                                             _Float16* __restrict__ pf3) {
  __shared__ __align__(16) unsigned char smemraw[38400];
  int bid = blockIdx.x, tid = threadIdx.x;

  if (bid < 256) {
    // ---- coarse MLP; flow term is exactly zero (broadcast pre-update) ----
    int n = bid >> 2, sb = (bid & 3) * 4;
    float* fc = (float*)smemraw;   // [784]
    float* f0l = fc + 784;         // [64]
    float* hp = f0l + 64;          // [2][4][128]
    float* hl = hp + 1024;         // [4][128]
    float xx = pts[n * 2 + 0] * 0.125f, yy = pts[n * 2 + 1] * 0.125f;
    if (tid < 64) f0l[tid] = bilin_hwc(fmc, cHC, cWC, xx, yy, tid);
    __syncthreads();
    for (int i = tid; i < 784; i += 256) {
      int r = i / 196, k = i - r * 196;
      const float4* b4 = (const float4*)(arp + ((size_t)(sb + r) * 196 + k) * cC);
      float acc = 0.f;
      #pragma unroll
      for (int c4 = 0; c4 < 16; c4++) {
        float4 v = b4[c4];
        acc += v.x * f0l[c4 * 4 + 0] + v.y * f0l[c4 * 4 + 1] +
               v.z * f0l[c4 * 4 + 2] + v.w * f0l[c4 * 4 + 3];
      }
      fc[i] = acc;
    }
    __syncthreads();
    int j = tid & 127, half = tid >> 7;
    float h0 = 0.f, h1 = 0.f, h2 = 0.f, h3 = 0.f;
    int k0 = half * 98;
    for (int k = k0; k < k0 + 98; k++) {
      float wv = w1[(size_t)k * 128 + j];
      h0 += fc[0 * 196 + k] * wv; h1 += fc[1 * 196 + k] * wv;
      h2 += fc[2 * 196 + k] * wv; h3 += fc[3 * 196 + k] * wv;
    }
    hp[(half * 4 + 0) * 128 + j] = h0; hp[(half * 4 + 1) * 128 + j] = h1;
    hp[(half * 4 + 2) * 128 + j] = h2; hp[(half * 4 + 3) * 128 + j] = h3;
    __syncthreads();
    if (half == 0) {
      const float* Wxy = w1 + (size_t)3198 * 128;
      #pragma unroll
      for (int r = 0; r < 4; r++) {
        int s = sb + r;
        float v = hp[r * 128 + j] + hp[(4 + r) * 128 + j] + b1[j] +
                  ffw[s * 128 + j] + xx * Wxy[j] + yy * Wxy[128 + j];
        hl[r * 128 + j] = fmaxf(v, 0.f);
      }
    }
    __syncthreads();
    if (tid < 8) {
      int r = tid >> 1, d = tid & 1;
      float acc = b2[d];
      for (int k = 0; k < 128; k++) acc += hl[r * 128 + k] * w2[k * 2 + d];
      int s = sb + r;
      float cc = pts[n * 2 + d] * 0.125f + acc;
      out[((size_t)s * cN + n) * 2 + d] = cc * 8.0f;   // preds[0]
      cof[((size_t)s * cN + n) * 2 + d] = cc * 4.0f;   // fine coords init
      if (s == 0) xys[n * 2 + d] = cc * 4.0f;
    }

  } else {
    // ---- fine pyramid ----
    int u = bid - 256;
    int q = u / 13, b = u % 13;
    _Float16* l1 = (_Float16*)smemraw;  // [4*60*64]
    _Float16* l2 = l1 + 15360;          // [2*30*64]
    int nr1 = (b == 12) ? 2 : 4;
    const _Float16* F = fmf + (size_t)q * cHF * cWF * cC;
    for (int i = tid; i < nr1 * 60 * 64; i += 256) {
      int c = i & 63, pos = i >> 6, rl = pos / 60, ox = pos % 60;
      int r1 = 4 * b + rl;
      const _Float16* p = F + ((size_t)(2 * r1) * cWF + 2 * ox) * cC + c;
      float v = 0.25f * ((float)p[0] + (float)p[cC] + (float)p[cWF * cC] + (float)p[cWF * cC + cC]);
      _Float16 h = (_Float16)v;
      l1[i] = h;
      pf1[(((size_t)q * 50 + r1) * 60 + ox) * cC + c] = h;
    }
    __syncthreads();
    int nr2 = (b == 12) ? 1 : 2;
    for (int i = tid; i < nr2 * 30 * 64; i += 256) {
      int c = i & 63, pos = i >> 6, rl = pos / 30, ox = pos % 30;
      const _Float16* p = l1 + ((2 * rl) * 60 + 2 * ox) * 64 + c;
      float v = 0.25f * ((float)p[0] + (float)p[64] + (float)p[60 * 64] + (float)p[60 * 64 + 64]);
      _Float16 h = (_Float16)v;
      l2[i] = h;
      pf2[(((size_t)q * 25 + 2 * b + rl) * 30 + ox) * cC + c] = h;
    }
    __syncthreads();
    if (b < 12) {
      for (int i = tid; i < 15 * 64; i += 256) {
        int c = i & 63, ox = i >> 6;
        const _Float16* p = l2 + (2 * ox) * 64 + c;
        float v = 0.25f * ((float)p[0] + (float)p[64] + (float)p[30 * 64] + (float)p[30 * 64 + 64]);
        pf3[(((size_t)q * 12 + b) * 15 + ox) * cC + c] = (_Float16)v;
      }
    }
  }
}

// ---------------------------------------------------------------------------
// k_iter: fused corr + window-sample + fine MLP + coords update.
// grid = 1024 (XCD-swizzled), block = 256. feat2[0] recomputed in-block from
// xys0 (frame-0 gather) — no precomputed f0 buffer needed.
// ---------------------------------------------------------------------------
__global__ __launch_bounds__(256) void k_iter(const _Float16* __restrict__ p0, const _Float16* __restrict__ p1,
                                              const _Float16* __restrict__ p2, const _Float16* __restrict__ p3,
                                              const float* __restrict__ stats,
                                              const _Float16* __restrict__ LWc, const float* __restrict__ b1e,
                                              const float* __restrict__ ffw, const float* __restrict__ w1t,
                                              const float* __restrict__ w2, const float* __restrict__ b2,
                                              const float* __restrict__ cof_cur, float* __restrict__ cof_nxt,
                                              const float* __restrict__ xys, float* __restrict__ out) {
  int bid = blockIdx.x;
  int w = (bid & 7) * 128 + (bid >> 3);
  int s = w >> 6, n = w & 63;
  __shared__ float feat2[3][64];
  __shared__ float biasS[3];
  __shared__ float fcL[588];
  __shared__ float hp[2][128];
  __shared__ float hl[128];
  int tid = threadIdx.x;

  // ---- phase A: normalized feature vectors (norm affine folded) ----
  {
    int t = tid >> 6, c = tid & 63;
    if (t < 3) {
      float sS = stats[(s * 64 + c) * 2 + 0], qS = stats[(s * 64 + c) * 2 + 1];
      float meanS = sS / 12000.f, varS = qS / 12000.f - meanS * meanS;
      float rstdS = rsqrtf(varS + 1e-5f);
      int ssrc = (t == 0) ? 0 : max(s - 2 * t, 0);
      float fx, fy;
      if (t == 0) { fx = xys[n * 2 + 0]; fy = xys[n * 2 + 1]; }
      else {
        fx = cof_cur[((size_t)ssrc * cN + n) * 2 + 0];
        fy = cof_cur[((size_t)ssrc * cN + n) * 2 + 1];
      }
      float s2 = stats[(ssrc * 64 + c) * 2 + 0], q2 = stats[(ssrc * 64 + c) * 2 + 1];
      float m2 = s2 / 12000.f, v2 = q2 / 12000.f - m2 * m2;
      float r2 = rsqrtf(v2 + 1e-5f);
      float ws;
      float raw = bilin_raw_h(p0 + (size_t)ssrc * cHF * cWF * cC, cHF, cWF, fx, fy, c, ws);
      float featn = (raw - m2 * ws) * r2;
      feat2[t][c] = featn * rstdS * 0.125f;        // 1/sqrt(64) folded
      float bc = featn * (-meanS * rstdS) * 0.125f;
      #pragma unroll
      for (int o = 32; o; o >>= 1) bc += __shfl_xor(bc, o);
      if (c == 0) biasS[t] = bc;
    }
  }
  __syncthreads();

  // ---- gather + 3 dots per 8x8 grid point, bilinear combine -> fcL ----
  {
    int l = tid >> 6, lane = tid & 63;
    const _Float16* Ls[4] = {p0, p1, p2, p3};
    const int Hs[4] = {cHF, 50, 25, 12}, Ws[4] = {cWF, 60, 30, 15};
    float cx = cof_cur[((size_t)s * cN + n) * 2 + 0];
    float cy = cof_cur[((size_t)s * cN + n) * 2 + 1];
    float sc = 1.0f / (float)(1 << l);
    float x = fminf(fmaxf(cx * sc, -2.0e6f), 2.0e6f);
    float y = fminf(fmaxf(cy * sc, -2.0e6f), 2.0e6f);
    float x0f = floorf(x), y0f = floorf(y);
    float wx = x - x0f, wy = y - y0f;
    int dxi = lane & 7, dyi = lane >> 3;
    int ix = (int)x0f + dxi - 3, iy = (int)y0f + dyi - 3;
    int Hl = Hs[l], Wl = Ws[l];
    float d[3] = {0.f, 0.f, 0.f};
    if (ix >= 0 && ix < Wl && iy >= 0 && iy < Hl) {
      const _Float16* row = Ls[l] + (((size_t)s * Hl + iy) * Wl + ix) * cC;
      float a0 = 0.f, a1 = 0.f, a2 = 0.f;
      #pragma unroll
      for (int c8 = 0; c8 < 8; c8++) {
        half8 v = *(const half8*)(row + c8 * 8);
        #pragma unroll
        for (int e = 0; e < 8; e++) {
          float f = (float)v[e];
          a0 += f * feat2[0][c8 * 8 + e];
          a1 += f * feat2[1][c8 * 8 + e];
          a2 += f * feat2[2][c8 * 8 + e];
        }
      }
      d[0] = a0 + biasS[0]; d[1] = a1 + biasS[1]; d[2] = a2 + biasS[2];
    }
    int dy = lane / 7, dx = lane - dy * 7;
    int bb = (lane < 49) ? (dy * 8 + dx) : 0;
    float w00 = (1.f - wy) * (1.f - wx), w01 = (1.f - wy) * wx;
    float w10 = wy * (1.f - wx), w11 = wy * wx;
    #pragma unroll
    for (int t = 0; t < 3; t++) {
      float d00 = __shfl(d[t], bb, 64);
      float d01 = __shfl(d[t], bb + 1, 64);
      float d10 = __shfl(d[t], bb + 8, 64);
      float d11 = __shfl(d[t], bb + 9, 64);
      if (lane < 49)
        fcL[t * 196 + l * 49 + lane] = w00 * d00 + w01 * d01 + w10 * d10 + w11 * d11;
    }
  }
  __syncthreads();

  // ---- phase B: MLP + coords update ----
  int j = tid & 127, half = tid >> 7;
  {
    float h = 0.f;
    int k0 = half * 294;
    const _Float16* Lw = LWc + (size_t)k0 * 128 + j;
    for (int k = 0; k < 294; k++) h += fcL[k0 + k] * (float)Lw[(size_t)k * 128];
    hp[half][j] = h;
  }
  __syncthreads();
  if (half == 0) {
    const float* Wfl = w1t + (size_t)392 * 128;
    const float* Wxy = w1t + (size_t)3394 * 128;
    float xx = xys[n * 2 + 0], yy = xys[n * 2 + 1];
    int sA = min(s + 1, 15), sB = (s == 15) ? 14 : s;
    float flx = cof_cur[(sA * cN + n) * 2 + 0] - cof_cur[(sB * cN + n) * 2 + 0];
    float fly = cof_cur[(sA * cN + n) * 2 + 1] - cof_cur[(sB * cN + n) * 2 + 1];
    float v = hp[0][j] + hp[1][j] + b1e[j] + ffw[s * 128 + j] +
              flx * Wfl[j] + fly * Wfl[128 + j] + xx * Wxy[j] + yy * Wxy[128 + j];
    hl[j] = fmaxf(v, 0.f);
  }
  __syncthreads();
  if (tid < 2) {
    int d = tid;
    float acc = b2[d];
    for (int k = 0; k < 128; k++) acc += hl[k] * w2[k * 2 + d];
    float cc = cof_cur[((size_t)s * cN + n) * 2 + d] + acc;
    cof_nxt[((size_t)s * cN + n) * 2 + d] = cc;
    out[((size_t)s * cN + n) * 2 + d] = cc * 2.0f;
  }
}

// ---------------------------------------------------------------------------
extern "C" void kernel_launch(void* const* d_in, const int* in_sizes, int n_in,
                              void* d_out, int out_size, void* d_ws, size_t ws_size,
                              hipStream_t stream) {
  (void)in_sizes; (void)n_in; (void)out_size; (void)ws_size;
  const float* rgbs = (const float*)d_in[0];
  const float* pts  = (const float*)d_in[1];
  const float* fnw  = (const float*)d_in[2];
  const float* fnfw = (const float*)d_in[3];
  const float* lw   = (const float*)d_in[4];
  const float* lb   = (const float*)d_in[5];
  const float* w1s  = (const float*)d_in[6];
  const float* b1s  = (const float*)d_in[7];
  const float* w2s  = (const float*)d_in[8];
  const float* b2s  = (const float*)d_in[9];
  const float* w1t  = (const float*)d_in[10];
  const float* b1t  = (const float*)d_in[11];
  const float* w2t  = (const float*)d_in[12];
  const float* b2t  = (const float*)d_in[13];
  float* out = (float*)d_out;

  float* p = (float*)d_ws;
  auto alloc = [&](size_t nf) { float* r = p; p += nf; return r; };
  float* part  = alloc((size_t)2 * cS * cNCH * 128);
  float* ffw_s = alloc(cS * 128);
  float* ffw_t = alloc(cS * 128);
  _Float16* LWc = (_Float16*)alloc((size_t)588 * 128 / 2);
  float* b1te  = alloc(128);
  float* fmc   = alloc((size_t)cS * cHC * cWC * cC);
  float* arp   = alloc((size_t)cS * 196 * cC);
  float* partf = alloc((size_t)cS * cHF * cC * 2);
  float* stats = alloc(cS * cC * 2);
  _Float16* fmf = (_Float16*)alloc((size_t)cS * cHF * cWF * cC / 2);
  _Float16* pf1 = (_Float16*)alloc((size_t)cS * 50 * 60 * cC / 2);
  _Float16* pf2 = (_Float16*)alloc((size_t)cS * 25 * 30 * cC / 2);
  _Float16* pf3 = (_Float16*)alloc((size_t)cS * 12 * 15 * cC / 2);
  float* xys0  = alloc(cN * 2);
  float* cofA  = alloc((size_t)cS * cN * 2);
  float* cofB  = alloc((size_t)cS * cN * 2);

  // 1) independent front work
  k_front<<<NB_FFP + NB_CONVC + NB_CONVF, 256, 0, stream>>>(
      rgbs, w1s, w1t, fnw, fnfw, part, fmc, fmf, partf);
  // 2) reductions + precomputes
  k_mid<<<123, 256, 0, stream>>>(part, ffw_s, ffw_t, lw, lb, w1t, b1t, LWc, b1te,
                                 partf, stats, fmc, arp);
  // 3) coarse MLP + fine pyramid (independent roles)
  k_mix<<<464, 256, 0, stream>>>(arp, fmc, w1s, b1s, ffw_s, w2s, b2s, pts,
                                 cofA, xys0, out, fmf, pf1, pf2, pf3);
  // 4-7) fused fine iterations
  float* cbuf[2] = {cofA, cofB};
  for (int it = 0; it < cITERS; it++) {
    float* cur = cbuf[it & 1];
    float* nxt = cbuf[(it & 1) ^ 1];
    k_iter<<<1024, 256, 0, stream>>>(fmf, pf1, pf2, pf3, stats, LWc, b1te, ffw_t,
                                     w1t, w2t, b2t, cur, nxt, xys0,
                                     out + (size_t)(it + 1) * cS * cN * 2);
  }
}